// Round 1
// baseline (727.099 us; speedup 1.0000x reference)
//
#include <hip/hip_runtime.h>
#include <math.h>

#define BQ 8
#define CC 2048
#define DDIM 128
#define LLAY 3
#define HH 4
#define KK 200
#define SSLOT 64
#define OUTN 24
#define DH 32
#define TI 25

__device__ __forceinline__ float fgelu(float x) {
  // tanh-approx gelu (err ~3e-3 abs; used only in hrel path where it is
  // attenuated by ~0.05*sqrt(32)/sqrt(32) into scores -> ~1e-4)
  float u = 0.7978845608028654f * fmaf(0.044715f * x * x, x, x);
  float e = __expf(2.f * u);
  float t = 1.f - 2.f / (e + 1.f);
  return 0.5f * x * (1.f + t);
}
__device__ __forceinline__ float egelu(float x) {
  return 0.5f * x * (1.f + erff(x * 0.7071067811865476f));
}

// ---------------- top-k over 2048 per row (binary search on float bits) ----
__global__ __launch_bounds__(256) void topk_kernel(const float* __restrict__ x,
                                                   float* __restrict__ vals,
                                                   int* __restrict__ idx) {
  const int b = blockIdx.x, tid = threadIdx.x;
  float xv[8]; unsigned xb[8];
#pragma unroll
  for (int t = 0; t < 8; t++) {
    float v = x[b * CC + t * 256 + tid];   // x >= 0 (uniform[0,5)); log1p monotone
    xv[t] = v;
    xb[t] = __float_as_uint(v);
  }
  __shared__ int red[4];
  __shared__ int cnt;
  unsigned lo = 0u, hi = 0x7f800000u;
  while (lo < hi) {                        // uniform across block
    unsigned mid = (lo + hi) >> 1;
    int c = 0;
#pragma unroll
    for (int t = 0; t < 8; t++) c += (xb[t] > mid) ? 1 : 0;
#pragma unroll
    for (int m = 1; m <= 32; m <<= 1) c += __shfl_xor(c, m);
    if ((tid & 63) == 0) red[tid >> 6] = c;
    __syncthreads();
    int ct = red[0] + red[1] + red[2] + red[3];
    __syncthreads();
    if (ct >= KK) lo = mid + 1; else hi = mid;
  }
  const unsigned thr = lo;                 // = K-th largest bit pattern
  if (tid == 0) cnt = 0;
  __syncthreads();
#pragma unroll
  for (int t = 0; t < 8; t++) {
    if (xb[t] > thr) {
      int p = atomicAdd(&cnt, 1);          // strictly-greater count < K guaranteed
      vals[b * KK + p] = log1pf(xv[t]);
      idx[b * KK + p] = t * 256 + tid;
    }
  }
  __syncthreads();
#pragma unroll
  for (int t = 0; t < 8; t++) {
    if (xb[t] == thr) {
      int p = atomicAdd(&cnt, 1);
      if (p < KK) {
        vals[b * KK + p] = log1pf(xv[t]);
        idx[b * KK + p] = t * 256 + tid;
      }
    }
  }
}

// ---------------- b = role_emb[idx] * gelu(val * filler_w) -----------------
__global__ __launch_bounds__(256) void bind_kernel(const float* __restrict__ vals,
    const int* __restrict__ idx, const float* __restrict__ role_emb,
    const float* __restrict__ fw, float* __restrict__ btok) {
  int u = blockIdx.x * 256 + threadIdx.x;  // < 204800
  int dd = u & 127;
  int r = u >> 7;
  int b = r / KK, t = r - b * KK;
  float v = vals[b * KK + t];
  float fill = egelu(v * fw[dd]);
  btok[u] = role_emb[(size_t)idx[b * KK + t] * DDIM + dd] * fill;
}

// ---------------- generic tiled fp32 GEMM: C = act(A@W + bias) -------------
template <int ACT>
__global__ __launch_bounds__(256) void gemm_bias(const float* __restrict__ A,
    const float* __restrict__ W, const float* __restrict__ bias,
    float* __restrict__ C, int M, int N, int K) {
  __shared__ __align__(16) float As[16][68];
  __shared__ __align__(16) float Ws[16][68];
  const int tid = threadIdx.x;
  const int tx = tid & 15, ty = tid >> 4;
  const int m0 = blockIdx.x * 64, n0 = blockIdx.y * 64;
  float acc[4][4];
#pragma unroll
  for (int i = 0; i < 4; i++)
#pragma unroll
    for (int j = 0; j < 4; j++) acc[i][j] = 0.f;
  const int lm = tid >> 2, lk4 = (tid & 3) * 4;
  const int ln = tid & 63, lkq = tid >> 6;
  for (int k0 = 0; k0 < K; k0 += 16) {
    float4 a4 = *(const float4*)(A + (size_t)(m0 + lm) * K + k0 + lk4);
    As[lk4 + 0][lm] = a4.x; As[lk4 + 1][lm] = a4.y;
    As[lk4 + 2][lm] = a4.z; As[lk4 + 3][lm] = a4.w;
#pragma unroll
    for (int r = 0; r < 4; r++)
      Ws[lkq * 4 + r][ln] = W[(size_t)(k0 + lkq * 4 + r) * N + n0 + ln];
    __syncthreads();
#pragma unroll
    for (int kk = 0; kk < 16; kk++) {
      const float4 a = *(const float4*)&As[kk][ty * 4];
      const float4 w = *(const float4*)&Ws[kk][tx * 4];
      const float av[4] = {a.x, a.y, a.z, a.w};
      const float wv[4] = {w.x, w.y, w.z, w.w};
#pragma unroll
      for (int i = 0; i < 4; i++)
#pragma unroll
        for (int j = 0; j < 4; j++) acc[i][j] = fmaf(av[i], wv[j], acc[i][j]);
    }
    __syncthreads();
  }
  const float b0 = bias[n0 + tx * 4 + 0];
  const float b1 = bias[n0 + tx * 4 + 1];
  const float b2 = bias[n0 + tx * 4 + 2];
  const float b3 = bias[n0 + tx * 4 + 3];
#pragma unroll
  for (int i = 0; i < 4; i++) {
    float4 r;
    r.x = acc[i][0] + b0; r.y = acc[i][1] + b1;
    r.z = acc[i][2] + b2; r.w = acc[i][3] + b3;
    if (ACT == 1) { r.x = egelu(r.x); r.y = egelu(r.y); r.z = egelu(r.z); r.w = egelu(r.w); }
    *(float4*)(C + (size_t)(m0 + ty * 4 + i) * N + n0 + tx * 4) = r;
  }
}

// ---------------- per-head qt = q@W1q ; ktb = k@W1k + relb1 ----------------
__global__ __launch_bounds__(256) void head_proj(const float* __restrict__ q,
    const float* __restrict__ k, const float* __restrict__ W1,
    const float* __restrict__ b1, float* __restrict__ qt, float* __restrict__ ktb) {
  int u = blockIdx.x * 256 + threadIdx.x;  // < 409600
  int f = u & 31;
  int r = u >> 5;                          // < 12800
  int sel = (r >= 6400) ? 1 : 0;
  int rr = r - sel * 6400;
  int bh = rr / KK;
  int i = rr - bh * KK;
  int b = bh >> 2, h = bh & 3;
  const float* row = (sel ? k : q) + (size_t)(b * KK + i) * DDIM + h * DH;
  const float* W = W1 + sel * 1024;        // W1q rows 0..31 / W1k rows 32..63
  float a = sel ? b1[f] : 0.f;             // fold relb1 into kt
#pragma unroll
  for (int e = 0; e < 32; e++) a = fmaf(row[e], W[e * DH + f], a);
  float* o = sel ? ktb : qt;
  o[(size_t)(bh * KK + i) * DH + f] = a;
}

// ---------------- fused relational attention (the big one) -----------------
// scores[i,j] = (sum_f gelu(qt[i,f]+ktb[j,f]+sum_e k[j,e]*(q[i,e]*W1i[e,f]))*w2[f] + rb2)/sqrt(32)
// o[i,:] = softmax_j(scores) @ v     -- online softmax, no [K,K] materialized
__global__ __launch_bounds__(256, 1) void rel_attn(
    const float* __restrict__ q, const float* __restrict__ k, const float* __restrict__ v,
    const float* __restrict__ qt, const float* __restrict__ ktb,
    const float* __restrict__ W1i, const float* __restrict__ w2p,
    const float* __restrict__ rb2p, float* __restrict__ o) {
  __shared__ __align__(16) float kT[32][260];   // k transposed [e][j], stride 260: stage-write 4-way, hot-read 2-way
  __shared__ __align__(16) float vsh[256][34];  // v [j][f], stride 34: float2 reads 2-way
  __shared__ float qsh[TI][33];
  __shared__ float qtsh[TI][33];
  const int tid = threadIdx.x;
  const int bh = blockIdx.y;
  const int b = bh >> 2, h = bh & 3;
  const int i0 = blockIdx.x * TI;
  const float* kg = k + (size_t)(b * KK) * DDIM + h * DH;
  const float* vg = v + (size_t)(b * KK) * DDIM + h * DH;
  const float* qg = q + (size_t)(b * KK) * DDIM + h * DH;
  const float* qtg = qt + (size_t)(bh * KK) * DH;
  const float* ktg = ktb + (size_t)(bh * KK) * DH;
  for (int u = tid; u < 32 * 256; u += 256) {
    int j = u >> 5, e = u & 31;
    kT[e][j] = (j < KK) ? kg[(size_t)j * DDIM + e] : 0.f;
  }
  for (int u = tid; u < 32 * 256; u += 256) {
    int j = u >> 5, f = u & 31;
    vsh[j][f] = (j < KK) ? vg[(size_t)j * DDIM + f] : 0.f;
  }
  for (int u = tid; u < TI * 32; u += 256) {
    int i = u >> 5, e = u & 31;
    qsh[i][e] = qg[(size_t)(i0 + i) * DDIM + e];
    qtsh[i][e] = qtg[(size_t)(i0 + i) * DH + e];
  }
  __syncthreads();
  const int wv = tid >> 6, lane = tid & 63;
  const int fg = lane & 7, jg = lane >> 3;
  const int fq4 = fg * 4;
  float4 Wreg[32];                          // W1i column-slice resident in VGPRs
#pragma unroll
  for (int e = 0; e < 32; e++) Wreg[e] = *(const float4*)(W1i + e * DH + fq4);
  const float4 w2v = *(const float4*)(w2p + fq4);
  const float rb2 = rb2p[0];
  const float inv_sd = 0.17677669529663687f;  // 1/sqrt(32)

  for (int il = wv; il < TI; il += 4) {
    const int i = i0 + il;
    const float qtv0 = qtsh[il][fq4 + 0], qtv1 = qtsh[il][fq4 + 1];
    const float qtv2 = qtsh[il][fq4 + 2], qtv3 = qtsh[il][fq4 + 3];
    float mrun = -1e30f, lrun = 0.f;
    float of0 = 0.f, of1 = 0.f, of2 = 0.f, of3 = 0.f;
    for (int jt = 0; jt < 256; jt += 64) {
      const int jbase = jt + 8 * jg;
      float4 ktr[8];
#pragma unroll
      for (int jj = 0; jj < 8; jj++) {
        int j = jbase + jj;
        if (j < KK) ktr[jj] = *(const float4*)(ktg + (size_t)j * DH + fq4);
        else ktr[jj] = make_float4(0.f, 0.f, 0.f, 0.f);
      }
      float4 acc[8];
#pragma unroll
      for (int jj = 0; jj < 8; jj++) acc[jj] = make_float4(0.f, 0.f, 0.f, 0.f);
#pragma unroll
      for (int e = 0; e < 32; e++) {
        const float qe = qsh[il][e];
        const float4 k0 = *(const float4*)&kT[e][jbase];
        const float4 k1 = *(const float4*)&kT[e][jbase + 4];
        const float4 w = Wreg[e];
        const float w0 = qe * w.x, w1 = qe * w.y, w2_ = qe * w.z, w3 = qe * w.w;
        const float kjv[8] = {k0.x, k0.y, k0.z, k0.w, k1.x, k1.y, k1.z, k1.w};
#pragma unroll
        for (int jj = 0; jj < 8; jj++) {
          acc[jj].x = fmaf(kjv[jj], w0, acc[jj].x);
          acc[jj].y = fmaf(kjv[jj], w1, acc[jj].y);
          acc[jj].z = fmaf(kjv[jj], w2_, acc[jj].z);
          acc[jj].w = fmaf(kjv[jj], w3, acc[jj].w);
        }
      }
      float sj[8];
#pragma unroll
      for (int jj = 0; jj < 8; jj++) {
        sj[jj] = fgelu(acc[jj].x + qtv0 + ktr[jj].x) * w2v.x
               + fgelu(acc[jj].y + qtv1 + ktr[jj].y) * w2v.y
               + fgelu(acc[jj].z + qtv2 + ktr[jj].z) * w2v.z
               + fgelu(acc[jj].w + qtv3 + ktr[jj].w) * w2v.w;
      }
#pragma unroll
      for (int jj = 0; jj < 8; jj++) {      // reduce over the 8 fg lanes
        sj[jj] += __shfl_xor(sj[jj], 1);
        sj[jj] += __shfl_xor(sj[jj], 2);
        sj[jj] += __shfl_xor(sj[jj], 4);
      }
      float tmax = -1e30f;
#pragma unroll
      for (int jj = 0; jj < 8; jj++) {
        float s = (sj[jj] + rb2) * inv_sd;
        if (jbase + jj >= KK) s = -1e30f;   // mask padded j (first tile always real -> m finite)
        sj[jj] = s;
        tmax = fmaxf(tmax, s);
      }
      const float mnew = fmaxf(mrun, tmax);
      const float alpha = __expf(mrun - mnew);
      lrun *= alpha; of0 *= alpha; of1 *= alpha; of2 *= alpha; of3 *= alpha;
#pragma unroll
      for (int jj = 0; jj < 8; jj++) {
        const float p = __expf(sj[jj] - mnew);
        lrun += p;
        const float2 v0 = *(const float2*)&vsh[jbase + jj][fq4];
        const float2 v1 = *(const float2*)&vsh[jbase + jj][fq4 + 2];
        of0 = fmaf(p, v0.x, of0); of1 = fmaf(p, v0.y, of1);
        of2 = fmaf(p, v1.x, of2); of3 = fmaf(p, v1.y, of3);
      }
      mrun = mnew;
    }
#pragma unroll
    for (int msk = 8; msk <= 32; msk <<= 1) {  // combine over the 8 jg lanes
      float mo = __shfl_xor(mrun, msk);
      float lo_ = __shfl_xor(lrun, msk);
      float a0 = __shfl_xor(of0, msk), a1 = __shfl_xor(of1, msk);
      float a2 = __shfl_xor(of2, msk), a3 = __shfl_xor(of3, msk);
      float mn = fmaxf(mrun, mo);
      float ea = __expf(mrun - mn), eb = __expf(mo - mn);
      lrun = ea * lrun + eb * lo_;
      of0 = ea * of0 + eb * a0; of1 = ea * of1 + eb * a1;
      of2 = ea * of2 + eb * a2; of3 = ea * of3 + eb * a3;
      mrun = mn;
    }
    if (jg == 0) {
      const float inv = 1.f / lrun;
      float4 r = make_float4(of0 * inv, of1 * inv, of2 * inv, of3 * inv);
      *(float4*)(o + (size_t)(b * KK + i) * DDIM + h * DH + fq4) = r;
    }
  }
}

// ---------------- residual + LayerNorm (wave per token) --------------------
__global__ __launch_bounds__(256) void res_ln(float* __restrict__ B,
    const float* __restrict__ add, const float* __restrict__ g,
    const float* __restrict__ bt) {
  int tok = blockIdx.x * 4 + (threadIdx.x >> 6);
  int ln = threadIdx.x & 63;
  float* row = B + (size_t)tok * DDIM;
  const float* ar = add + (size_t)tok * DDIM;
  float x0 = row[ln] + ar[ln];
  float x1 = row[ln + 64] + ar[ln + 64];
  float s = x0 + x1;
#pragma unroll
  for (int m = 1; m <= 32; m <<= 1) s += __shfl_xor(s, m);
  float mean = s * (1.f / 128.f);
  float d0 = x0 - mean, d1 = x1 - mean;
  float qq = d0 * d0 + d1 * d1;
#pragma unroll
  for (int m = 1; m <= 32; m <<= 1) qq += __shfl_xor(qq, m);
  float rs = rsqrtf(qq * (1.f / 128.f) + 1e-5f);
  row[ln] = d0 * rs * g[ln] + bt[ln];
  row[ln + 64] = d1 * rs * g[ln + 64] + bt[ln + 64];
}

// ---------------- memory-slot attention rows: ma[b,s,c] --------------------
__global__ __launch_bounds__(256) void slot_ma(const float* __restrict__ B,
    const float* __restrict__ slots, float* __restrict__ ma) {
  const int bs = blockIdx.x;  // b*64+s
  const int s = bs & 63;
  const int b = bs >> 6;
  const int tid = threadIdx.x;
  __shared__ __align__(16) float sl[128];
  __shared__ float red1[4], red2[4];
  if (tid < 128) sl[tid] = slots[(size_t)s * DDIM + tid];
  __syncthreads();
  float sc = -1e30f;
  if (tid < KK) {
    const float* br = B + (size_t)(b * KK + tid) * DDIM;
    float a = 0.f;
#pragma unroll
    for (int d4 = 0; d4 < 32; d4++) {
      float4 bb = *(const float4*)(br + d4 * 4);
      float4 ss = *(const float4*)(sl + d4 * 4);
      a += bb.x * ss.x + bb.y * ss.y + bb.z * ss.z + bb.w * ss.w;
    }
    sc = a * 0.08838834764831845f;  // 1/sqrt(128)
  }
  float mx = sc;
#pragma unroll
  for (int m = 1; m <= 32; m <<= 1) mx = fmaxf(mx, __shfl_xor(mx, m));
  if ((tid & 63) == 0) red1[tid >> 6] = mx;
  __syncthreads();
  mx = fmaxf(fmaxf(red1[0], red1[1]), fmaxf(red1[2], red1[3]));
  float p = (tid < KK) ? __expf(sc - mx) : 0.f;
  float sm = p;
#pragma unroll
  for (int m = 1; m <= 32; m <<= 1) sm += __shfl_xor(sm, m);
  if ((tid & 63) == 0) red2[tid >> 6] = sm;
  __syncthreads();
  sm = red2[0] + red2[1] + red2[2] + red2[3];
  if (tid < KK) ma[(size_t)bs * KK + tid] = p / sm;
}

// ---------------- final readout: h + LN(mem) -> head ------------------------
__global__ __launch_bounds__(256) void readout_kernel(const float* __restrict__ B,
    const float* __restrict__ ma, const float* __restrict__ task_q,
    const float* __restrict__ memg, const float* __restrict__ membt,
    const float* __restrict__ headW, const float* __restrict__ headb,
    float* __restrict__ out) {
  const int b = blockIdx.x, tid = threadIdx.x;
  __shared__ __align__(16) float tq[128];
  __shared__ float ras[KK];
  __shared__ float wc[KK];
  __shared__ float red1[4], red2[4];
  __shared__ float hv[128], mv[128], rv[128];
  __shared__ float stats[2];
  if (tid < 128) tq[tid] = task_q[tid];
  __syncthreads();
  float sc = -1e30f;
  if (tid < KK) {
    const float* br = B + (size_t)(b * KK + tid) * DDIM;
    float a = 0.f;
#pragma unroll
    for (int d4 = 0; d4 < 32; d4++) {
      float4 bb = *(const float4*)(br + d4 * 4);
      float4 ss = *(const float4*)(tq + d4 * 4);
      a += bb.x * ss.x + bb.y * ss.y + bb.z * ss.z + bb.w * ss.w;
    }
    sc = a * 0.08838834764831845f;
  }
  float mx = sc;
#pragma unroll
  for (int m = 1; m <= 32; m <<= 1) mx = fmaxf(mx, __shfl_xor(mx, m));
  if ((tid & 63) == 0) red1[tid >> 6] = mx;
  __syncthreads();
  mx = fmaxf(fmaxf(red1[0], red1[1]), fmaxf(red1[2], red1[3]));
  float p = (tid < KK) ? __expf(sc - mx) : 0.f;
  float sm = p;
#pragma unroll
  for (int m = 1; m <= 32; m <<= 1) sm += __shfl_xor(sm, m);
  if ((tid & 63) == 0) red2[tid >> 6] = sm;
  __syncthreads();
  sm = red2[0] + red2[1] + red2[2] + red2[3];
  if (tid < KK) {
    ras[tid] = p / sm;
    float a = 0.f;
    for (int s_ = 0; s_ < SSLOT; s_++) a += ma[((size_t)b * SSLOT + s_) * KK + tid];
    wc[tid] = a * (1.f / 64.f);
  }
  __syncthreads();
  if (tid < 128) {
    float hd = 0.f, md = 0.f;
    for (int c = 0; c < KK; c++) {
      float bv = B[(size_t)(b * KK + c) * DDIM + tid];
      hd = fmaf(ras[c], bv, hd);
      md = fmaf(wc[c], bv, md);
    }
    hv[tid] = hd; mv[tid] = md;
  }
  __syncthreads();
  if (tid < 64) {
    float x0 = mv[tid], x1 = mv[tid + 64];
    float s = x0 + x1, qq = x0 * x0 + x1 * x1;
#pragma unroll
    for (int m = 1; m <= 32; m <<= 1) { s += __shfl_xor(s, m); qq += __shfl_xor(qq, m); }
    if (tid == 0) { stats[0] = s; stats[1] = qq; }
  }
  __syncthreads();
  float mean = stats[0] * (1.f / 128.f);
  float var = stats[1] * (1.f / 128.f) - mean * mean;
  float rs = rsqrtf(var + 1e-5f);
  if (tid < 128) rv[tid] = hv[tid] + (mv[tid] - mean) * rs * memg[tid] + membt[tid];
  __syncthreads();
  if (tid < OUTN) {
    float a = headb[tid];
    for (int dd = 0; dd < 128; dd++) a = fmaf(rv[dd], headW[dd * OUTN + tid], a);
    out[b * OUTN + tid] = a;
  }
}

// ---------------------------------------------------------------------------
extern "C" void kernel_launch(void* const* d_in, const int* in_sizes, int n_in,
                              void* d_out, int out_size, void* d_ws, size_t ws_size,
                              hipStream_t stream) {
  (void)in_sizes; (void)n_in; (void)out_size; (void)ws_size;
  const float* x        = (const float*)d_in[0];
  const float* role_emb = (const float*)d_in[1];
  const float* filler_w = (const float*)d_in[2];
  const float* qW = (const float*)d_in[3];
  const float* qb = (const float*)d_in[4];
  const float* kW = (const float*)d_in[5];
  const float* kb = (const float*)d_in[6];
  const float* vW = (const float*)d_in[7];
  const float* vb = (const float*)d_in[8];
  const float* oW = (const float*)d_in[9];
  const float* ob = (const float*)d_in[10];
  const float* relW1 = (const float*)d_in[11];
  const float* relb1 = (const float*)d_in[12];
  const float* relW2 = (const float*)d_in[13];
  const float* relb2 = (const float*)d_in[14];
  const float* ln1g = (const float*)d_in[15];
  const float* ln1b = (const float*)d_in[16];
  const float* ln2g = (const float*)d_in[17];
  const float* ln2b = (const float*)d_in[18];
  const float* fW1 = (const float*)d_in[19];
  const float* fb1 = (const float*)d_in[20];
  const float* fW2 = (const float*)d_in[21];
  const float* fb2 = (const float*)d_in[22];
  const float* slots = (const float*)d_in[23];
  const float* memg = (const float*)d_in[24];
  const float* memb = (const float*)d_in[25];
  const float* taskq = (const float*)d_in[26];
  const float* headW = (const float*)d_in[27];
  const float* headb = (const float*)d_in[28];
  float* out = (float*)d_out;

  // workspace layout (float offsets; all 16B aligned)
  float* fws  = (float*)d_ws;
  int*   idxb = (int*)d_ws;              //   1600 ints
  float* vals = fws + 1600;              //   1600
  float* btok = fws + 3200;              // 204800
  float* qbuf = fws + 208000;            // 204800
  float* kbuf = fws + 412800;            // 204800
  float* vbuf = fws + 617600;            // 204800
  float* qtb  = fws + 822400;            // 204800
  float* ktbb = fws + 1027200;           // 204800
  float* obuf = fws + 1232000;           // 204800
  float* tmpb = fws + 1436800;           // 204800
  float* hbuf = fws + 1641600;           // 819200
  float* mab  = fws + 2460800;           // 102400  (total ~10.3 MB)

  topk_kernel<<<8, 256, 0, stream>>>(x, vals, idxb);
  bind_kernel<<<800, 256, 0, stream>>>(vals, idxb, role_emb, filler_w, btok);
  for (int l = 0; l < LLAY; l++) {
    gemm_bias<0><<<dim3(25, 2), 256, 0, stream>>>(btok, qW + l * 16384, qb + l * 128, qbuf, 1600, 128, 128);
    gemm_bias<0><<<dim3(25, 2), 256, 0, stream>>>(btok, kW + l * 16384, kb + l * 128, kbuf, 1600, 128, 128);
    gemm_bias<0><<<dim3(25, 2), 256, 0, stream>>>(btok, vW + l * 16384, vb + l * 128, vbuf, 1600, 128, 128);
    head_proj<<<1600, 256, 0, stream>>>(qbuf, kbuf, relW1 + l * 3072, relb1 + l * 32, qtb, ktbb);
    rel_attn<<<dim3(8, 32), 256, 0, stream>>>(qbuf, kbuf, vbuf, qtb, ktbb,
        relW1 + l * 3072 + 2048, relW2 + l * 32, relb2 + l, obuf);
    gemm_bias<0><<<dim3(25, 2), 256, 0, stream>>>(obuf, oW + l * 16384, ob + l * 128, tmpb, 1600, 128, 128);
    res_ln<<<400, 256, 0, stream>>>(btok, tmpb, ln1g + l * 128, ln1b + l * 128);
    gemm_bias<1><<<dim3(25, 8), 256, 0, stream>>>(btok, fW1 + l * 65536, fb1 + l * 512, hbuf, 1600, 512, 128);
    gemm_bias<0><<<dim3(25, 2), 256, 0, stream>>>(hbuf, fW2 + l * 65536, fb2 + l * 128, tmpb, 1600, 128, 512);
    res_ln<<<400, 256, 0, stream>>>(btok, tmpb, ln2g + l * 128, ln2b + l * 128);
  }
  slot_ma<<<512, 256, 0, stream>>>(btok, slots, mab);
  readout_kernel<<<8, 256, 0, stream>>>(btok, mab, taskq, memg, memb, headW, headb, out);
}

// Round 2
// 606.054 us; speedup vs baseline: 1.1997x; 1.1997x over previous
//
#include <hip/hip_runtime.h>
#include <math.h>

#define BQ 8
#define CC 2048
#define DDIM 128
#define LLAY 3
#define HH 4
#define KK 200
#define SSLOT 64
#define OUTN 24
#define DH 32
#define TI 13

__device__ __forceinline__ float fgelu(float x) {
  // tanh-approx gelu (err ~3e-3 abs; only in hrel path, attenuated into scores)
  float u = 0.7978845608028654f * fmaf(0.044715f * x * x, x, x);
  float e = __expf(2.f * u);
  float t = 1.f - 2.f / (e + 1.f);
  return 0.5f * x * (1.f + t);
}
__device__ __forceinline__ float egelu(float x) {
  return 0.5f * x * (1.f + erff(x * 0.7071067811865476f));
}

// ---------------- top-k over 2048 per row (binary search on float bits) ----
__global__ __launch_bounds__(256) void topk_kernel(const float* __restrict__ x,
                                                   float* __restrict__ vals,
                                                   int* __restrict__ idx) {
  const int b = blockIdx.x, tid = threadIdx.x;
  float xv[8]; unsigned xb[8];
#pragma unroll
  for (int t = 0; t < 8; t++) {
    float v = x[b * CC + t * 256 + tid];
    xv[t] = v;
    xb[t] = __float_as_uint(v);
  }
  __shared__ int red[4];
  __shared__ int cnt;
  unsigned lo = 0u, hi = 0x7f800000u;
  while (lo < hi) {
    unsigned mid = (lo + hi) >> 1;
    int c = 0;
#pragma unroll
    for (int t = 0; t < 8; t++) c += (xb[t] > mid) ? 1 : 0;
#pragma unroll
    for (int m = 1; m <= 32; m <<= 1) c += __shfl_xor(c, m);
    if ((tid & 63) == 0) red[tid >> 6] = c;
    __syncthreads();
    int ct = red[0] + red[1] + red[2] + red[3];
    __syncthreads();
    if (ct >= KK) lo = mid + 1; else hi = mid;
  }
  const unsigned thr = lo;
  if (tid == 0) cnt = 0;
  __syncthreads();
#pragma unroll
  for (int t = 0; t < 8; t++) {
    if (xb[t] > thr) {
      int p = atomicAdd(&cnt, 1);
      vals[b * KK + p] = log1pf(xv[t]);
      idx[b * KK + p] = t * 256 + tid;
    }
  }
  __syncthreads();
#pragma unroll
  for (int t = 0; t < 8; t++) {
    if (xb[t] == thr) {
      int p = atomicAdd(&cnt, 1);
      if (p < KK) {
        vals[b * KK + p] = log1pf(xv[t]);
        idx[b * KK + p] = t * 256 + tid;
      }
    }
  }
}

// ---------------- b = role_emb[idx] * gelu(val * filler_w) -----------------
__global__ __launch_bounds__(256) void bind_kernel(const float* __restrict__ vals,
    const int* __restrict__ idx, const float* __restrict__ role_emb,
    const float* __restrict__ fw, float* __restrict__ btok) {
  int u = blockIdx.x * 256 + threadIdx.x;  // < 204800
  int dd = u & 127;
  int r = u >> 7;
  int b = r / KK, t = r - b * KK;
  float v = vals[b * KK + t];
  float fill = egelu(v * fw[dd]);
  btok[u] = role_emb[(size_t)idx[b * KK + t] * DDIM + dd] * fill;
}

// ---------------- generic tiled fp32 GEMM: C = act(A@W + bias) -------------
template <int ACT>
__global__ __launch_bounds__(256) void gemm_bias(const float* __restrict__ A,
    const float* __restrict__ W, const float* __restrict__ bias,
    float* __restrict__ C, int M, int N, int K) {
  __shared__ __align__(16) float As[16][68];
  __shared__ __align__(16) float Ws[16][68];
  const int tid = threadIdx.x;
  const int tx = tid & 15, ty = tid >> 4;
  const int m0 = blockIdx.x * 64, n0 = blockIdx.y * 64;
  float acc[4][4];
#pragma unroll
  for (int i = 0; i < 4; i++)
#pragma unroll
    for (int j = 0; j < 4; j++) acc[i][j] = 0.f;
  const int lm = tid >> 2, lk4 = (tid & 3) * 4;
  const int ln = tid & 63, lkq = tid >> 6;
  for (int k0 = 0; k0 < K; k0 += 16) {
    float4 a4 = *(const float4*)(A + (size_t)(m0 + lm) * K + k0 + lk4);
    As[lk4 + 0][lm] = a4.x; As[lk4 + 1][lm] = a4.y;
    As[lk4 + 2][lm] = a4.z; As[lk4 + 3][lm] = a4.w;
#pragma unroll
    for (int r = 0; r < 4; r++)
      Ws[lkq * 4 + r][ln] = W[(size_t)(k0 + lkq * 4 + r) * N + n0 + ln];
    __syncthreads();
#pragma unroll
    for (int kk = 0; kk < 16; kk++) {
      const float4 a = *(const float4*)&As[kk][ty * 4];
      const float4 w = *(const float4*)&Ws[kk][tx * 4];
      const float av[4] = {a.x, a.y, a.z, a.w};
      const float wv[4] = {w.x, w.y, w.z, w.w};
#pragma unroll
      for (int i = 0; i < 4; i++)
#pragma unroll
        for (int j = 0; j < 4; j++) acc[i][j] = fmaf(av[i], wv[j], acc[i][j]);
    }
    __syncthreads();
  }
  const float b0 = bias[n0 + tx * 4 + 0];
  const float b1 = bias[n0 + tx * 4 + 1];
  const float b2 = bias[n0 + tx * 4 + 2];
  const float b3 = bias[n0 + tx * 4 + 3];
#pragma unroll
  for (int i = 0; i < 4; i++) {
    float4 r;
    r.x = acc[i][0] + b0; r.y = acc[i][1] + b1;
    r.z = acc[i][2] + b2; r.w = acc[i][3] + b3;
    if (ACT == 1) { r.x = egelu(r.x); r.y = egelu(r.y); r.z = egelu(r.z); r.w = egelu(r.w); }
    *(float4*)(C + (size_t)(m0 + ty * 4 + i) * N + n0 + tx * 4) = r;
  }
}

// ---------------- batched QKV GEMM (z selects q/k/v), M=1600 N=128 K=128 ---
__global__ __launch_bounds__(256) void qkv_gemm(const float* __restrict__ A,
    const float* __restrict__ qW, const float* __restrict__ qb,
    const float* __restrict__ kW, const float* __restrict__ kb,
    const float* __restrict__ vW, const float* __restrict__ vb,
    float* __restrict__ qo, float* __restrict__ ko, float* __restrict__ vo) {
  const float* W; const float* bias; float* C;
  if (blockIdx.z == 0) { W = qW; bias = qb; C = qo; }
  else if (blockIdx.z == 1) { W = kW; bias = kb; C = ko; }
  else { W = vW; bias = vb; C = vo; }
  __shared__ __align__(16) float As[16][68];
  __shared__ __align__(16) float Ws[16][68];
  const int tid = threadIdx.x;
  const int tx = tid & 15, ty = tid >> 4;
  const int m0 = blockIdx.x * 64, n0 = blockIdx.y * 64;
  float acc[4][4];
#pragma unroll
  for (int i = 0; i < 4; i++)
#pragma unroll
    for (int j = 0; j < 4; j++) acc[i][j] = 0.f;
  const int lm = tid >> 2, lk4 = (tid & 3) * 4;
  const int ln = tid & 63, lkq = tid >> 6;
  for (int k0 = 0; k0 < 128; k0 += 16) {
    float4 a4 = *(const float4*)(A + (size_t)(m0 + lm) * 128 + k0 + lk4);
    As[lk4 + 0][lm] = a4.x; As[lk4 + 1][lm] = a4.y;
    As[lk4 + 2][lm] = a4.z; As[lk4 + 3][lm] = a4.w;
#pragma unroll
    for (int r = 0; r < 4; r++)
      Ws[lkq * 4 + r][ln] = W[(size_t)(k0 + lkq * 4 + r) * 128 + n0 + ln];
    __syncthreads();
#pragma unroll
    for (int kk = 0; kk < 16; kk++) {
      const float4 a = *(const float4*)&As[kk][ty * 4];
      const float4 w = *(const float4*)&Ws[kk][tx * 4];
      const float av[4] = {a.x, a.y, a.z, a.w};
      const float wv[4] = {w.x, w.y, w.z, w.w};
#pragma unroll
      for (int i = 0; i < 4; i++)
#pragma unroll
        for (int j = 0; j < 4; j++) acc[i][j] = fmaf(av[i], wv[j], acc[i][j]);
    }
    __syncthreads();
  }
  const float b0 = bias[n0 + tx * 4 + 0];
  const float b1 = bias[n0 + tx * 4 + 1];
  const float b2 = bias[n0 + tx * 4 + 2];
  const float b3 = bias[n0 + tx * 4 + 3];
#pragma unroll
  for (int i = 0; i < 4; i++) {
    float4 r;
    r.x = acc[i][0] + b0; r.y = acc[i][1] + b1;
    r.z = acc[i][2] + b2; r.w = acc[i][3] + b3;
    *(float4*)(C + (size_t)(m0 + ty * 4 + i) * 128 + n0 + tx * 4) = r;
  }
}

// ---------------- fused relational attention v2 ----------------------------
// Weff[e,f] = q[i,e]*W1i[e,f] + W1k[e,f]  (register-resident per il)
// score arg = (q_i@W1q + b1)[f] + sum_e k[j,e]*Weff[e,f]
// o[i,:] = softmax_j((sum_f gelu(arg)*w2[f] + rb2)/sqrt(32)) @ v
__global__ __launch_bounds__(256, 2) void rel_attn(
    const float* __restrict__ q, const float* __restrict__ k, const float* __restrict__ v,
    const float* __restrict__ W1g, const float* __restrict__ b1g,
    const float* __restrict__ w2p, const float* __restrict__ rb2p,
    float* __restrict__ o) {
  __shared__ __align__(16) float kT[32][212];   // k transposed [e][j], cols 200..211 zero
  __shared__ __align__(16) float vsh[208][34];  // v [j][f], rows 200..207 zero
  __shared__ __align__(16) float w1sh[3072];    // [96][32]: W1q | W1k | W1i
  __shared__ __align__(16) float qsh[TI][33];
  __shared__ float b1sh[32];
  const int tid = threadIdx.x;
  const int bh = blockIdx.y;
  const int b = bh >> 2, h = bh & 3;
  const int i0 = blockIdx.x * TI;
  const float* kg = k + (size_t)(b * KK) * DDIM + h * DH;
  const float* vg = v + (size_t)(b * KK) * DDIM + h * DH;
  const float* qg = q + (size_t)(b * KK) * DDIM + h * DH;
  for (int u = tid; u < 208 * 32; u += 256) {
    int j = u >> 5, e = u & 31;
    kT[e][j] = (j < KK) ? kg[(size_t)j * DDIM + e] : 0.f;
  }
  for (int u = tid; u < 208 * 32; u += 256) {
    int j = u >> 5, f = u & 31;
    vsh[j][f] = (j < KK) ? vg[(size_t)j * DDIM + f] : 0.f;
  }
  for (int u = tid; u < 3072; u += 256) w1sh[u] = W1g[u];
  if (tid < 32) b1sh[tid] = b1g[tid];
  for (int u = tid; u < TI * 32; u += 256) {
    int il = u >> 5, e = u & 31;
    int i = i0 + il;
    qsh[il][e] = (i < KK) ? qg[(size_t)i * DDIM + e] : 0.f;
  }
  __syncthreads();
  const int wv = tid >> 6, lane = tid & 63;
  const int fg = lane & 7, jg = lane >> 3;
  const int fq4 = fg * 4;
  const float4 w2v = *(const float4*)(w2p + fq4);
  const float rb2 = rb2p[0];
  const float inv_sd = 0.17677669529663687f;  // 1/sqrt(32)

  for (int il = wv; il < TI; il += 4) {
    const int i = i0 + il;
    if (i >= KK) continue;  // wave-uniform
    // ---- per-i preamble: qtv = q_i@W1q + b1 ; Weff = q_i*W1i + W1k -------
    float4 Weff[32];
    float4 qtv = *(const float4*)(b1sh + fq4);
#pragma unroll
    for (int e = 0; e < 32; e++) {
      const float qe = qsh[il][e];
      const float4 wq = *(const float4*)(w1sh + e * 32 + fq4);
      const float4 wk = *(const float4*)(w1sh + 1024 + e * 32 + fq4);
      const float4 wi = *(const float4*)(w1sh + 2048 + e * 32 + fq4);
      qtv.x = fmaf(qe, wq.x, qtv.x); qtv.y = fmaf(qe, wq.y, qtv.y);
      qtv.z = fmaf(qe, wq.z, qtv.z); qtv.w = fmaf(qe, wq.w, qtv.w);
      Weff[e].x = fmaf(qe, wi.x, wk.x); Weff[e].y = fmaf(qe, wi.y, wk.y);
      Weff[e].z = fmaf(qe, wi.z, wk.z); Weff[e].w = fmaf(qe, wi.w, wk.w);
    }
    float mrun = -1e30f, lrun = 0.f;
    float of0 = 0.f, of1 = 0.f, of2 = 0.f, of3 = 0.f;
    for (int jt = 0; jt < 256; jt += 64) {
      const int jbase = jt + 8 * jg;
      const int jb = (jbase < 200) ? jbase : 200;  // clamp: rows 200..207 are zeros
      float4 acc[8];
#pragma unroll
      for (int jj = 0; jj < 8; jj++) acc[jj] = make_float4(0.f, 0.f, 0.f, 0.f);
#pragma unroll
      for (int e = 0; e < 32; e++) {
        const float4 k0 = *(const float4*)&kT[e][jb];
        const float4 k1 = *(const float4*)&kT[e][jb + 4];
        const float4 w = Weff[e];
        const float kjv[8] = {k0.x, k0.y, k0.z, k0.w, k1.x, k1.y, k1.z, k1.w};
#pragma unroll
        for (int jj = 0; jj < 8; jj++) {
          acc[jj].x = fmaf(kjv[jj], w.x, acc[jj].x);
          acc[jj].y = fmaf(kjv[jj], w.y, acc[jj].y);
          acc[jj].z = fmaf(kjv[jj], w.z, acc[jj].z);
          acc[jj].w = fmaf(kjv[jj], w.w, acc[jj].w);
        }
      }
      float sj[8];
#pragma unroll
      for (int jj = 0; jj < 8; jj++) {
        sj[jj] = fgelu(acc[jj].x + qtv.x) * w2v.x
               + fgelu(acc[jj].y + qtv.y) * w2v.y
               + fgelu(acc[jj].z + qtv.z) * w2v.z
               + fgelu(acc[jj].w + qtv.w) * w2v.w;
      }
#pragma unroll
      for (int jj = 0; jj < 8; jj++) {      // reduce over the 8 fg lanes
        sj[jj] += __shfl_xor(sj[jj], 1);
        sj[jj] += __shfl_xor(sj[jj], 2);
        sj[jj] += __shfl_xor(sj[jj], 4);
      }
      float tmax = -1e30f;
#pragma unroll
      for (int jj = 0; jj < 8; jj++) {
        float s = (sj[jj] + rb2) * inv_sd;
        if (jbase + jj >= KK) s = -1e30f;   // mask padded j
        sj[jj] = s;
        tmax = fmaxf(tmax, s);
      }
      const float mnew = fmaxf(mrun, tmax);
      const float alpha = __expf(mrun - mnew);
      lrun *= alpha; of0 *= alpha; of1 *= alpha; of2 *= alpha; of3 *= alpha;
#pragma unroll
      for (int jj = 0; jj < 8; jj++) {
        const float p = __expf(sj[jj] - mnew);  // p==0 exactly for masked j
        lrun += p;
        const float2 v0 = *(const float2*)&vsh[jb + jj][fq4];
        const float2 v1 = *(const float2*)&vsh[jb + jj][fq4 + 2];
        of0 = fmaf(p, v0.x, of0); of1 = fmaf(p, v0.y, of1);
        of2 = fmaf(p, v1.x, of2); of3 = fmaf(p, v1.y, of3);
      }
      mrun = mnew;
    }
#pragma unroll
    for (int msk = 8; msk <= 32; msk <<= 1) {  // combine over the 8 jg lanes
      float mo = __shfl_xor(mrun, msk);
      float lo_ = __shfl_xor(lrun, msk);
      float a0 = __shfl_xor(of0, msk), a1 = __shfl_xor(of1, msk);
      float a2 = __shfl_xor(of2, msk), a3 = __shfl_xor(of3, msk);
      float mn = fmaxf(mrun, mo);
      float ea = __expf(mrun - mn), eb = __expf(mo - mn);
      lrun = ea * lrun + eb * lo_;
      of0 = ea * of0 + eb * a0; of1 = ea * of1 + eb * a1;
      of2 = ea * of2 + eb * a2; of3 = ea * of3 + eb * a3;
      mrun = mn;
    }
    if (jg == 0) {
      const float inv = 1.f / lrun;
      float4 r = make_float4(of0 * inv, of1 * inv, of2 * inv, of3 * inv);
      *(float4*)(o + (size_t)(b * KK + i) * DDIM + h * DH + fq4) = r;
    }
  }
}

// ---------------- residual + LayerNorm (wave per token) --------------------
__global__ __launch_bounds__(256) void res_ln(float* __restrict__ B,
    const float* __restrict__ add, const float* __restrict__ g,
    const float* __restrict__ bt) {
  int tok = blockIdx.x * 4 + (threadIdx.x >> 6);
  int ln = threadIdx.x & 63;
  float* row = B + (size_t)tok * DDIM;
  const float* ar = add + (size_t)tok * DDIM;
  float x0 = row[ln] + ar[ln];
  float x1 = row[ln + 64] + ar[ln + 64];
  float s = x0 + x1;
#pragma unroll
  for (int m = 1; m <= 32; m <<= 1) s += __shfl_xor(s, m);
  float mean = s * (1.f / 128.f);
  float d0 = x0 - mean, d1 = x1 - mean;
  float qq = d0 * d0 + d1 * d1;
#pragma unroll
  for (int m = 1; m <= 32; m <<= 1) qq += __shfl_xor(qq, m);
  float rs = rsqrtf(qq * (1.f / 128.f) + 1e-5f);
  row[ln] = d0 * rs * g[ln] + bt[ln];
  row[ln + 64] = d1 * rs * g[ln + 64] + bt[ln + 64];
}

// ---------------- memory-slot attention rows: ma[b,s,c] --------------------
__global__ __launch_bounds__(256) void slot_ma(const float* __restrict__ B,
    const float* __restrict__ slots, float* __restrict__ ma) {
  const int bs = blockIdx.x;  // b*64+s
  const int s = bs & 63;
  const int b = bs >> 6;
  const int tid = threadIdx.x;
  __shared__ __align__(16) float sl[128];
  __shared__ float red1[4], red2[4];
  if (tid < 128) sl[tid] = slots[(size_t)s * DDIM + tid];
  __syncthreads();
  float sc = -1e30f;
  if (tid < KK) {
    const float* br = B + (size_t)(b * KK + tid) * DDIM;
    float a = 0.f;
#pragma unroll
    for (int d4 = 0; d4 < 32; d4++) {
      float4 bb = *(const float4*)(br + d4 * 4);
      float4 ss = *(const float4*)(sl + d4 * 4);
      a += bb.x * ss.x + bb.y * ss.y + bb.z * ss.z + bb.w * ss.w;
    }
    sc = a * 0.08838834764831845f;  // 1/sqrt(128)
  }
  float mx = sc;
#pragma unroll
  for (int m = 1; m <= 32; m <<= 1) mx = fmaxf(mx, __shfl_xor(mx, m));
  if ((tid & 63) == 0) red1[tid >> 6] = mx;
  __syncthreads();
  mx = fmaxf(fmaxf(red1[0], red1[1]), fmaxf(red1[2], red1[3]));
  float p = (tid < KK) ? __expf(sc - mx) : 0.f;
  float sm = p;
#pragma unroll
  for (int m = 1; m <= 32; m <<= 1) sm += __shfl_xor(sm, m);
  if ((tid & 63) == 0) red2[tid >> 6] = sm;
  __syncthreads();
  sm = red2[0] + red2[1] + red2[2] + red2[3];
  if (tid < KK) ma[(size_t)bs * KK + tid] = p / sm;
}

// ---------------- final readout: h + LN(mem) -> head ------------------------
__global__ __launch_bounds__(256) void readout_kernel(const float* __restrict__ B,
    const float* __restrict__ ma, const float* __restrict__ task_q,
    const float* __restrict__ memg, const float* __restrict__ membt,
    const float* __restrict__ headW, const float* __restrict__ headb,
    float* __restrict__ out) {
  const int b = blockIdx.x, tid = threadIdx.x;
  __shared__ __align__(16) float tq[128];
  __shared__ float ras[KK];
  __shared__ float wc[KK];
  __shared__ float red1[4], red2[4];
  __shared__ float hv[128], mv[128], rv[128];
  __shared__ float stats[2];
  if (tid < 128) tq[tid] = task_q[tid];
  __syncthreads();
  float sc = -1e30f;
  if (tid < KK) {
    const float* br = B + (size_t)(b * KK + tid) * DDIM;
    float a = 0.f;
#pragma unroll
    for (int d4 = 0; d4 < 32; d4++) {
      float4 bb = *(const float4*)(br + d4 * 4);
      float4 ss = *(const float4*)(tq + d4 * 4);
      a += bb.x * ss.x + bb.y * ss.y + bb.z * ss.z + bb.w * ss.w;
    }
    sc = a * 0.08838834764831845f;
  }
  float mx = sc;
#pragma unroll
  for (int m = 1; m <= 32; m <<= 1) mx = fmaxf(mx, __shfl_xor(mx, m));
  if ((tid & 63) == 0) red1[tid >> 6] = mx;
  __syncthreads();
  mx = fmaxf(fmaxf(red1[0], red1[1]), fmaxf(red1[2], red1[3]));
  float p = (tid < KK) ? __expf(sc - mx) : 0.f;
  float sm = p;
#pragma unroll
  for (int m = 1; m <= 32; m <<= 1) sm += __shfl_xor(sm, m);
  if ((tid & 63) == 0) red2[tid >> 6] = sm;
  __syncthreads();
  sm = red2[0] + red2[1] + red2[2] + red2[3];
  if (tid < KK) {
    ras[tid] = p / sm;
    float a = 0.f;
    for (int s_ = 0; s_ < SSLOT; s_++) a += ma[((size_t)b * SSLOT + s_) * KK + tid];
    wc[tid] = a * (1.f / 64.f);
  }
  __syncthreads();
  if (tid < 128) {
    float hd = 0.f, md = 0.f;
    for (int c = 0; c < KK; c++) {
      float bv = B[(size_t)(b * KK + c) * DDIM + tid];
      hd = fmaf(ras[c], bv, hd);
      md = fmaf(wc[c], bv, md);
    }
    hv[tid] = hd; mv[tid] = md;
  }
  __syncthreads();
  if (tid < 64) {
    float x0 = mv[tid], x1 = mv[tid + 64];
    float s = x0 + x1, qq = x0 * x0 + x1 * x1;
#pragma unroll
    for (int m = 1; m <= 32; m <<= 1) { s += __shfl_xor(s, m); qq += __shfl_xor(qq, m); }
    if (tid == 0) { stats[0] = s; stats[1] = qq; }
  }
  __syncthreads();
  float mean = stats[0] * (1.f / 128.f);
  float var = stats[1] * (1.f / 128.f) - mean * mean;
  float rs = rsqrtf(var + 1e-5f);
  if (tid < 128) rv[tid] = hv[tid] + (mv[tid] - mean) * rs * memg[tid] + membt[tid];
  __syncthreads();
  if (tid < OUTN) {
    float a = headb[tid];
    for (int dd = 0; dd < 128; dd++) a = fmaf(rv[dd], headW[dd * OUTN + tid], a);
    out[b * OUTN + tid] = a;
  }
}

// ---------------------------------------------------------------------------
extern "C" void kernel_launch(void* const* d_in, const int* in_sizes, int n_in,
                              void* d_out, int out_size, void* d_ws, size_t ws_size,
                              hipStream_t stream) {
  (void)in_sizes; (void)n_in; (void)out_size; (void)ws_size;
  const float* x        = (const float*)d_in[0];
  const float* role_emb = (const float*)d_in[1];
  const float* filler_w = (const float*)d_in[2];
  const float* qW = (const float*)d_in[3];
  const float* qb = (const float*)d_in[4];
  const float* kW = (const float*)d_in[5];
  const float* kb = (const float*)d_in[6];
  const float* vW = (const float*)d_in[7];
  const float* vb = (const float*)d_in[8];
  const float* oW = (const float*)d_in[9];
  const float* ob = (const float*)d_in[10];
  const float* relW1 = (const float*)d_in[11];
  const float* relb1 = (const float*)d_in[12];
  const float* relW2 = (const float*)d_in[13];
  const float* relb2 = (const float*)d_in[14];
  const float* ln1g = (const float*)d_in[15];
  const float* ln1b = (const float*)d_in[16];
  const float* ln2g = (const float*)d_in[17];
  const float* ln2b = (const float*)d_in[18];
  const float* fW1 = (const float*)d_in[19];
  const float* fb1 = (const float*)d_in[20];
  const float* fW2 = (const float*)d_in[21];
  const float* fb2 = (const float*)d_in[22];
  const float* slots = (const float*)d_in[23];
  const float* memg = (const float*)d_in[24];
  const float* memb = (const float*)d_in[25];
  const float* taskq = (const float*)d_in[26];
  const float* headW = (const float*)d_in[27];
  const float* headb = (const float*)d_in[28];
  float* out = (float*)d_out;

  // workspace layout (float offsets; all 16B aligned)
  float* fws  = (float*)d_ws;
  int*   idxb = (int*)d_ws;              //   1600 ints
  float* vals = fws + 1600;              //   1600
  float* btok = fws + 3200;              // 204800
  float* qbuf = fws + 208000;            // 204800
  float* kbuf = fws + 412800;            // 204800
  float* vbuf = fws + 617600;            // 204800
  float* obuf = fws + 822400;            // 204800
  float* tmpb = fws + 1027200;           // 204800
  float* hbuf = fws + 1232000;           // 819200  (total ~8.2 MB)

  topk_kernel<<<8, 256, 0, stream>>>(x, vals, idxb);
  bind_kernel<<<800, 256, 0, stream>>>(vals, idxb, role_emb, filler_w, btok);
  for (int l = 0; l < LLAY; l++) {
    qkv_gemm<<<dim3(25, 2, 3), 256, 0, stream>>>(btok,
        qW + l * 16384, qb + l * 128, kW + l * 16384, kb + l * 128,
        vW + l * 16384, vb + l * 128, qbuf, kbuf, vbuf);
    rel_attn<<<dim3(16, 32), 256, 0, stream>>>(qbuf, kbuf, vbuf,
        relW1 + l * 3072, relb1 + l * 32, relW2 + l * 32, relb2 + l, obuf);
    gemm_bias<0><<<dim3(25, 2), 256, 0, stream>>>(obuf, oW + l * 16384, ob + l * 128, tmpb, 1600, 128, 128);
    res_ln<<<400, 256, 0, stream>>>(btok, tmpb, ln1g + l * 128, ln1b + l * 128);
    gemm_bias<1><<<dim3(25, 8), 256, 0, stream>>>(btok, fW1 + l * 65536, fb1 + l * 512, hbuf, 1600, 512, 128);
    gemm_bias<0><<<dim3(25, 2), 256, 0, stream>>>(hbuf, fW2 + l * 65536, fb2 + l * 128, tmpb, 1600, 128, 512);
    res_ln<<<400, 256, 0, stream>>>(btok, tmpb, ln2g + l * 128, ln2b + l * 128);
  }
  slot_ma<<<512, 256, 0, stream>>>(btok, slots, fws + 1027200);  // reuse tmpb region? no: mab below
  readout_kernel<<<8, 256, 0, stream>>>(btok, fws + 1027200, taskq, memg, memb, headW, headb, out);
}

// Round 3
// 442.441 us; speedup vs baseline: 1.6434x; 1.3698x over previous
//
#include <hip/hip_runtime.h>
#include <math.h>

#define BQ 8
#define CC 2048
#define DDIM 128
#define LLAY 3
#define HH 4
#define KK 200
#define SSLOT 64
#define OUTN 24
#define DH 32

typedef __bf16 bf16_t;
typedef __bf16 bf16x8 __attribute__((ext_vector_type(8)));
typedef float f32x4 __attribute__((ext_vector_type(4)));

__device__ __forceinline__ float fgelu(float x) {
  // tanh-approx gelu (abs err ~3e-4 in active range; feeds scores only)
  float u = 0.7978845608028654f * fmaf(0.044715f * x * x, x, x);
  float e = __expf(2.f * u);
  float t = 1.f - 2.f / (e + 1.f);
  return 0.5f * x * (1.f + t);
}
__device__ __forceinline__ float egelu(float x) {
  return 0.5f * x * (1.f + erff(x * 0.7071067811865476f));
}

// ---------------- top-k over 2048 per row (binary search on float bits) ----
__global__ __launch_bounds__(256) void topk_kernel(const float* __restrict__ x,
                                                   float* __restrict__ vals,
                                                   int* __restrict__ idx) {
  const int b = blockIdx.x, tid = threadIdx.x;
  float xv[8]; unsigned xb[8];
#pragma unroll
  for (int t = 0; t < 8; t++) {
    float v = x[b * CC + t * 256 + tid];
    xv[t] = v;
    xb[t] = __float_as_uint(v);
  }
  __shared__ int red[4];
  __shared__ int cnt;
  unsigned lo = 0u, hi = 0x7f800000u;
  while (lo < hi) {
    unsigned mid = (lo + hi) >> 1;
    int c = 0;
#pragma unroll
    for (int t = 0; t < 8; t++) c += (xb[t] > mid) ? 1 : 0;
#pragma unroll
    for (int m = 1; m <= 32; m <<= 1) c += __shfl_xor(c, m);
    if ((tid & 63) == 0) red[tid >> 6] = c;
    __syncthreads();
    int ct = red[0] + red[1] + red[2] + red[3];
    __syncthreads();
    if (ct >= KK) lo = mid + 1; else hi = mid;
  }
  const unsigned thr = lo;
  if (tid == 0) cnt = 0;
  __syncthreads();
#pragma unroll
  for (int t = 0; t < 8; t++) {
    if (xb[t] > thr) {
      int p = atomicAdd(&cnt, 1);
      vals[b * KK + p] = log1pf(xv[t]);
      idx[b * KK + p] = t * 256 + tid;
    }
  }
  __syncthreads();
#pragma unroll
  for (int t = 0; t < 8; t++) {
    if (xb[t] == thr) {
      int p = atomicAdd(&cnt, 1);
      if (p < KK) {
        vals[b * KK + p] = log1pf(xv[t]);
        idx[b * KK + p] = t * 256 + tid;
      }
    }
  }
}

// ---------------- b = role_emb[idx] * gelu(val * filler_w) -----------------
__global__ __launch_bounds__(256) void bind_kernel(const float* __restrict__ vals,
    const int* __restrict__ idx, const float* __restrict__ role_emb,
    const float* __restrict__ fw, float* __restrict__ btok) {
  int u = blockIdx.x * 256 + threadIdx.x;  // < 204800
  int dd = u & 127;
  int r = u >> 7;
  int b = r / KK, t = r - b * KK;
  float v = vals[b * KK + t];
  float fill = egelu(v * fw[dd]);
  btok[u] = role_emb[(size_t)idx[b * KK + t] * DDIM + dd] * fill;
}

// ---------------- generic tiled fp32 GEMM: C = act(A@W + bias) -------------
template <int ACT>
__global__ __launch_bounds__(256) void gemm_bias(const float* __restrict__ A,
    const float* __restrict__ W, const float* __restrict__ bias,
    float* __restrict__ C, int M, int N, int K) {
  __shared__ __align__(16) float As[16][68];
  __shared__ __align__(16) float Ws[16][68];
  const int tid = threadIdx.x;
  const int tx = tid & 15, ty = tid >> 4;
  const int m0 = blockIdx.x * 64, n0 = blockIdx.y * 64;
  float acc[4][4];
#pragma unroll
  for (int i = 0; i < 4; i++)
#pragma unroll
    for (int j = 0; j < 4; j++) acc[i][j] = 0.f;
  const int lm = tid >> 2, lk4 = (tid & 3) * 4;
  const int ln = tid & 63, lkq = tid >> 6;
  for (int k0 = 0; k0 < K; k0 += 16) {
    float4 a4 = *(const float4*)(A + (size_t)(m0 + lm) * K + k0 + lk4);
    As[lk4 + 0][lm] = a4.x; As[lk4 + 1][lm] = a4.y;
    As[lk4 + 2][lm] = a4.z; As[lk4 + 3][lm] = a4.w;
#pragma unroll
    for (int r = 0; r < 4; r++)
      Ws[lkq * 4 + r][ln] = W[(size_t)(k0 + lkq * 4 + r) * N + n0 + ln];
    __syncthreads();
#pragma unroll
    for (int kk = 0; kk < 16; kk++) {
      const float4 a = *(const float4*)&As[kk][ty * 4];
      const float4 w = *(const float4*)&Ws[kk][tx * 4];
      const float av[4] = {a.x, a.y, a.z, a.w};
      const float wv[4] = {w.x, w.y, w.z, w.w};
#pragma unroll
      for (int i = 0; i < 4; i++)
#pragma unroll
        for (int j = 0; j < 4; j++) acc[i][j] = fmaf(av[i], wv[j], acc[i][j]);
    }
    __syncthreads();
  }
  const float b0 = bias[n0 + tx * 4 + 0];
  const float b1 = bias[n0 + tx * 4 + 1];
  const float b2 = bias[n0 + tx * 4 + 2];
  const float b3 = bias[n0 + tx * 4 + 3];
#pragma unroll
  for (int i = 0; i < 4; i++) {
    float4 r;
    r.x = acc[i][0] + b0; r.y = acc[i][1] + b1;
    r.z = acc[i][2] + b2; r.w = acc[i][3] + b3;
    if (ACT == 1) { r.x = egelu(r.x); r.y = egelu(r.y); r.z = egelu(r.z); r.w = egelu(r.w); }
    *(float4*)(C + (size_t)(m0 + ty * 4 + i) * N + n0 + tx * 4) = r;
  }
}

// ---------------- batched QKV GEMM (z selects q/k/v), M=1600 N=128 K=128 ---
__global__ __launch_bounds__(256) void qkv_gemm(const float* __restrict__ A,
    const float* __restrict__ qW, const float* __restrict__ qb,
    const float* __restrict__ kW, const float* __restrict__ kb,
    const float* __restrict__ vW, const float* __restrict__ vb,
    float* __restrict__ qo, float* __restrict__ ko, float* __restrict__ vo) {
  const float* W; const float* bias; float* C;
  if (blockIdx.z == 0) { W = qW; bias = qb; C = qo; }
  else if (blockIdx.z == 1) { W = kW; bias = kb; C = ko; }
  else { W = vW; bias = vb; C = vo; }
  __shared__ __align__(16) float As[16][68];
  __shared__ __align__(16) float Ws[16][68];
  const int tid = threadIdx.x;
  const int tx = tid & 15, ty = tid >> 4;
  const int m0 = blockIdx.x * 64, n0 = blockIdx.y * 64;
  float acc[4][4];
#pragma unroll
  for (int i = 0; i < 4; i++)
#pragma unroll
    for (int j = 0; j < 4; j++) acc[i][j] = 0.f;
  const int lm = tid >> 2, lk4 = (tid & 3) * 4;
  const int ln = tid & 63, lkq = tid >> 6;
  for (int k0 = 0; k0 < 128; k0 += 16) {
    float4 a4 = *(const float4*)(A + (size_t)(m0 + lm) * 128 + k0 + lk4);
    As[lk4 + 0][lm] = a4.x; As[lk4 + 1][lm] = a4.y;
    As[lk4 + 2][lm] = a4.z; As[lk4 + 3][lm] = a4.w;
#pragma unroll
    for (int r = 0; r < 4; r++)
      Ws[lkq * 4 + r][ln] = W[(size_t)(k0 + lkq * 4 + r) * 128 + n0 + ln];
    __syncthreads();
#pragma unroll
    for (int kk = 0; kk < 16; kk++) {
      const float4 a = *(const float4*)&As[kk][ty * 4];
      const float4 w = *(const float4*)&Ws[kk][tx * 4];
      const float av[4] = {a.x, a.y, a.z, a.w};
      const float wv[4] = {w.x, w.y, w.z, w.w};
#pragma unroll
      for (int i = 0; i < 4; i++)
#pragma unroll
        for (int j = 0; j < 4; j++) acc[i][j] = fmaf(av[i], wv[j], acc[i][j]);
    }
    __syncthreads();
  }
  const float b0 = bias[n0 + tx * 4 + 0];
  const float b1 = bias[n0 + tx * 4 + 1];
  const float b2 = bias[n0 + tx * 4 + 2];
  const float b3 = bias[n0 + tx * 4 + 3];
#pragma unroll
  for (int i = 0; i < 4; i++) {
    float4 r;
    r.x = acc[i][0] + b0; r.y = acc[i][1] + b1;
    r.z = acc[i][2] + b2; r.w = acc[i][3] + b3;
    *(float4*)(C + (size_t)(m0 + ty * 4 + i) * 128 + n0 + tx * 4) = r;
  }
}

// ---------------- fused relational attention v3: MFMA bilinear -------------
// Per i: Weff[e,f] = q_i[e]*W1i[e,f] + W1k[e,f] (bf16 B-frag in regs)
// arg[j,f] = qtv_i[f] + (K @ Weff)[j,f]  via mfma_f32_16x16x32_bf16
// s[j] = sum_f gelu(arg)*w2f  (w2f = w2/sqrt(32); rb2 drops by shift-invar.)
// o[i,:] = softmax_j(s) @ V   via MFMA (P bf16 in LDS, V^T bf16 in LDS)
__global__ __launch_bounds__(256, 2) void rel_attn_mfma(
    const float* __restrict__ q, const float* __restrict__ k, const float* __restrict__ v,
    const float* __restrict__ W1g, const float* __restrict__ b1g,
    const float* __restrict__ w2p, float* __restrict__ o) {
  __shared__ __align__(16) bf16_t ksh[208 * 32];   // K bf16, row-major, 16B-block swizz
  __shared__ __align__(16) bf16_t vtsh[32 * 232];  // V^T bf16 [f'][j], stride 232
  __shared__ __align__(16) bf16_t psh[16 * 232];   // P bf16 [i_local][j], stride 232
  __shared__ float W1sh[96 * 33];                  // W1 f32 rows e: q|k|i, stride 33
  __shared__ __align__(16) float qsh[16 * 32];     // q rows f32
  __shared__ float qtsh[16 * 32];                  // qtv = q@W1q + b1
  const int tid = threadIdx.x;
  const int bh = blockIdx.y, bb = bh >> 2, h = bh & 3;
  const int i0 = blockIdx.x * 16;
  const float* kg = k + (size_t)(bb * KK) * DDIM + h * DH;
  const float* vg = v + (size_t)(bb * KK) * DDIM + h * DH;
  const float* qg = q + (size_t)(bb * KK) * DDIM + h * DH;
  // ---- stage K (bf16, swizzled: 16B block ^= (j>>1)&3) ----
#pragma unroll
  for (int it = 0; it < 13; ++it) {
    int u = tid + it * 256;                 // < 3328 = 208 j * 16 e-pairs
    int j = u >> 4, ep = u & 15;
    float a0 = 0.f, a1 = 0.f;
    if (j < KK) { float2 t2 = *(const float2*)(kg + (size_t)j * DDIM + 2 * ep); a0 = t2.x; a1 = t2.y; }
    int sb = (ep >> 2) ^ ((j >> 1) & 3);
    union { bf16_t h2[2]; unsigned uu; } pk;
    pk.h2[0] = (bf16_t)a0; pk.h2[1] = (bf16_t)a1;
    *(unsigned*)&ksh[j * 32 + sb * 8 + (ep & 3) * 2] = pk.uu;
  }
  // ---- stage V^T (bf16) ----
#pragma unroll
  for (int it = 0; it < 13; ++it) {
    int u = tid + it * 256;                 // < 3328 = 104 j-pairs * 32 f
    int jp = u >> 5, f = u & 31;
    int j0 = jp * 2;
    float a0 = (j0 < KK) ? vg[(size_t)j0 * DDIM + f] : 0.f;
    float a1 = (j0 + 1 < KK) ? vg[(size_t)(j0 + 1) * DDIM + f] : 0.f;
    union { bf16_t h2[2]; unsigned uu; } pk;
    pk.h2[0] = (bf16_t)a0; pk.h2[1] = (bf16_t)a1;
    *(unsigned*)&vtsh[f * 232 + j0] = pk.uu;
  }
  // ---- zero pads: vtsh cols 208..223, psh cols 208..223 ----
  if (tid < 256) {                          // vtsh: 32 f * 8 pairs
    int f = tid >> 3, cp = tid & 7;
    *(unsigned*)&vtsh[f * 232 + 208 + cp * 2] = 0u;
  }
  if (tid < 128) {                          // psh: 16 rows * 8 pairs
    int r = tid >> 3, cp = tid & 7;
    *(unsigned*)&psh[r * 232 + 208 + cp * 2] = 0u;
  }
  // ---- stage W1 (f32) and q rows (f32) ----
#pragma unroll
  for (int it = 0; it < 12; ++it) {
    int u = tid + it * 256;                 // < 3072
    W1sh[(u >> 5) * 33 + (u & 31)] = W1g[u];
  }
#pragma unroll
  for (int it = 0; it < 2; ++it) {
    int u = tid + it * 256;                 // < 512
    int il = u >> 5, e = u & 31;
    int i = i0 + il;
    qsh[il * 32 + e] = (i < KK) ? qg[(size_t)i * DDIM + e] : 0.f;
  }
  __syncthreads();
  // ---- qtv = q @ W1q + b1 ----
#pragma unroll
  for (int it = 0; it < 2; ++it) {
    int u = tid + it * 256;
    int il = u >> 5, f = u & 31;
    float a = b1g[f];
#pragma unroll
    for (int e = 0; e < 32; ++e) a = fmaf(qsh[il * 32 + e], W1sh[e * 33 + f], a);
    qtsh[il * 32 + f] = a;
  }
  __syncthreads();
  const int w = tid >> 6, lane = tid & 63;
  const int fcol = lane & 15, g = lane >> 4;
  const float w2v0 = w2p[fcol] * 0.17677669529663687f;
  const float w2v1 = w2p[fcol + 16] * 0.17677669529663687f;
  for (int c = 0; c < 4; ++c) {
    const int il = w * 4 + c, i = i0 + il;
    if (i < KK) {  // wave-uniform
      const float4 qa = *(const float4*)&qsh[il * 32 + g * 8];
      const float4 qb = *(const float4*)&qsh[il * 32 + g * 8 + 4];
      const float qv[8] = {qa.x, qa.y, qa.z, qa.w, qb.x, qb.y, qb.z, qb.w};
      bf16x8 bw0, bw1;
#pragma unroll
      for (int e8 = 0; e8 < 8; ++e8) {
        int e = g * 8 + e8;
        bw0[e8] = (bf16_t)fmaf(qv[e8], W1sh[(64 + e) * 33 + fcol], W1sh[(32 + e) * 33 + fcol]);
        bw1[e8] = (bf16_t)fmaf(qv[e8], W1sh[(64 + e) * 33 + fcol + 16], W1sh[(32 + e) * 33 + fcol + 16]);
      }
      const float qtv0 = qtsh[il * 32 + fcol];
      const float qtv1 = qtsh[il * 32 + fcol + 16];
      float s[13][4];
#pragma unroll
      for (int jt = 0; jt < 13; ++jt) {
        int j = jt * 16 + fcol;
        bf16x8 af = *(const bf16x8*)&ksh[j * 32 + (g ^ ((j >> 1) & 3)) * 8];
        f32x4 acc0 = {0.f, 0.f, 0.f, 0.f}, acc1 = {0.f, 0.f, 0.f, 0.f};
        acc0 = __builtin_amdgcn_mfma_f32_16x16x32_bf16(af, bw0, acc0, 0, 0, 0);
        acc1 = __builtin_amdgcn_mfma_f32_16x16x32_bf16(af, bw1, acc1, 0, 0, 0);
#pragma unroll
        for (int r = 0; r < 4; ++r) {
          float sp = fgelu(acc0[r] + qtv0) * w2v0 + fgelu(acc1[r] + qtv1) * w2v1;
          sp += __shfl_xor(sp, 1);
          sp += __shfl_xor(sp, 2);
          sp += __shfl_xor(sp, 4);
          sp += __shfl_xor(sp, 8);
          if (jt == 12 && (g * 4 + r) >= 8) sp = -1e30f;  // j >= 200 mask
          s[jt][r] = sp;
        }
      }
      // ---- softmax over 208 rows (rows live at g-group, dup over fcol) ----
      float m = -1e30f;
#pragma unroll
      for (int jt = 0; jt < 13; ++jt)
#pragma unroll
        for (int r = 0; r < 4; ++r) m = fmaxf(m, s[jt][r]);
      m = fmaxf(m, __shfl_xor(m, 16));
      m = fmaxf(m, __shfl_xor(m, 32));
      float lsum = 0.f;
#pragma unroll
      for (int jt = 0; jt < 13; ++jt)
#pragma unroll
        for (int r = 0; r < 4; ++r) {
          float p = __expf(s[jt][r] - m);
          s[jt][r] = p;
          lsum += p;
        }
      lsum += __shfl_xor(lsum, 16);
      lsum += __shfl_xor(lsum, 32);
      const float inv = 1.f / lsum;
      if (fcol == 0) {
#pragma unroll
        for (int jt = 0; jt < 13; ++jt) {
          union { bf16_t h4[4]; unsigned long long u8; } p4;
#pragma unroll
          for (int r = 0; r < 4; ++r) p4.h4[r] = (bf16_t)(s[jt][r] * inv);
          *(unsigned long long*)&psh[il * 232 + jt * 16 + g * 4] = p4.u8;
        }
      }
    }
  }
  __syncthreads();
  // ---- PV: O[16 i, 32 f'] = P[16,224] @ V[224,32]; waves 0,1 = f'-tiles ----
  if (w < 2) {
    f32x4 acc = {0.f, 0.f, 0.f, 0.f};
#pragma unroll
    for (int ks = 0; ks < 7; ++ks) {
      bf16x8 ap = *(const bf16x8*)&psh[fcol * 232 + ks * 32 + g * 8];
      bf16x8 bv = *(const bf16x8*)&vtsh[(w * 16 + fcol) * 232 + ks * 32 + g * 8];
      acc = __builtin_amdgcn_mfma_f32_16x16x32_bf16(ap, bv, acc, 0, 0, 0);
    }
#pragma unroll
    for (int r = 0; r < 4; ++r) {
      int i = i0 + g * 4 + r;
      if (i < KK) o[(size_t)(bb * KK + i) * DDIM + h * DH + w * 16 + fcol] = acc[r];
    }
  }
}

// ---------------- residual + LayerNorm (wave per token) --------------------
__global__ __launch_bounds__(256) void res_ln(float* __restrict__ B,
    const float* __restrict__ add, const float* __restrict__ g,
    const float* __restrict__ bt) {
  int tok = blockIdx.x * 4 + (threadIdx.x >> 6);
  int ln = threadIdx.x & 63;
  float* row = B + (size_t)tok * DDIM;
  const float* ar = add + (size_t)tok * DDIM;
  float x0 = row[ln] + ar[ln];
  float x1 = row[ln + 64] + ar[ln + 64];
  float s = x0 + x1;
#pragma unroll
  for (int m = 1; m <= 32; m <<= 1) s += __shfl_xor(s, m);
  float mean = s * (1.f / 128.f);
  float d0 = x0 - mean, d1 = x1 - mean;
  float qq = d0 * d0 + d1 * d1;
#pragma unroll
  for (int m = 1; m <= 32; m <<= 1) qq += __shfl_xor(qq, m);
  float rs = rsqrtf(qq * (1.f / 128.f) + 1e-5f);
  row[ln] = d0 * rs * g[ln] + bt[ln];
  row[ln + 64] = d1 * rs * g[ln + 64] + bt[ln + 64];
}

// ---------------- memory-slot attention rows: ma[b,s,c] --------------------
__global__ __launch_bounds__(256) void slot_ma(const float* __restrict__ B,
    const float* __restrict__ slots, float* __restrict__ ma) {
  const int bs = blockIdx.x;  // b*64+s
  const int s = bs & 63;
  const int b = bs >> 6;
  const int tid = threadIdx.x;
  __shared__ __align__(16) float sl[128];
  __shared__ float red1[4], red2[4];
  if (tid < 128) sl[tid] = slots[(size_t)s * DDIM + tid];
  __syncthreads();
  float sc = -1e30f;
  if (tid < KK) {
    const float* br = B + (size_t)(b * KK + tid) * DDIM;
    float a = 0.f;
#pragma unroll
    for (int d4 = 0; d4 < 32; d4++) {
      float4 bb = *(const float4*)(br + d4 * 4);
      float4 ss = *(const float4*)(sl + d4 * 4);
      a += bb.x * ss.x + bb.y * ss.y + bb.z * ss.z + bb.w * ss.w;
    }
    sc = a * 0.08838834764831845f;  // 1/sqrt(128)
  }
  float mx = sc;
#pragma unroll
  for (int m = 1; m <= 32; m <<= 1) mx = fmaxf(mx, __shfl_xor(mx, m));
  if ((tid & 63) == 0) red1[tid >> 6] = mx;
  __syncthreads();
  mx = fmaxf(fmaxf(red1[0], red1[1]), fmaxf(red1[2], red1[3]));
  float p = (tid < KK) ? __expf(sc - mx) : 0.f;
  float sm = p;
#pragma unroll
  for (int m = 1; m <= 32; m <<= 1) sm += __shfl_xor(sm, m);
  if ((tid & 63) == 0) red2[tid >> 6] = sm;
  __syncthreads();
  sm = red2[0] + red2[1] + red2[2] + red2[3];
  if (tid < KK) ma[(size_t)bs * KK + tid] = p / sm;
}

// ---------------- final readout: h + LN(mem) -> head ------------------------
__global__ __launch_bounds__(256) void readout_kernel(const float* __restrict__ B,
    const float* __restrict__ ma, const float* __restrict__ task_q,
    const float* __restrict__ memg, const float* __restrict__ membt,
    const float* __restrict__ headW, const float* __restrict__ headb,
    float* __restrict__ out) {
  const int b = blockIdx.x, tid = threadIdx.x;
  __shared__ __align__(16) float tq[128];
  __shared__ float ras[KK];
  __shared__ float wc[KK];
  __shared__ float red1[4], red2[4];
  __shared__ float hv[128], mv[128], rv[128];
  __shared__ float stats[2];
  if (tid < 128) tq[tid] = task_q[tid];
  __syncthreads();
  float sc = -1e30f;
  if (tid < KK) {
    const float* br = B + (size_t)(b * KK + tid) * DDIM;
    float a = 0.f;
#pragma unroll
    for (int d4 = 0; d4 < 32; d4++) {
      float4 bb = *(const float4*)(br + d4 * 4);
      float4 ss = *(const float4*)(tq + d4 * 4);
      a += bb.x * ss.x + bb.y * ss.y + bb.z * ss.z + bb.w * ss.w;
    }
    sc = a * 0.08838834764831845f;
  }
  float mx = sc;
#pragma unroll
  for (int m = 1; m <= 32; m <<= 1) mx = fmaxf(mx, __shfl_xor(mx, m));
  if ((tid & 63) == 0) red1[tid >> 6] = mx;
  __syncthreads();
  mx = fmaxf(fmaxf(red1[0], red1[1]), fmaxf(red1[2], red1[3]));
  float p = (tid < KK) ? __expf(sc - mx) : 0.f;
  float sm = p;
#pragma unroll
  for (int m = 1; m <= 32; m <<= 1) sm += __shfl_xor(sm, m);
  if ((tid & 63) == 0) red2[tid >> 6] = sm;
  __syncthreads();
  sm = red2[0] + red2[1] + red2[2] + red2[3];
  if (tid < KK) {
    ras[tid] = p / sm;
    float a = 0.f;
    for (int s_ = 0; s_ < SSLOT; s_++) a += ma[((size_t)b * SSLOT + s_) * KK + tid];
    wc[tid] = a * (1.f / 64.f);
  }
  __syncthreads();
  if (tid < 128) {
    float hd = 0.f, md = 0.f;
    for (int c = 0; c < KK; c++) {
      float bv = B[(size_t)(b * KK + c) * DDIM + tid];
      hd = fmaf(ras[c], bv, hd);
      md = fmaf(wc[c], bv, md);
    }
    hv[tid] = hd; mv[tid] = md;
  }
  __syncthreads();
  if (tid < 64) {
    float x0 = mv[tid], x1 = mv[tid + 64];
    float s = x0 + x1, qq = x0 * x0 + x1 * x1;
#pragma unroll
    for (int m = 1; m <= 32; m <<= 1) { s += __shfl_xor(s, m); qq += __shfl_xor(qq, m); }
    if (tid == 0) { stats[0] = s; stats[1] = qq; }
  }
  __syncthreads();
  float mean = stats[0] * (1.f / 128.f);
  float var = stats[1] * (1.f / 128.f) - mean * mean;
  float rs = rsqrtf(var + 1e-5f);
  if (tid < 128) rv[tid] = hv[tid] + (mv[tid] - mean) * rs * memg[tid] + membt[tid];
  __syncthreads();
  if (tid < OUTN) {
    float a = headb[tid];
    for (int dd = 0; dd < 128; dd++) a = fmaf(rv[dd], headW[dd * OUTN + tid], a);
    out[b * OUTN + tid] = a;
  }
}

// ---------------------------------------------------------------------------
extern "C" void kernel_launch(void* const* d_in, const int* in_sizes, int n_in,
                              void* d_out, int out_size, void* d_ws, size_t ws_size,
                              hipStream_t stream) {
  (void)in_sizes; (void)n_in; (void)out_size; (void)ws_size;
  const float* x        = (const float*)d_in[0];
  const float* role_emb = (const float*)d_in[1];
  const float* filler_w = (const float*)d_in[2];
  const float* qW = (const float*)d_in[3];
  const float* qb = (const float*)d_in[4];
  const float* kW = (const float*)d_in[5];
  const float* kb = (const float*)d_in[6];
  const float* vW = (const float*)d_in[7];
  const float* vb = (const float*)d_in[8];
  const float* oW = (const float*)d_in[9];
  const float* ob = (const float*)d_in[10];
  const float* relW1 = (const float*)d_in[11];
  const float* relb1 = (const float*)d_in[12];
  const float* relW2 = (const float*)d_in[13];
  const float* relb2 = (const float*)d_in[14];
  const float* ln1g = (const float*)d_in[15];
  const float* ln1b = (const float*)d_in[16];
  const float* ln2g = (const float*)d_in[17];
  const float* ln2b = (const float*)d_in[18];
  const float* fW1 = (const float*)d_in[19];
  const float* fb1 = (const float*)d_in[20];
  const float* fW2 = (const float*)d_in[21];
  const float* fb2 = (const float*)d_in[22];
  const float* slots = (const float*)d_in[23];
  const float* memg = (const float*)d_in[24];
  const float* memb = (const float*)d_in[25];
  const float* taskq = (const float*)d_in[26];
  const float* headW = (const float*)d_in[27];
  const float* headb = (const float*)d_in[28];
  float* out = (float*)d_out;
  (void)relb2;  // dropped: softmax shift-invariance

  // workspace layout (float offsets; all 16B aligned)
  float* fws  = (float*)d_ws;
  int*   idxb = (int*)d_ws;              //   1600 ints
  float* vals = fws + 1600;              //   1600
  float* btok = fws + 3200;              // 204800
  float* qbuf = fws + 208000;            // 204800
  float* kbuf = fws + 412800;            // 204800
  float* vbuf = fws + 617600;            // 204800
  float* obuf = fws + 822400;            // 204800
  float* tmpb = fws + 1027200;           // 204800
  float* hbuf = fws + 1232000;           // 819200
  float* mab  = fws + 2051200;           // 102400  (total ~8.6 MB)

  topk_kernel<<<8, 256, 0, stream>>>(x, vals, idxb);
  bind_kernel<<<800, 256, 0, stream>>>(vals, idxb, role_emb, filler_w, btok);
  for (int l = 0; l < LLAY; l++) {
    qkv_gemm<<<dim3(25, 2, 3), 256, 0, stream>>>(btok,
        qW + l * 16384, qb + l * 128, kW + l * 16384, kb + l * 128,
        vW + l * 16384, vb + l * 128, qbuf, kbuf, vbuf);
    rel_attn_mfma<<<dim3(13, 32), 256, 0, stream>>>(qbuf, kbuf, vbuf,
        relW1 + l * 3072, relb1 + l * 32, relW2 + l * 32, obuf);
    gemm_bias<0><<<dim3(25, 2), 256, 0, stream>>>(obuf, oW + l * 16384, ob + l * 128, tmpb, 1600, 128, 128);
    res_ln<<<400, 256, 0, stream>>>(btok, tmpb, ln1g + l * 128, ln1b + l * 128);
    gemm_bias<1><<<dim3(25, 8), 256, 0, stream>>>(btok, fW1 + l * 65536, fb1 + l * 512, hbuf, 1600, 512, 128);
    gemm_bias<0><<<dim3(25, 2), 256, 0, stream>>>(hbuf, fW2 + l * 65536, fb2 + l * 128, tmpb, 1600, 128, 512);
    res_ln<<<400, 256, 0, stream>>>(btok, tmpb, ln2g + l * 128, ln2b + l * 128);
  }
  slot_ma<<<512, 256, 0, stream>>>(btok, slots, mab);
  readout_kernel<<<8, 256, 0, stream>>>(btok, mab, taskq, memg, memb, headW, headb, out);
}

// Round 4
// 421.713 us; speedup vs baseline: 1.7242x; 1.0492x over previous
//
#include <hip/hip_runtime.h>
#include <math.h>

#define BQ 8
#define CC 2048
#define DDIM 128
#define LLAY 3
#define HH 4
#define KK 200
#define SSLOT 64
#define OUTN 24
#define DH 32

typedef __bf16 bf16_t;
typedef __bf16 bf16x8 __attribute__((ext_vector_type(8)));
typedef float f32x4 __attribute__((ext_vector_type(4)));

__device__ __forceinline__ float fgelu2(float x) {
  // tanh-approx gelu via exp2; x*sig(2*0.79788*(x+0.044715x^3))
  float xc = fminf(x, 8.f);  // overflow guard (gelu(x>8)==x to fp32)
  float inner = fmaf(0.044715f * xc * xc, xc, xc);
  float e = exp2f(inner * 2.302118610509359f);  // 2*0.79788456*log2(e)
  return x * e * __frcp_rn(1.f + e);
}
__device__ __forceinline__ float egelu(float x) {
  return 0.5f * x * (1.f + erff(x * 0.7071067811865476f));
}

// ---------------- top-k over 2048 per row (binary search on float bits) ----
__global__ __launch_bounds__(256) void topk_kernel(const float* __restrict__ x,
                                                   float* __restrict__ vals,
                                                   int* __restrict__ idx) {
  const int b = blockIdx.x, tid = threadIdx.x;
  float xv[8]; unsigned xb[8];
#pragma unroll
  for (int t = 0; t < 8; t++) {
    float v = x[b * CC + t * 256 + tid];
    xv[t] = v;
    xb[t] = __float_as_uint(v);
  }
  __shared__ int red[4];
  __shared__ int cnt;
  unsigned lo = 0u, hi = 0x7f800000u;
  while (lo < hi) {
    unsigned mid = (lo + hi) >> 1;
    int c = 0;
#pragma unroll
    for (int t = 0; t < 8; t++) c += (xb[t] > mid) ? 1 : 0;
#pragma unroll
    for (int m = 1; m <= 32; m <<= 1) c += __shfl_xor(c, m);
    if ((tid & 63) == 0) red[tid >> 6] = c;
    __syncthreads();
    int ct = red[0] + red[1] + red[2] + red[3];
    __syncthreads();
    if (ct >= KK) lo = mid + 1; else hi = mid;
  }
  const unsigned thr = lo;
  if (tid == 0) cnt = 0;
  __syncthreads();
#pragma unroll
  for (int t = 0; t < 8; t++) {
    if (xb[t] > thr) {
      int p = atomicAdd(&cnt, 1);
      vals[b * KK + p] = log1pf(xv[t]);
      idx[b * KK + p] = t * 256 + tid;
    }
  }
  __syncthreads();
#pragma unroll
  for (int t = 0; t < 8; t++) {
    if (xb[t] == thr) {
      int p = atomicAdd(&cnt, 1);
      if (p < KK) {
        vals[b * KK + p] = log1pf(xv[t]);
        idx[b * KK + p] = t * 256 + tid;
      }
    }
  }
}

// ---------------- b = role_emb[idx] * gelu(val * filler_w) -----------------
__global__ __launch_bounds__(256) void bind_kernel(const float* __restrict__ vals,
    const int* __restrict__ idx, const float* __restrict__ role_emb,
    const float* __restrict__ fw, float* __restrict__ btok) {
  int u = blockIdx.x * 256 + threadIdx.x;  // < 204800
  int dd = u & 127;
  int r = u >> 7;
  int b = r / KK, t = r - b * KK;
  float v = vals[b * KK + t];
  float fill = egelu(v * fw[dd]);
  btok[u] = role_emb[(size_t)idx[b * KK + t] * DDIM + dd] * fill;
}

// ---------------- generic tiled fp32 GEMM: C = act(A@W + bias) -------------
template <int ACT>
__global__ __launch_bounds__(256) void gemm_bias(const float* __restrict__ A,
    const float* __restrict__ W, const float* __restrict__ bias,
    float* __restrict__ C, int M, int N, int K) {
  __shared__ __align__(16) float As[16][68];
  __shared__ __align__(16) float Ws[16][68];
  const int tid = threadIdx.x;
  const int tx = tid & 15, ty = tid >> 4;
  const int m0 = blockIdx.x * 64, n0 = blockIdx.y * 64;
  float acc[4][4];
#pragma unroll
  for (int i = 0; i < 4; i++)
#pragma unroll
    for (int j = 0; j < 4; j++) acc[i][j] = 0.f;
  const int lm = tid >> 2, lk4 = (tid & 3) * 4;
  const int ln = tid & 63, lkq = tid >> 6;
  for (int k0 = 0; k0 < K; k0 += 16) {
    float4 a4 = *(const float4*)(A + (size_t)(m0 + lm) * K + k0 + lk4);
    As[lk4 + 0][lm] = a4.x; As[lk4 + 1][lm] = a4.y;
    As[lk4 + 2][lm] = a4.z; As[lk4 + 3][lm] = a4.w;
#pragma unroll
    for (int r = 0; r < 4; r++)
      Ws[lkq * 4 + r][ln] = W[(size_t)(k0 + lkq * 4 + r) * N + n0 + ln];
    __syncthreads();
#pragma unroll
    for (int kk = 0; kk < 16; kk++) {
      const float4 a = *(const float4*)&As[kk][ty * 4];
      const float4 w = *(const float4*)&Ws[kk][tx * 4];
      const float av[4] = {a.x, a.y, a.z, a.w};
      const float wv[4] = {w.x, w.y, w.z, w.w};
#pragma unroll
      for (int i = 0; i < 4; i++)
#pragma unroll
        for (int j = 0; j < 4; j++) acc[i][j] = fmaf(av[i], wv[j], acc[i][j]);
    }
    __syncthreads();
  }
  const float b0 = bias[n0 + tx * 4 + 0];
  const float b1 = bias[n0 + tx * 4 + 1];
  const float b2 = bias[n0 + tx * 4 + 2];
  const float b3 = bias[n0 + tx * 4 + 3];
#pragma unroll
  for (int i = 0; i < 4; i++) {
    float4 r;
    r.x = acc[i][0] + b0; r.y = acc[i][1] + b1;
    r.z = acc[i][2] + b2; r.w = acc[i][3] + b3;
    if (ACT == 1) { r.x = egelu(r.x); r.y = egelu(r.y); r.z = egelu(r.z); r.w = egelu(r.w); }
    *(float4*)(C + (size_t)(m0 + ty * 4 + i) * N + n0 + tx * 4) = r;
  }
}

// ---------------- batched QKV GEMM (z selects q/k/v), M=1600 N=128 K=128 ---
__global__ __launch_bounds__(256) void qkv_gemm(const float* __restrict__ A,
    const float* __restrict__ qW, const float* __restrict__ qb,
    const float* __restrict__ kW, const float* __restrict__ kb,
    const float* __restrict__ vW, const float* __restrict__ vb,
    float* __restrict__ qo, float* __restrict__ ko, float* __restrict__ vo) {
  const float* W; const float* bias; float* C;
  if (blockIdx.z == 0) { W = qW; bias = qb; C = qo; }
  else if (blockIdx.z == 1) { W = kW; bias = kb; C = ko; }
  else { W = vW; bias = vb; C = vo; }
  __shared__ __align__(16) float As[16][68];
  __shared__ __align__(16) float Ws[16][68];
  const int tid = threadIdx.x;
  const int tx = tid & 15, ty = tid >> 4;
  const int m0 = blockIdx.x * 64, n0 = blockIdx.y * 64;
  float acc[4][4];
#pragma unroll
  for (int i = 0; i < 4; i++)
#pragma unroll
    for (int j = 0; j < 4; j++) acc[i][j] = 0.f;
  const int lm = tid >> 2, lk4 = (tid & 3) * 4;
  const int ln = tid & 63, lkq = tid >> 6;
  for (int k0 = 0; k0 < 128; k0 += 16) {
    float4 a4 = *(const float4*)(A + (size_t)(m0 + lm) * 128 + k0 + lk4);
    As[lk4 + 0][lm] = a4.x; As[lk4 + 1][lm] = a4.y;
    As[lk4 + 2][lm] = a4.z; As[lk4 + 3][lm] = a4.w;
#pragma unroll
    for (int r = 0; r < 4; r++)
      Ws[lkq * 4 + r][ln] = W[(size_t)(k0 + lkq * 4 + r) * 128 + n0 + ln];
    __syncthreads();
#pragma unroll
    for (int kk = 0; kk < 16; kk++) {
      const float4 a = *(const float4*)&As[kk][ty * 4];
      const float4 w = *(const float4*)&Ws[kk][tx * 4];
      const float av[4] = {a.x, a.y, a.z, a.w};
      const float wv[4] = {w.x, w.y, w.z, w.w};
#pragma unroll
      for (int i = 0; i < 4; i++)
#pragma unroll
        for (int j = 0; j < 4; j++) acc[i][j] = fmaf(av[i], wv[j], acc[i][j]);
    }
    __syncthreads();
  }
  const float b0 = bias[n0 + tx * 4 + 0];
  const float b1 = bias[n0 + tx * 4 + 1];
  const float b2 = bias[n0 + tx * 4 + 2];
  const float b3 = bias[n0 + tx * 4 + 3];
#pragma unroll
  for (int i = 0; i < 4; i++) {
    float4 r;
    r.x = acc[i][0] + b0; r.y = acc[i][1] + b1;
    r.z = acc[i][2] + b2; r.w = acc[i][3] + b3;
    *(float4*)(C + (size_t)(m0 + ty * 4 + i) * 128 + n0 + tx * 4) = r;
  }
}

// ---------------- fused relational attention v4: swapped MFMA --------------
// arg^T[f,j] = qtv_i[f] + (Weff_i^T @ K^T)[f,j]  via mfma(bw, af)
// lane holds 8 f for ONE j -> in-lane w2-dot, 2 shuffles; softmax 13 regs.
// 8-query tiles: grid (25,32)=800 blocks, 45.5KB LDS -> 3 blocks/CU.
__global__ __launch_bounds__(256, 3) void rel_attn_mfma(
    const float* __restrict__ q, const float* __restrict__ k, const float* __restrict__ v,
    const float* __restrict__ W1g, const float* __restrict__ b1g,
    const float* __restrict__ w2p, float* __restrict__ o) {
  __shared__ __align__(16) bf16_t ksh[208 * 32];   // K bf16, 16B-block swizz
  __shared__ __align__(16) bf16_t vtsh[32 * 232];  // V^T bf16 [f'][j]
  __shared__ __align__(16) bf16_t psh[8 * 232];    // P bf16 [i_local][j]
  __shared__ __align__(16) float W1ki[32 * 64];    // (W1k,W1i) f32 pairs [e][f][2]
  __shared__ float W1qsh[32 * 33];                 // W1q f32 [e][f]
  __shared__ __align__(16) float qsh[8 * 32];
  __shared__ __align__(16) float qtsh[8 * 32];     // qtv = q@W1q + b1
  const int tid = threadIdx.x;
  const int bh = blockIdx.y, bb = bh >> 2, h = bh & 3;
  const int i0 = blockIdx.x * 8;                   // 25*8 = 200 exact
  const float* kg = k + (size_t)(bb * KK) * DDIM + h * DH;
  const float* vg = v + (size_t)(bb * KK) * DDIM + h * DH;
  const float* qg = q + (size_t)(bb * KK) * DDIM + h * DH;
  // ---- stage K (bf16, swizzled: 16B block ^= (j>>1)&3) ----
#pragma unroll
  for (int it = 0; it < 13; ++it) {
    int u = tid + it * 256;                 // < 3328 = 208 j * 16 e-pairs
    int j = u >> 4, ep = u & 15;
    float a0 = 0.f, a1 = 0.f;
    if (j < KK) { float2 t2 = *(const float2*)(kg + (size_t)j * DDIM + 2 * ep); a0 = t2.x; a1 = t2.y; }
    int sb = (ep >> 2) ^ ((j >> 1) & 3);
    union { bf16_t h2[2]; unsigned uu; } pk;
    pk.h2[0] = (bf16_t)a0; pk.h2[1] = (bf16_t)a1;
    *(unsigned*)&ksh[j * 32 + sb * 8 + (ep & 3) * 2] = pk.uu;
  }
  // ---- stage V^T (bf16) ----
#pragma unroll
  for (int it = 0; it < 13; ++it) {
    int u = tid + it * 256;                 // < 3328 = 104 j-pairs * 32 f
    int jp = u >> 5, f = u & 31;
    int j0 = jp * 2;
    float a0 = (j0 < KK) ? vg[(size_t)j0 * DDIM + f] : 0.f;
    float a1 = (j0 + 1 < KK) ? vg[(size_t)(j0 + 1) * DDIM + f] : 0.f;
    union { bf16_t h2[2]; unsigned uu; } pk;
    pk.h2[0] = (bf16_t)a0; pk.h2[1] = (bf16_t)a1;
    *(unsigned*)&vtsh[f * 232 + j0] = pk.uu;
  }
  // ---- zero pads: vtsh cols 208..223, psh cols 208..223 ----
  if (tid < 256) {                          // vtsh: 32 f * 8 pairs
    int f = tid >> 3, cp = tid & 7;
    *(unsigned*)&vtsh[f * 232 + 208 + cp * 2] = 0u;
  }
  if (tid < 64) {                           // psh: 8 rows * 8 pairs
    int r = tid >> 3, cp = tid & 7;
    *(unsigned*)&psh[r * 232 + 208 + cp * 2] = 0u;
  }
  // ---- stage W1: (k,i) interleaved pairs + W1q ----
#pragma unroll
  for (int it = 0; it < 8; ++it) {
    int u = tid + it * 256;                 // < 2048 = 32e * 32f * 2
    int sel = u & 1, f = (u >> 1) & 31, e = u >> 6;
    W1ki[e * 64 + f * 2 + sel] = W1g[(32 + sel * 32 + e) * 32 + f];
  }
#pragma unroll
  for (int it = 0; it < 4; ++it) {
    int u = tid + it * 256;                 // < 1024
    int e = u >> 5, f = u & 31;
    W1qsh[e * 33 + f] = W1g[e * 32 + f];
  }
  {
    int il = tid >> 5, e = tid & 31;        // 8*32 = 256
    qsh[il * 32 + e] = qg[(size_t)(i0 + il) * DDIM + e];
  }
  __syncthreads();
  // ---- qtv = q @ W1q + b1 ----
  {
    int il = tid >> 5, f = tid & 31;
    float a = b1g[f];
#pragma unroll
    for (int e = 0; e < 32; ++e) a = fmaf(qsh[il * 32 + e], W1qsh[e * 33 + f], a);
    qtsh[il * 32 + f] = a;
  }
  __syncthreads();
  const int w = tid >> 6, lane = tid & 63;
  const int fcol = lane & 15, g = lane >> 4;
  // w2 scaled by 1/sqrt(32) * log2(e)  (exp2 softmax domain)
  const float w2c = 0.17677669529663687f * 1.4426950408889634f;
  float4 w2a = *(const float4*)(w2p + 4 * g);
  float4 w2b = *(const float4*)(w2p + 16 + 4 * g);
  w2a.x *= w2c; w2a.y *= w2c; w2a.z *= w2c; w2a.w *= w2c;
  w2b.x *= w2c; w2b.y *= w2c; w2b.z *= w2c; w2b.w *= w2c;
  for (int c = 0; c < 2; ++c) {
    const int il = w * 2 + c, i = i0 + il;
    // ---- Weff^T A-frags: bw0 (f=fcol), bw1 (f=fcol+16) ----
    const float4 qa = *(const float4*)&qsh[il * 32 + g * 8];
    const float4 qb4 = *(const float4*)&qsh[il * 32 + g * 8 + 4];
    const float qv[8] = {qa.x, qa.y, qa.z, qa.w, qb4.x, qb4.y, qb4.z, qb4.w};
    bf16x8 bw0, bw1;
#pragma unroll
    for (int e8 = 0; e8 < 8; ++e8) {
      int e = g * 8 + e8;
      const float2 ki0 = *(const float2*)&W1ki[e * 64 + fcol * 2];
      const float2 ki1 = *(const float2*)&W1ki[e * 64 + fcol * 2 + 32];
      bw0[e8] = (bf16_t)fmaf(qv[e8], ki0.y, ki0.x);
      bw1[e8] = (bf16_t)fmaf(qv[e8], ki1.y, ki1.x);
    }
    const float4 qta = *(const float4*)&qtsh[il * 32 + 4 * g];
    const float4 qtb = *(const float4*)&qtsh[il * 32 + 16 + 4 * g];
    float s[13];
#pragma unroll
    for (int jt = 0; jt < 13; ++jt) {
      int j = jt * 16 + fcol;
      bf16x8 af = *(const bf16x8*)&ksh[j * 32 + (g ^ ((j >> 1) & 3)) * 8];
      f32x4 acc0 = {0.f, 0.f, 0.f, 0.f}, acc1 = {0.f, 0.f, 0.f, 0.f};
      acc0 = __builtin_amdgcn_mfma_f32_16x16x32_bf16(bw0, af, acc0, 0, 0, 0);
      acc1 = __builtin_amdgcn_mfma_f32_16x16x32_bf16(bw1, af, acc1, 0, 0, 0);
      float t = fgelu2(acc0[0] + qta.x) * w2a.x;
      t = fmaf(fgelu2(acc0[1] + qta.y), w2a.y, t);
      t = fmaf(fgelu2(acc0[2] + qta.z), w2a.z, t);
      t = fmaf(fgelu2(acc0[3] + qta.w), w2a.w, t);
      t = fmaf(fgelu2(acc1[0] + qtb.x), w2b.x, t);
      t = fmaf(fgelu2(acc1[1] + qtb.y), w2b.y, t);
      t = fmaf(fgelu2(acc1[2] + qtb.z), w2b.z, t);
      t = fmaf(fgelu2(acc1[3] + qtb.w), w2b.w, t);
      t += __shfl_xor(t, 16);
      t += __shfl_xor(t, 32);
      s[jt] = t;                            // score*log2e for j, dup over g
    }
    if (fcol >= 8) s[12] = -1e30f;          // j = 192+fcol >= 200 mask
    float m = s[0];
#pragma unroll
    for (int jt = 1; jt < 13; ++jt) m = fmaxf(m, s[jt]);
    m = fmaxf(m, __shfl_xor(m, 1));
    m = fmaxf(m, __shfl_xor(m, 2));
    m = fmaxf(m, __shfl_xor(m, 4));
    m = fmaxf(m, __shfl_xor(m, 8));
    float l = 0.f;
#pragma unroll
    for (int jt = 0; jt < 13; ++jt) {
      float p = exp2f(s[jt] - m);
      s[jt] = p;
      l += p;
    }
    l += __shfl_xor(l, 1);
    l += __shfl_xor(l, 2);
    l += __shfl_xor(l, 4);
    l += __shfl_xor(l, 8);
    const float inv = __frcp_rn(l);
    if (g == 0) {
#pragma unroll
      for (int jt = 0; jt < 13; ++jt)
        psh[il * 232 + jt * 16 + fcol] = (bf16_t)(s[jt] * inv);
    }
    (void)i;
  }
  __syncthreads();
  // ---- PV: O[8 i, 32 f'] = P[8(+pad),224] @ V[224,32]; waves 0,1 ----
  if (w < 2) {
    f32x4 acc = {0.f, 0.f, 0.f, 0.f};
#pragma unroll
    for (int ks = 0; ks < 7; ++ks) {
      bf16x8 ap;
      if (fcol < 8) ap = *(const bf16x8*)&psh[fcol * 232 + ks * 32 + g * 8];
      else { bf16x8 z = {}; ap = z; }
      bf16x8 bv = *(const bf16x8*)&vtsh[(w * 16 + fcol) * 232 + ks * 32 + g * 8];
      acc = __builtin_amdgcn_mfma_f32_16x16x32_bf16(ap, bv, acc, 0, 0, 0);
    }
    if (g < 2) {
#pragma unroll
      for (int r = 0; r < 4; ++r) {
        int i = i0 + g * 4 + r;
        o[(size_t)(bb * KK + i) * DDIM + h * DH + w * 16 + fcol] = acc[r];
      }
    }
  }
}

// ---------------- residual + LayerNorm (wave per token) --------------------
__global__ __launch_bounds__(256) void res_ln(float* __restrict__ B,
    const float* __restrict__ add, const float* __restrict__ g,
    const float* __restrict__ bt) {
  int tok = blockIdx.x * 4 + (threadIdx.x >> 6);
  int ln = threadIdx.x & 63;
  float* row = B + (size_t)tok * DDIM;
  const float* ar = add + (size_t)tok * DDIM;
  float x0 = row[ln] + ar[ln];
  float x1 = row[ln + 64] + ar[ln + 64];
  float s = x0 + x1;
#pragma unroll
  for (int m = 1; m <= 32; m <<= 1) s += __shfl_xor(s, m);
  float mean = s * (1.f / 128.f);
  float d0 = x0 - mean, d1 = x1 - mean;
  float qq = d0 * d0 + d1 * d1;
#pragma unroll
  for (int m = 1; m <= 32; m <<= 1) qq += __shfl_xor(qq, m);
  float rs = rsqrtf(qq * (1.f / 128.f) + 1e-5f);
  row[ln] = d0 * rs * g[ln] + bt[ln];
  row[ln + 64] = d1 * rs * g[ln + 64] + bt[ln + 64];
}

// ---------------- memory-slot attention rows: ma[b,s,c] --------------------
__global__ __launch_bounds__(256) void slot_ma(const float* __restrict__ B,
    const float* __restrict__ slots, float* __restrict__ ma) {
  const int bs = blockIdx.x;  // b*64+s
  const int s = bs & 63;
  const int b = bs >> 6;
  const int tid = threadIdx.x;
  __shared__ __align__(16) float sl[128];
  __shared__ float red1[4], red2[4];
  if (tid < 128) sl[tid] = slots[(size_t)s * DDIM + tid];
  __syncthreads();
  float sc = -1e30f;
  if (tid < KK) {
    const float* br = B + (size_t)(b * KK + tid) * DDIM;
    float a = 0.f;
#pragma unroll
    for (int d4 = 0; d4 < 32; d4++) {
      float4 bb = *(const float4*)(br + d4 * 4);
      float4 ss = *(const float4*)(sl + d4 * 4);
      a += bb.x * ss.x + bb.y * ss.y + bb.z * ss.z + bb.w * ss.w;
    }
    sc = a * 0.08838834764831845f;  // 1/sqrt(128)
  }
  float mx = sc;
#pragma unroll
  for (int m = 1; m <= 32; m <<= 1) mx = fmaxf(mx, __shfl_xor(mx, m));
  if ((tid & 63) == 0) red1[tid >> 6] = mx;
  __syncthreads();
  mx = fmaxf(fmaxf(red1[0], red1[1]), fmaxf(red1[2], red1[3]));
  float p = (tid < KK) ? __expf(sc - mx) : 0.f;
  float sm = p;
#pragma unroll
  for (int m = 1; m <= 32; m <<= 1) sm += __shfl_xor(sm, m);
  if ((tid & 63) == 0) red2[tid >> 6] = sm;
  __syncthreads();
  sm = red2[0] + red2[1] + red2[2] + red2[3];
  if (tid < KK) ma[(size_t)bs * KK + tid] = p / sm;
}

// ---------------- final readout: h + LN(mem) -> head ------------------------
__global__ __launch_bounds__(256) void readout_kernel(const float* __restrict__ B,
    const float* __restrict__ ma, const float* __restrict__ task_q,
    const float* __restrict__ memg, const float* __restrict__ membt,
    const float* __restrict__ headW, const float* __restrict__ headb,
    float* __restrict__ out) {
  const int b = blockIdx.x, tid = threadIdx.x;
  __shared__ __align__(16) float tq[128];
  __shared__ float ras[KK];
  __shared__ float wc[KK];
  __shared__ float red1[4], red2[4];
  __shared__ float hv[128], mv[128], rv[128];
  __shared__ float stats[2];
  if (tid < 128) tq[tid] = task_q[tid];
  __syncthreads();
  float sc = -1e30f;
  if (tid < KK) {
    const float* br = B + (size_t)(b * KK + tid) * DDIM;
    float a = 0.f;
#pragma unroll
    for (int d4 = 0; d4 < 32; d4++) {
      float4 bb = *(const float4*)(br + d4 * 4);
      float4 ss = *(const float4*)(tq + d4 * 4);
      a += bb.x * ss.x + bb.y * ss.y + bb.z * ss.z + bb.w * ss.w;
    }
    sc = a * 0.08838834764831845f;
  }
  float mx = sc;
#pragma unroll
  for (int m = 1; m <= 32; m <<= 1) mx = fmaxf(mx, __shfl_xor(mx, m));
  if ((tid & 63) == 0) red1[tid >> 6] = mx;
  __syncthreads();
  mx = fmaxf(fmaxf(red1[0], red1[1]), fmaxf(red1[2], red1[3]));
  float p = (tid < KK) ? __expf(sc - mx) : 0.f;
  float sm = p;
#pragma unroll
  for (int m = 1; m <= 32; m <<= 1) sm += __shfl_xor(sm, m);
  if ((tid & 63) == 0) red2[tid >> 6] = sm;
  __syncthreads();
  sm = red2[0] + red2[1] + red2[2] + red2[3];
  if (tid < KK) {
    ras[tid] = p / sm;
    float a = 0.f;
    for (int s_ = 0; s_ < SSLOT; s_++) a += ma[((size_t)b * SSLOT + s_) * KK + tid];
    wc[tid] = a * (1.f / 64.f);
  }
  __syncthreads();
  if (tid < 128) {
    float hd = 0.f, md = 0.f;
    for (int c = 0; c < KK; c++) {
      float bv = B[(size_t)(b * KK + c) * DDIM + tid];
      hd = fmaf(ras[c], bv, hd);
      md = fmaf(wc[c], bv, md);
    }
    hv[tid] = hd; mv[tid] = md;
  }
  __syncthreads();
  if (tid < 64) {
    float x0 = mv[tid], x1 = mv[tid + 64];
    float s = x0 + x1, qq = x0 * x0 + x1 * x1;
#pragma unroll
    for (int m = 1; m <= 32; m <<= 1) { s += __shfl_xor(s, m); qq += __shfl_xor(qq, m); }
    if (tid == 0) { stats[0] = s; stats[1] = qq; }
  }
  __syncthreads();
  float mean = stats[0] * (1.f / 128.f);
  float var = stats[1] * (1.f / 128.f) - mean * mean;
  float rs = rsqrtf(var + 1e-5f);
  if (tid < 128) rv[tid] = hv[tid] + (mv[tid] - mean) * rs * memg[tid] + membt[tid];
  __syncthreads();
  if (tid < OUTN) {
    float a = headb[tid];
    for (int dd = 0; dd < 128; dd++) a = fmaf(rv[dd], headW[dd * OUTN + tid], a);
    out[b * OUTN + tid] = a;
  }
}

// ---------------------------------------------------------------------------
extern "C" void kernel_launch(void* const* d_in, const int* in_sizes, int n_in,
                              void* d_out, int out_size, void* d_ws, size_t ws_size,
                              hipStream_t stream) {
  (void)in_sizes; (void)n_in; (void)out_size; (void)ws_size;
  const float* x        = (const float*)d_in[0];
  const float* role_emb = (const float*)d_in[1];
  const float* filler_w = (const float*)d_in[2];
  const float* qW = (const float*)d_in[3];
  const float* qb = (const float*)d_in[4];
  const float* kW = (const float*)d_in[5];
  const float* kb = (const float*)d_in[6];
  const float* vW = (const float*)d_in[7];
  const float* vb = (const float*)d_in[8];
  const float* oW = (const float*)d_in[9];
  const float* ob = (const float*)d_in[10];
  const float* relW1 = (const float*)d_in[11];
  const float* relb1 = (const float*)d_in[12];
  const float* relW2 = (const float*)d_in[13];
  const float* relb2 = (const float*)d_in[14];
  const float* ln1g = (const float*)d_in[15];
  const float* ln1b = (const float*)d_in[16];
  const float* ln2g = (const float*)d_in[17];
  const float* ln2b = (const float*)d_in[18];
  const float* fW1 = (const float*)d_in[19];
  const float* fb1 = (const float*)d_in[20];
  const float* fW2 = (const float*)d_in[21];
  const float* fb2 = (const float*)d_in[22];
  const float* slots = (const float*)d_in[23];
  const float* memg = (const float*)d_in[24];
  const float* memb = (const float*)d_in[25];
  const float* taskq = (const float*)d_in[26];
  const float* headW = (const float*)d_in[27];
  const float* headb = (const float*)d_in[28];
  float* out = (float*)d_out;
  (void)relb2;  // dropped: softmax shift-invariance

  // workspace layout (float offsets; all 16B aligned)
  float* fws  = (float*)d_ws;
  int*   idxb = (int*)d_ws;              //   1600 ints
  float* vals = fws + 1600;              //   1600
  float* btok = fws + 3200;              // 204800
  float* qbuf = fws + 208000;            // 204800
  float* kbuf = fws + 412800;            // 204800
  float* vbuf = fws + 617600;            // 204800
  float* obuf = fws + 822400;            // 204800
  float* tmpb = fws + 1027200;           // 204800
  float* hbuf = fws + 1232000;           // 819200
  float* mab  = fws + 2051200;           // 102400  (total ~8.6 MB)

  topk_kernel<<<8, 256, 0, stream>>>(x, vals, idxb);
  bind_kernel<<<800, 256, 0, stream>>>(vals, idxb, role_emb, filler_w, btok);
  for (int l = 0; l < LLAY; l++) {
    qkv_gemm<<<dim3(25, 2, 3), 256, 0, stream>>>(btok,
        qW + l * 16384, qb + l * 128, kW + l * 16384, kb + l * 128,
        vW + l * 16384, vb + l * 128, qbuf, kbuf, vbuf);
    rel_attn_mfma<<<dim3(25, 32), 256, 0, stream>>>(qbuf, kbuf, vbuf,
        relW1 + l * 3072, relb1 + l * 32, relW2 + l * 32, obuf);
    gemm_bias<0><<<dim3(25, 2), 256, 0, stream>>>(obuf, oW + l * 16384, ob + l * 128, tmpb, 1600, 128, 128);
    res_ln<<<400, 256, 0, stream>>>(btok, tmpb, ln1g + l * 128, ln1b + l * 128);
    gemm_bias<1><<<dim3(25, 8), 256, 0, stream>>>(btok, fW1 + l * 65536, fb1 + l * 512, hbuf, 1600, 512, 128);
    gemm_bias<0><<<dim3(25, 2), 256, 0, stream>>>(hbuf, fW2 + l * 65536, fb2 + l * 128, tmpb, 1600, 128, 512);
    res_ln<<<400, 256, 0, stream>>>(btok, tmpb, ln2g + l * 128, ln2b + l * 128);
  }
  slot_ma<<<512, 256, 0, stream>>>(btok, slots, mab);
  readout_kernel<<<8, 256, 0, stream>>>(btok, mab, taskq, memg, memb, headW, headb, out);
}

// Round 5
// 329.924 us; speedup vs baseline: 2.2038x; 1.2782x over previous
//
#include <hip/hip_runtime.h>
#include <math.h>

#define BQ 8
#define CC 2048
#define DDIM 128
#define LLAY 3
#define HH 4
#define KK 200
#define SSLOT 64
#define OUTN 24
#define DH 32

typedef __bf16 bf16_t;
typedef __bf16 bf16x8 __attribute__((ext_vector_type(8)));
typedef float f32x4 __attribute__((ext_vector_type(4)));

__device__ __forceinline__ float fgelu2(float x) {
  float xc = fminf(x, 8.f);
  float inner = fmaf(0.044715f * xc * xc, xc, xc);
  float e = exp2f(inner * 2.302118610509359f);
  return x * e * __frcp_rn(1.f + e);
}
__device__ __forceinline__ float egelu(float x) {
  return 0.5f * x * (1.f + erff(x * 0.7071067811865476f));
}

// ---------------- top-k over 2048 per row (binary search on float bits) ----
__global__ __launch_bounds__(256) void topk_kernel(const float* __restrict__ x,
                                                   float* __restrict__ vals,
                                                   int* __restrict__ idx) {
  const int b = blockIdx.x, tid = threadIdx.x;
  float xv[8]; unsigned xb[8];
#pragma unroll
  for (int t = 0; t < 8; t++) {
    float v = x[b * CC + t * 256 + tid];
    xv[t] = v;
    xb[t] = __float_as_uint(v);
  }
  __shared__ int red[4];
  __shared__ int cnt;
  unsigned lo = 0u, hi = 0x7f800000u;
  while (lo < hi) {
    unsigned mid = (lo + hi) >> 1;
    int c = 0;
#pragma unroll
    for (int t = 0; t < 8; t++) c += (xb[t] > mid) ? 1 : 0;
#pragma unroll
    for (int m = 1; m <= 32; m <<= 1) c += __shfl_xor(c, m);
    if ((tid & 63) == 0) red[tid >> 6] = c;
    __syncthreads();
    int ct = red[0] + red[1] + red[2] + red[3];
    __syncthreads();
    if (ct >= KK) lo = mid + 1; else hi = mid;
  }
  const unsigned thr = lo;
  if (tid == 0) cnt = 0;
  __syncthreads();
#pragma unroll
  for (int t = 0; t < 8; t++) {
    if (xb[t] > thr) {
      int p = atomicAdd(&cnt, 1);
      vals[b * KK + p] = log1pf(xv[t]);
      idx[b * KK + p] = t * 256 + tid;
    }
  }
  __syncthreads();
#pragma unroll
  for (int t = 0; t < 8; t++) {
    if (xb[t] == thr) {
      int p = atomicAdd(&cnt, 1);
      if (p < KK) {
        vals[b * KK + p] = log1pf(xv[t]);
        idx[b * KK + p] = t * 256 + tid;
      }
    }
  }
}

// ---------------- b = role_emb[idx] * gelu(val * filler_w) -----------------
__global__ __launch_bounds__(256) void bind_kernel(const float* __restrict__ vals,
    const int* __restrict__ idx, const float* __restrict__ role_emb,
    const float* __restrict__ fw, float* __restrict__ btok,
    bf16_t* __restrict__ btokbf) {
  int u = blockIdx.x * 256 + threadIdx.x;  // < 204800
  int dd = u & 127;
  int r = u >> 7;
  int b = r / KK, t = r - b * KK;
  float v = vals[b * KK + t];
  float fill = egelu(v * fw[dd]);
  float val = role_emb[(size_t)idx[b * KK + t] * DDIM + dd] * fill;
  btok[u] = val;
  btokbf[u] = (bf16_t)val;
}

// ====== MFMA GEMM building blocks: BM=64, BN=128, K-chunk=128 ==============
// LDS layout: 16B units, slot XOR-swizzled so ds_read_b128 is conflict-free.
// A-frag: lane holds A[row = l&15][k=8*(l>>4)..+7]; B-frag: B[k][col=l&15].

// ---------------- qkv: z selects q/k/v; q,v -> f32; k -> bf16 --------------
__global__ __launch_bounds__(256) void qkv_mfma(const bf16_t* __restrict__ A,
    const float* __restrict__ qW, const float* __restrict__ qb,
    const float* __restrict__ kW, const float* __restrict__ kb,
    const float* __restrict__ vW, const float* __restrict__ vb,
    float* __restrict__ qo, bf16_t* __restrict__ ko, float* __restrict__ vo) {
  __shared__ __align__(16) bf16_t Alds[64 * 16 * 8];
  __shared__ __align__(16) bf16_t Blds[128 * 16 * 8];
  const int tid = threadIdx.x, m0 = blockIdx.x * 64, z = blockIdx.y;
  const float* W; const float* bias;
  if (z == 0) { W = qW; bias = qb; }
  else if (z == 1) { W = kW; bias = kb; }
  else { W = vW; bias = vb; }
#pragma unroll
  for (int it = 0; it < 4; ++it) {
    int u = tid + it * 256;
    int row = u >> 4, kc = u & 15;
    uint4 d = *(const uint4*)(A + (size_t)(m0 + row) * 128 + kc * 8);
    *(uint4*)&Alds[(row * 16 + (kc ^ (row & 7))) * 8] = d;
  }
#pragma unroll
  for (int it = 0; it < 8; ++it) {
    int u = tid + it * 256;
    int col = u & 127, kcb = u >> 7;
    const float* Wp = W + (size_t)(kcb * 8) * 128 + col;
    bf16_t tmp[8];
#pragma unroll
    for (int e = 0; e < 8; ++e) tmp[e] = (bf16_t)Wp[(size_t)e * 128];
    *(uint4*)&Blds[(col * 16 + (kcb ^ (col & 7))) * 8] = *(uint4*)tmp;
  }
  __syncthreads();
  const int w = tid >> 6, lane = tid & 63, fcol = lane & 15, g = lane >> 4;
  f32x4 acc[8];
#pragma unroll
  for (int ni = 0; ni < 8; ++ni) acc[ni] = (f32x4){0.f, 0.f, 0.f, 0.f};
#pragma unroll
  for (int ks = 0; ks < 4; ++ks) {
    const int arow = 16 * w + fcol;
    bf16x8 a = *(const bf16x8*)&Alds[(arow * 16 + ((ks * 4 + g) ^ (arow & 7))) * 8];
#pragma unroll
    for (int ni = 0; ni < 8; ++ni) {
      const int bcol = ni * 16 + fcol;
      bf16x8 b = *(const bf16x8*)&Blds[(bcol * 16 + ((ks * 4 + g) ^ (bcol & 7))) * 8];
      acc[ni] = __builtin_amdgcn_mfma_f32_16x16x32_bf16(a, b, acc[ni], 0, 0, 0);
    }
  }
#pragma unroll
  for (int ni = 0; ni < 8; ++ni) {
    const int col = ni * 16 + fcol;
    const float bv = bias[col];
#pragma unroll
    for (int r = 0; r < 4; ++r) {
      const int row = m0 + 16 * w + 4 * g + r;
      float val = acc[ni][r] + bv;
      if (z == 0) qo[(size_t)row * 128 + col] = val;
      else if (z == 1) ko[(size_t)row * 128 + col] = (bf16_t)val;
      else vo[(size_t)row * 128 + col] = val;
    }
  }
}

// ---------------- ffn1: hbuf = gelu(btok @ W1 + b1) as bf16 ----------------
__global__ __launch_bounds__(256) void ffn1_mfma(const bf16_t* __restrict__ A,
    const float* __restrict__ W, const float* __restrict__ bias,
    bf16_t* __restrict__ hb) {
  __shared__ __align__(16) bf16_t Alds[64 * 16 * 8];
  __shared__ __align__(16) bf16_t Blds[128 * 16 * 8];
  const int tid = threadIdx.x, m0 = blockIdx.x * 64, n0 = blockIdx.y * 128;
#pragma unroll
  for (int it = 0; it < 4; ++it) {
    int u = tid + it * 256;
    int row = u >> 4, kc = u & 15;
    uint4 d = *(const uint4*)(A + (size_t)(m0 + row) * 128 + kc * 8);
    *(uint4*)&Alds[(row * 16 + (kc ^ (row & 7))) * 8] = d;
  }
#pragma unroll
  for (int it = 0; it < 8; ++it) {
    int u = tid + it * 256;
    int col = u & 127, kcb = u >> 7;
    const float* Wp = W + (size_t)(kcb * 8) * 512 + n0 + col;
    bf16_t tmp[8];
#pragma unroll
    for (int e = 0; e < 8; ++e) tmp[e] = (bf16_t)Wp[(size_t)e * 512];
    *(uint4*)&Blds[(col * 16 + (kcb ^ (col & 7))) * 8] = *(uint4*)tmp;
  }
  __syncthreads();
  const int w = tid >> 6, lane = tid & 63, fcol = lane & 15, g = lane >> 4;
  f32x4 acc[8];
#pragma unroll
  for (int ni = 0; ni < 8; ++ni) acc[ni] = (f32x4){0.f, 0.f, 0.f, 0.f};
#pragma unroll
  for (int ks = 0; ks < 4; ++ks) {
    const int arow = 16 * w + fcol;
    bf16x8 a = *(const bf16x8*)&Alds[(arow * 16 + ((ks * 4 + g) ^ (arow & 7))) * 8];
#pragma unroll
    for (int ni = 0; ni < 8; ++ni) {
      const int bcol = ni * 16 + fcol;
      bf16x8 b = *(const bf16x8*)&Blds[(bcol * 16 + ((ks * 4 + g) ^ (bcol & 7))) * 8];
      acc[ni] = __builtin_amdgcn_mfma_f32_16x16x32_bf16(a, b, acc[ni], 0, 0, 0);
    }
  }
#pragma unroll
  for (int ni = 0; ni < 8; ++ni) {
    const int col = ni * 16 + fcol;
    const float bv = bias[n0 + col];
#pragma unroll
    for (int r = 0; r < 4; ++r) {
      const int row = m0 + 16 * w + 4 * g + r;
      hb[(size_t)row * 512 + n0 + col] = (bf16_t)egelu(acc[ni][r] + bv);
    }
  }
}

// ---------------- gemm + residual + LayerNorm (N=128 full row) -------------
// btok = LN(btok + A@W + bias); also writes bf16 shadow.
__global__ __launch_bounds__(256) void gemmln_mfma(const bf16_t* __restrict__ A,
    int lda, int K, const float* __restrict__ W, const float* __restrict__ bias,
    const float* __restrict__ lng, const float* __restrict__ lnb,
    float* __restrict__ btok, bf16_t* __restrict__ btokbf) {
  __shared__ __align__(16) bf16_t Alds[64 * 16 * 8];
  __shared__ __align__(16) bf16_t Blds[128 * 16 * 8];
  const int tid = threadIdx.x, m0 = blockIdx.x * 64;
  const int w = tid >> 6, lane = tid & 63, fcol = lane & 15, g = lane >> 4;
  f32x4 acc[8];
#pragma unroll
  for (int ni = 0; ni < 8; ++ni) acc[ni] = (f32x4){0.f, 0.f, 0.f, 0.f};
  for (int kc0 = 0; kc0 < K; kc0 += 128) {
    if (kc0) __syncthreads();
#pragma unroll
    for (int it = 0; it < 4; ++it) {
      int u = tid + it * 256;
      int row = u >> 4, kc = u & 15;
      uint4 d = *(const uint4*)(A + (size_t)(m0 + row) * lda + kc0 + kc * 8);
      *(uint4*)&Alds[(row * 16 + (kc ^ (row & 7))) * 8] = d;
    }
#pragma unroll
    for (int it = 0; it < 8; ++it) {
      int u = tid + it * 256;
      int col = u & 127, kcb = u >> 7;
      const float* Wp = W + (size_t)(kc0 + kcb * 8) * 128 + col;
      bf16_t tmp[8];
#pragma unroll
      for (int e = 0; e < 8; ++e) tmp[e] = (bf16_t)Wp[(size_t)e * 128];
      *(uint4*)&Blds[(col * 16 + (kcb ^ (col & 7))) * 8] = *(uint4*)tmp;
    }
    __syncthreads();
#pragma unroll
    for (int ks = 0; ks < 4; ++ks) {
      const int arow = 16 * w + fcol;
      bf16x8 a = *(const bf16x8*)&Alds[(arow * 16 + ((ks * 4 + g) ^ (arow & 7))) * 8];
#pragma unroll
      for (int ni = 0; ni < 8; ++ni) {
        const int bcol = ni * 16 + fcol;
        bf16x8 b = *(const bf16x8*)&Blds[(bcol * 16 + ((ks * 4 + g) ^ (bcol & 7))) * 8];
        acc[ni] = __builtin_amdgcn_mfma_f32_16x16x32_bf16(a, b, acc[ni], 0, 0, 0);
      }
    }
  }
  // epilogue: bias + residual, row-wise LN over 128 cols
  float t[8][4];
  float s0 = 0.f, s1 = 0.f, s2 = 0.f, s3 = 0.f;
  float q0 = 0.f, q1 = 0.f, q2 = 0.f, q3 = 0.f;
#pragma unroll
  for (int ni = 0; ni < 8; ++ni) {
    const int col = ni * 16 + fcol;
    const float bv = bias[col];
#pragma unroll
    for (int r = 0; r < 4; ++r) {
      const int row = m0 + 16 * w + 4 * g + r;
      float val = acc[ni][r] + bv + btok[(size_t)row * 128 + col];
      t[ni][r] = val;
      if (r == 0) { s0 += val; q0 += val * val; }
      else if (r == 1) { s1 += val; q1 += val * val; }
      else if (r == 2) { s2 += val; q2 += val * val; }
      else { s3 += val; q3 += val * val; }
    }
  }
#pragma unroll
  for (int m = 1; m <= 8; m <<= 1) {
    s0 += __shfl_xor(s0, m); q0 += __shfl_xor(q0, m);
    s1 += __shfl_xor(s1, m); q1 += __shfl_xor(q1, m);
    s2 += __shfl_xor(s2, m); q2 += __shfl_xor(q2, m);
    s3 += __shfl_xor(s3, m); q3 += __shfl_xor(q3, m);
  }
  float mean[4], rs[4];
  mean[0] = s0 * (1.f / 128.f); mean[1] = s1 * (1.f / 128.f);
  mean[2] = s2 * (1.f / 128.f); mean[3] = s3 * (1.f / 128.f);
  rs[0] = rsqrtf(q0 * (1.f / 128.f) - mean[0] * mean[0] + 1e-5f);
  rs[1] = rsqrtf(q1 * (1.f / 128.f) - mean[1] * mean[1] + 1e-5f);
  rs[2] = rsqrtf(q2 * (1.f / 128.f) - mean[2] * mean[2] + 1e-5f);
  rs[3] = rsqrtf(q3 * (1.f / 128.f) - mean[3] * mean[3] + 1e-5f);
#pragma unroll
  for (int ni = 0; ni < 8; ++ni) {
    const int col = ni * 16 + fcol;
    const float gv = lng[col], bv2 = lnb[col];
#pragma unroll
    for (int r = 0; r < 4; ++r) {
      const int row = m0 + 16 * w + 4 * g + r;
      float o = (t[ni][r] - mean[r]) * rs[r] * gv + bv2;
      btok[(size_t)row * 128 + col] = o;
      btokbf[(size_t)row * 128 + col] = (bf16_t)o;
    }
  }
}

// ---------------- fused relational attention (bf16 K in, bf16 O out) -------
__global__ __launch_bounds__(256, 3) void rel_attn_mfma(
    const float* __restrict__ q, const bf16_t* __restrict__ kbf,
    const float* __restrict__ v,
    const float* __restrict__ W1g, const float* __restrict__ b1g,
    const float* __restrict__ w2p, bf16_t* __restrict__ o) {
  __shared__ __align__(16) bf16_t ksh[208 * 32];   // K bf16, 16B-block swizz
  __shared__ __align__(16) bf16_t vtsh[32 * 232];  // V^T bf16 [f'][j]
  __shared__ __align__(16) bf16_t psh[8 * 232];    // P bf16 [i_local][j]
  __shared__ __align__(16) float W1ki[32 * 64];    // (W1k,W1i) f32 pairs
  __shared__ float W1qsh[32 * 33];
  __shared__ __align__(16) float qsh[8 * 32];
  __shared__ __align__(16) float qtsh[8 * 32];
  const int tid = threadIdx.x;
  const int bh = blockIdx.y, bb = bh >> 2, h = bh & 3;
  const int i0 = blockIdx.x * 8;
  const bf16_t* kgb = kbf + (size_t)(bb * KK) * DDIM + h * DH;
  const float* vg = v + (size_t)(bb * KK) * DDIM + h * DH;
  const float* qg = q + (size_t)(bb * KK) * DDIM + h * DH;
  // ---- stage K (bf16 16B units, swizzled) ----
#pragma unroll
  for (int it = 0; it < 4; ++it) {
    int u = tid + it * 256;                 // < 832 = 208 j * 4 blocks
    if (u < 832) {
      int j = u >> 2, bi = u & 3;
      uint4 d = {0u, 0u, 0u, 0u};
      if (j < KK) d = *(const uint4*)(kgb + (size_t)j * DDIM + bi * 8);
      *(uint4*)&ksh[j * 32 + (bi ^ ((j >> 1) & 3)) * 8] = d;
    }
  }
  // ---- stage V^T (f32 -> bf16) ----
#pragma unroll
  for (int it = 0; it < 13; ++it) {
    int u = tid + it * 256;                 // < 3328 = 104 j-pairs * 32 f
    int jp = u >> 5, f = u & 31;
    int j0 = jp * 2;
    float a0 = (j0 < KK) ? vg[(size_t)j0 * DDIM + f] : 0.f;
    float a1 = (j0 + 1 < KK) ? vg[(size_t)(j0 + 1) * DDIM + f] : 0.f;
    union { bf16_t h2[2]; unsigned uu; } pk;
    pk.h2[0] = (bf16_t)a0; pk.h2[1] = (bf16_t)a1;
    *(unsigned*)&vtsh[f * 232 + j0] = pk.uu;
  }
  if (tid < 256) {
    int f = tid >> 3, cp = tid & 7;
    *(unsigned*)&vtsh[f * 232 + 208 + cp * 2] = 0u;
  }
  if (tid < 64) {
    int r = tid >> 3, cp = tid & 7;
    *(unsigned*)&psh[r * 232 + 208 + cp * 2] = 0u;
  }
#pragma unroll
  for (int it = 0; it < 8; ++it) {
    int u = tid + it * 256;
    int sel = u & 1, f = (u >> 1) & 31, e = u >> 6;
    W1ki[e * 64 + f * 2 + sel] = W1g[(32 + sel * 32 + e) * 32 + f];
  }
#pragma unroll
  for (int it = 0; it < 4; ++it) {
    int u = tid + it * 256;
    int e = u >> 5, f = u & 31;
    W1qsh[e * 33 + f] = W1g[e * 32 + f];
  }
  {
    int il = tid >> 5, e = tid & 31;
    qsh[il * 32 + e] = qg[(size_t)(i0 + il) * DDIM + e];
  }
  __syncthreads();
  {
    int il = tid >> 5, f = tid & 31;
    float a = b1g[f];
#pragma unroll
    for (int e = 0; e < 32; ++e) a = fmaf(qsh[il * 32 + e], W1qsh[e * 33 + f], a);
    qtsh[il * 32 + f] = a;
  }
  __syncthreads();
  const int w = tid >> 6, lane = tid & 63;
  const int fcol = lane & 15, g = lane >> 4;
  const float w2c = 0.17677669529663687f * 1.4426950408889634f;
  float4 w2a = *(const float4*)(w2p + 4 * g);
  float4 w2b = *(const float4*)(w2p + 16 + 4 * g);
  w2a.x *= w2c; w2a.y *= w2c; w2a.z *= w2c; w2a.w *= w2c;
  w2b.x *= w2c; w2b.y *= w2c; w2b.z *= w2c; w2b.w *= w2c;
  for (int c = 0; c < 2; ++c) {
    const int il = w * 2 + c;
    const float4 qa = *(const float4*)&qsh[il * 32 + g * 8];
    const float4 qb4 = *(const float4*)&qsh[il * 32 + g * 8 + 4];
    const float qv[8] = {qa.x, qa.y, qa.z, qa.w, qb4.x, qb4.y, qb4.z, qb4.w};
    bf16x8 bw0, bw1;
#pragma unroll
    for (int e8 = 0; e8 < 8; ++e8) {
      int e = g * 8 + e8;
      const float2 ki0 = *(const float2*)&W1ki[e * 64 + fcol * 2];
      const float2 ki1 = *(const float2*)&W1ki[e * 64 + fcol * 2 + 32];
      bw0[e8] = (bf16_t)fmaf(qv[e8], ki0.y, ki0.x);
      bw1[e8] = (bf16_t)fmaf(qv[e8], ki1.y, ki1.x);
    }
    const float4 qta = *(const float4*)&qtsh[il * 32 + 4 * g];
    const float4 qtb = *(const float4*)&qtsh[il * 32 + 16 + 4 * g];
    float s[13];
#pragma unroll
    for (int jt = 0; jt < 13; ++jt) {
      int j = jt * 16 + fcol;
      bf16x8 af = *(const bf16x8*)&ksh[j * 32 + (g ^ ((j >> 1) & 3)) * 8];
      f32x4 acc0 = {0.f, 0.f, 0.f, 0.f}, acc1 = {0.f, 0.f, 0.f, 0.f};
      acc0 = __builtin_amdgcn_mfma_f32_16x16x32_bf16(bw0, af, acc0, 0, 0, 0);
      acc1 = __builtin_amdgcn_mfma_f32_16x16x32_bf16(bw1, af, acc1, 0, 0, 0);
      float t = fgelu2(acc0[0] + qta.x) * w2a.x;
      t = fmaf(fgelu2(acc0[1] + qta.y), w2a.y, t);
      t = fmaf(fgelu2(acc0[2] + qta.z), w2a.z, t);
      t = fmaf(fgelu2(acc0[3] + qta.w), w2a.w, t);
      t = fmaf(fgelu2(acc1[0] + qtb.x), w2b.x, t);
      t = fmaf(fgelu2(acc1[1] + qtb.y), w2b.y, t);
      t = fmaf(fgelu2(acc1[2] + qtb.z), w2b.z, t);
      t = fmaf(fgelu2(acc1[3] + qtb.w), w2b.w, t);
      t += __shfl_xor(t, 16);
      t += __shfl_xor(t, 32);
      s[jt] = t;
    }
    if (fcol >= 8) s[12] = -1e30f;
    float m = s[0];
#pragma unroll
    for (int jt = 1; jt < 13; ++jt) m = fmaxf(m, s[jt]);
    m = fmaxf(m, __shfl_xor(m, 1));
    m = fmaxf(m, __shfl_xor(m, 2));
    m = fmaxf(m, __shfl_xor(m, 4));
    m = fmaxf(m, __shfl_xor(m, 8));
    float l = 0.f;
#pragma unroll
    for (int jt = 0; jt < 13; ++jt) {
      float p = exp2f(s[jt] - m);
      s[jt] = p;
      l += p;
    }
    l += __shfl_xor(l, 1);
    l += __shfl_xor(l, 2);
    l += __shfl_xor(l, 4);
    l += __shfl_xor(l, 8);
    const float inv = __frcp_rn(l);
    if (g == 0) {
#pragma unroll
      for (int jt = 0; jt < 13; ++jt)
        psh[il * 232 + jt * 16 + fcol] = (bf16_t)(s[jt] * inv);
    }
  }
  __syncthreads();
  if (w < 2) {
    f32x4 acc = {0.f, 0.f, 0.f, 0.f};
#pragma unroll
    for (int ks = 0; ks < 7; ++ks) {
      bf16x8 ap;
      if (fcol < 8) ap = *(const bf16x8*)&psh[fcol * 232 + ks * 32 + g * 8];
      else { bf16x8 z = {}; ap = z; }
      bf16x8 bv = *(const bf16x8*)&vtsh[(w * 16 + fcol) * 232 + ks * 32 + g * 8];
      acc = __builtin_amdgcn_mfma_f32_16x16x32_bf16(ap, bv, acc, 0, 0, 0);
    }
    if (g < 2) {
#pragma unroll
      for (int r = 0; r < 4; ++r) {
        int i = i0 + g * 4 + r;
        o[(size_t)(bb * KK + i) * DDIM + h * DH + w * 16 + fcol] = (bf16_t)acc[r];
      }
    }
  }
}

// ---------------- memory-slot attention rows: ma[b,s,c] --------------------
__global__ __launch_bounds__(256) void slot_ma(const float* __restrict__ B,
    const float* __restrict__ slots, float* __restrict__ ma) {
  const int bs = blockIdx.x;
  const int s = bs & 63;
  const int b = bs >> 6;
  const int tid = threadIdx.x;
  __shared__ __align__(16) float sl[128];
  __shared__ float red1[4], red2[4];
  if (tid < 128) sl[tid] = slots[(size_t)s * DDIM + tid];
  __syncthreads();
  float sc = -1e30f;
  if (tid < KK) {
    const float* br = B + (size_t)(b * KK + tid) * DDIM;
    float a = 0.f;
#pragma unroll
    for (int d4 = 0; d4 < 32; d4++) {
      float4 bb = *(const float4*)(br + d4 * 4);
      float4 ss = *(const float4*)(sl + d4 * 4);
      a += bb.x * ss.x + bb.y * ss.y + bb.z * ss.z + bb.w * ss.w;
    }
    sc = a * 0.08838834764831845f;
  }
  float mx = sc;
#pragma unroll
  for (int m = 1; m <= 32; m <<= 1) mx = fmaxf(mx, __shfl_xor(mx, m));
  if ((tid & 63) == 0) red1[tid >> 6] = mx;
  __syncthreads();
  mx = fmaxf(fmaxf(red1[0], red1[1]), fmaxf(red1[2], red1[3]));
  float p = (tid < KK) ? __expf(sc - mx) : 0.f;
  float sm = p;
#pragma unroll
  for (int m = 1; m <= 32; m <<= 1) sm += __shfl_xor(sm, m);
  if ((tid & 63) == 0) red2[tid >> 6] = sm;
  __syncthreads();
  sm = red2[0] + red2[1] + red2[2] + red2[3];
  if (tid < KK) ma[(size_t)bs * KK + tid] = p / sm;
}

// ---------------- final readout: h + LN(mem) -> head ------------------------
__global__ __launch_bounds__(256) void readout_kernel(const float* __restrict__ B,
    const float* __restrict__ ma, const float* __restrict__ task_q,
    const float* __restrict__ memg, const float* __restrict__ membt,
    const float* __restrict__ headW, const float* __restrict__ headb,
    float* __restrict__ out) {
  const int b = blockIdx.x, tid = threadIdx.x;
  __shared__ __align__(16) float tq[128];
  __shared__ float ras[KK];
  __shared__ float wc[KK];
  __shared__ float red1[4], red2[4];
  __shared__ float hv[128], mv[128], rv[128];
  __shared__ float stats[2];
  if (tid < 128) tq[tid] = task_q[tid];
  __syncthreads();
  float sc = -1e30f;
  if (tid < KK) {
    const float* br = B + (size_t)(b * KK + tid) * DDIM;
    float a = 0.f;
#pragma unroll
    for (int d4 = 0; d4 < 32; d4++) {
      float4 bb = *(const float4*)(br + d4 * 4);
      float4 ss = *(const float4*)(tq + d4 * 4);
      a += bb.x * ss.x + bb.y * ss.y + bb.z * ss.z + bb.w * ss.w;
    }
    sc = a * 0.08838834764831845f;
  }
  float mx = sc;
#pragma unroll
  for (int m = 1; m <= 32; m <<= 1) mx = fmaxf(mx, __shfl_xor(mx, m));
  if ((tid & 63) == 0) red1[tid >> 6] = mx;
  __syncthreads();
  mx = fmaxf(fmaxf(red1[0], red1[1]), fmaxf(red1[2], red1[3]));
  float p = (tid < KK) ? __expf(sc - mx) : 0.f;
  float sm = p;
#pragma unroll
  for (int m = 1; m <= 32; m <<= 1) sm += __shfl_xor(sm, m);
  if ((tid & 63) == 0) red2[tid >> 6] = sm;
  __syncthreads();
  sm = red2[0] + red2[1] + red2[2] + red2[3];
  if (tid < KK) {
    ras[tid] = p / sm;
    float a = 0.f;
    for (int s_ = 0; s_ < SSLOT; s_++) a += ma[((size_t)b * SSLOT + s_) * KK + tid];
    wc[tid] = a * (1.f / 64.f);
  }
  __syncthreads();
  if (tid < 128) {
    float hd = 0.f, md = 0.f;
    for (int c = 0; c < KK; c++) {
      float bv = B[(size_t)(b * KK + c) * DDIM + tid];
      hd = fmaf(ras[c], bv, hd);
      md = fmaf(wc[c], bv, md);
    }
    hv[tid] = hd; mv[tid] = md;
  }
  __syncthreads();
  if (tid < 64) {
    float x0 = mv[tid], x1 = mv[tid + 64];
    float s = x0 + x1, qq = x0 * x0 + x1 * x1;
#pragma unroll
    for (int m = 1; m <= 32; m <<= 1) { s += __shfl_xor(s, m); qq += __shfl_xor(qq, m); }
    if (tid == 0) { stats[0] = s; stats[1] = qq; }
  }
  __syncthreads();
  float mean = stats[0] * (1.f / 128.f);
  float var = stats[1] * (1.f / 128.f) - mean * mean;
  float rs = rsqrtf(var + 1e-5f);
  if (tid < 128) rv[tid] = hv[tid] + (mv[tid] - mean) * rs * memg[tid] + membt[tid];
  __syncthreads();
  if (tid < OUTN) {
    float a = headb[tid];
    for (int dd = 0; dd < 128; dd++) a = fmaf(rv[dd], headW[dd * OUTN + tid], a);
    out[b * OUTN + tid] = a;
  }
}

// ---------------------------------------------------------------------------
extern "C" void kernel_launch(void* const* d_in, const int* in_sizes, int n_in,
                              void* d_out, int out_size, void* d_ws, size_t ws_size,
                              hipStream_t stream) {
  (void)in_sizes; (void)n_in; (void)out_size; (void)ws_size;
  const float* x        = (const float*)d_in[0];
  const float* role_emb = (const float*)d_in[1];
  const float* filler_w = (const float*)d_in[2];
  const float* qW = (const float*)d_in[3];
  const float* qb = (const float*)d_in[4];
  const float* kW = (const float*)d_in[5];
  const float* kb = (const float*)d_in[6];
  const float* vW = (const float*)d_in[7];
  const float* vb = (const float*)d_in[8];
  const float* oW = (const float*)d_in[9];
  const float* ob = (const float*)d_in[10];
  const float* relW1 = (const float*)d_in[11];
  const float* relb1 = (const float*)d_in[12];
  const float* relW2 = (const float*)d_in[13];
  const float* relb2 = (const float*)d_in[14];
  const float* ln1g = (const float*)d_in[15];
  const float* ln1b = (const float*)d_in[16];
  const float* ln2g = (const float*)d_in[17];
  const float* ln2b = (const float*)d_in[18];
  const float* fW1 = (const float*)d_in[19];
  const float* fb1 = (const float*)d_in[20];
  const float* fW2 = (const float*)d_in[21];
  const float* fb2 = (const float*)d_in[22];
  const float* slots = (const float*)d_in[23];
  const float* memg = (const float*)d_in[24];
  const float* memb = (const float*)d_in[25];
  const float* taskq = (const float*)d_in[26];
  const float* headW = (const float*)d_in[27];
  const float* headb = (const float*)d_in[28];
  float* out = (float*)d_out;
  (void)relb2;  // dropped: softmax shift-invariance

  // workspace layout (float-slot offsets; all 16B aligned)
  float* fws  = (float*)d_ws;
  int*    idxb   = (int*)d_ws;               //   1600 ints
  float*  vals   = fws + 1600;               //   1600 f
  float*  btok   = fws + 3200;               // 204800 f
  float*  qbuf   = fws + 208000;             // 204800 f
  float*  vbuf   = fws + 412800;             // 204800 f
  float*  mab    = fws + 617600;             // 102400 f
  bf16_t* btokbf = (bf16_t*)(fws + 720000);  // 204800 bf16 = 102400 f
  bf16_t* kbf    = (bf16_t*)(fws + 822400);  // 204800 bf16
  bf16_t* obufbf = (bf16_t*)(fws + 924800);  // 204800 bf16
  bf16_t* hbuf   = (bf16_t*)(fws + 1027200); // 819200 bf16 = 409600 f  (end 1436800)

  topk_kernel<<<8, 256, 0, stream>>>(x, vals, idxb);
  bind_kernel<<<800, 256, 0, stream>>>(vals, idxb, role_emb, filler_w, btok, btokbf);
  for (int l = 0; l < LLAY; l++) {
    qkv_mfma<<<dim3(25, 3), 256, 0, stream>>>(btokbf,
        qW + l * 16384, qb + l * 128, kW + l * 16384, kb + l * 128,
        vW + l * 16384, vb + l * 128, qbuf, kbf, vbuf);
    rel_attn_mfma<<<dim3(25, 32), 256, 0, stream>>>(qbuf, kbf, vbuf,
        relW1 + l * 3072, relb1 + l * 32, relW2 + l * 32, obufbf);
    gemmln_mfma<<<25, 256, 0, stream>>>(obufbf, 128, 128, oW + l * 16384,
        ob + l * 128, ln1g + l * 128, ln1b + l * 128, btok, btokbf);
    ffn1_mfma<<<dim3(25, 4), 256, 0, stream>>>(btokbf, fW1 + l * 65536,
        fb1 + l * 512, hbuf);
    gemmln_mfma<<<25, 256, 0, stream>>>(hbuf, 512, 512, fW2 + l * 65536,
        fb2 + l * 128, ln2g + l * 128, ln2b + l * 128, btok, btokbf);
  }
  slot_ma<<<512, 256, 0, stream>>>(btok, slots, mab);
  readout_kernel<<<8, 256, 0, stream>>>(btok, mab, taskq, memg, memb, headW, headb, out);
}

// Round 6
// 275.735 us; speedup vs baseline: 2.6369x; 1.1965x over previous
//
#include <hip/hip_runtime.h>
#include <math.h>

#define BQ 8
#define CC 2048
#define DDIM 128
#define LLAY 3
#define HH 4
#define KK 200
#define SSLOT 64
#define OUTN 24
#define DH 32

typedef __bf16 bf16_t;
typedef __bf16 bf16x8 __attribute__((ext_vector_type(8)));
typedef float f32x4 __attribute__((ext_vector_type(4)));

__device__ __forceinline__ float fastrcp(float x) {
#if __has_builtin(__builtin_amdgcn_rcpf)
  return __builtin_amdgcn_rcpf(x);
#else
  return 1.0f / x;
#endif
}
__device__ __forceinline__ float fgelu2(float x) {
  // tanh-approx gelu: x*sigmoid(2*0.79788*(x+0.044715x^3)), exp2+v_rcp
  float xc = fminf(x, 8.f);
  float inner = fmaf(0.044715f * xc * xc, xc, xc);
  float e = exp2f(inner * 2.302118610509359f);
  return x * e * fastrcp(1.f + e);
}
__device__ __forceinline__ float egelu(float x) {
  return 0.5f * x * (1.f + erff(x * 0.7071067811865476f));
}

// ---------------- top-k over 2048 per row (binary search on float bits) ----
__global__ __launch_bounds__(256) void topk_kernel(const float* __restrict__ x,
                                                   float* __restrict__ vals,
                                                   int* __restrict__ idx) {
  const int b = blockIdx.x, tid = threadIdx.x;
  float xv[8]; unsigned xb[8];
#pragma unroll
  for (int t = 0; t < 8; t++) {
    float v = x[b * CC + t * 256 + tid];
    xv[t] = v;
    xb[t] = __float_as_uint(v);
  }
  __shared__ int red[4];
  __shared__ int cnt;
  unsigned lo = 0u, hi = 0x7f800000u;
  while (lo < hi) {
    unsigned mid = (lo + hi) >> 1;
    int c = 0;
#pragma unroll
    for (int t = 0; t < 8; t++) c += (xb[t] > mid) ? 1 : 0;
#pragma unroll
    for (int m = 1; m <= 32; m <<= 1) c += __shfl_xor(c, m);
    if ((tid & 63) == 0) red[tid >> 6] = c;
    __syncthreads();
    int ct = red[0] + red[1] + red[2] + red[3];
    __syncthreads();
    if (ct >= KK) lo = mid + 1; else hi = mid;
  }
  const unsigned thr = lo;
  if (tid == 0) cnt = 0;
  __syncthreads();
#pragma unroll
  for (int t = 0; t < 8; t++) {
    if (xb[t] > thr) {
      int p = atomicAdd(&cnt, 1);
      vals[b * KK + p] = log1pf(xv[t]);
      idx[b * KK + p] = t * 256 + tid;
    }
  }
  __syncthreads();
#pragma unroll
  for (int t = 0; t < 8; t++) {
    if (xb[t] == thr) {
      int p = atomicAdd(&cnt, 1);
      if (p < KK) {
        vals[b * KK + p] = log1pf(xv[t]);
        idx[b * KK + p] = t * 256 + tid;
      }
    }
  }
}

// ---------------- weight convert+transpose: f32 row-major -> bf16 col-major -
// 64x64 tiles; 144 tiles total (qkv/o 48, fW1 48, fW2 48)
__global__ __launch_bounds__(256) void wconv_kernel(
    const float* __restrict__ qW, const float* __restrict__ kW,
    const float* __restrict__ vW, const float* __restrict__ oW,
    const float* __restrict__ fW1, const float* __restrict__ fW2,
    bf16_t* __restrict__ wtb) {
  __shared__ float Ts[64][65];
  const int t = blockIdx.x, tid = threadIdx.x;
  const float* src; bf16_t* dst; int N, K, k0, n0;
  if (t < 48) {
    int which = t / 12, rem = t % 12;
    int l = rem >> 2, tt = rem & 3;
    N = 128; K = 128; k0 = (tt >> 1) * 64; n0 = (tt & 1) * 64;
    src = (which == 0 ? qW : which == 1 ? kW : which == 2 ? vW : oW) + l * 16384;
    dst = wtb + which * 49152 + l * 16384;
  } else if (t < 96) {
    int t2 = t - 48, l = t2 >> 4, tt = t2 & 15;
    N = 512; K = 128; k0 = (tt >> 3) * 64; n0 = (tt & 7) * 64;
    src = fW1 + l * 65536;
    dst = wtb + 196608 + l * 65536;
  } else {
    int t3 = t - 96, l = t3 >> 4, tt = t3 & 15;
    N = 128; K = 512; k0 = (tt >> 1) * 64; n0 = (tt & 1) * 64;
    src = fW2 + l * 65536;
    dst = wtb + 393216 + l * 65536;
  }
#pragma unroll
  for (int i = 0; i < 16; ++i) {
    int u = tid + i * 256;
    int r = u >> 6, c = u & 63;
    Ts[r][c] = src[(size_t)(k0 + r) * N + n0 + c];
  }
  __syncthreads();
#pragma unroll
  for (int i = 0; i < 16; ++i) {
    int u = tid + i * 256;
    int rn = u >> 6, ck = u & 63;
    dst[(size_t)(n0 + rn) * K + k0 + ck] = (bf16_t)Ts[ck][rn];
  }
}

// ---------------- b = role_emb[idx] * gelu(val * filler_w) -----------------
__global__ __launch_bounds__(256) void bind_kernel(const float* __restrict__ vals,
    const int* __restrict__ idx, const float* __restrict__ role_emb,
    const float* __restrict__ fw, float* __restrict__ btok,
    bf16_t* __restrict__ btokbf) {
  int u = blockIdx.x * 256 + threadIdx.x;  // < 204800
  int dd = u & 127;
  int r = u >> 7;
  int b = r / KK, t = r - b * KK;
  float v = vals[b * KK + t];
  float fill = egelu(v * fw[dd]);
  float val = role_emb[(size_t)idx[b * KK + t] * DDIM + dd] * fill;
  btok[u] = val;
  btokbf[u] = (bf16_t)val;
}

// ====== MFMA GEMM blocks: BM=64, BN=128, bf16 col-major weights ============

// ---------------- qkv: z selects q/k/v; q -> f32; k,v -> bf16 --------------
__global__ __launch_bounds__(256) void qkv_mfma(const bf16_t* __restrict__ A,
    const bf16_t* __restrict__ qWt, const float* __restrict__ qb,
    const bf16_t* __restrict__ kWt, const float* __restrict__ kb,
    const bf16_t* __restrict__ vWt, const float* __restrict__ vb,
    float* __restrict__ qo, bf16_t* __restrict__ ko, bf16_t* __restrict__ vo) {
  __shared__ __align__(16) bf16_t Alds[64 * 16 * 8];
  __shared__ __align__(16) bf16_t Blds[128 * 16 * 8];
  const int tid = threadIdx.x, m0 = blockIdx.x * 64, z = blockIdx.y;
  const bf16_t* Wt; const float* bias;
  if (z == 0) { Wt = qWt; bias = qb; }
  else if (z == 1) { Wt = kWt; bias = kb; }
  else { Wt = vWt; bias = vb; }
#pragma unroll
  for (int it = 0; it < 4; ++it) {
    int u = tid + it * 256;
    int row = u >> 4, kc = u & 15;
    uint4 d = *(const uint4*)(A + (size_t)(m0 + row) * 128 + kc * 8);
    *(uint4*)&Alds[(row * 16 + (kc ^ (row & 7))) * 8] = d;
  }
#pragma unroll
  for (int it = 0; it < 8; ++it) {
    int u = tid + it * 256;
    int col = u >> 4, kcb = u & 15;
    uint4 d = *(const uint4*)(Wt + (size_t)col * 128 + kcb * 8);
    *(uint4*)&Blds[(col * 16 + (kcb ^ (col & 7))) * 8] = d;
  }
  __syncthreads();
  const int w = tid >> 6, lane = tid & 63, fcol = lane & 15, g = lane >> 4;
  f32x4 acc[8];
#pragma unroll
  for (int ni = 0; ni < 8; ++ni) acc[ni] = (f32x4){0.f, 0.f, 0.f, 0.f};
#pragma unroll
  for (int ks = 0; ks < 4; ++ks) {
    const int arow = 16 * w + fcol;
    bf16x8 a = *(const bf16x8*)&Alds[(arow * 16 + ((ks * 4 + g) ^ (arow & 7))) * 8];
#pragma unroll
    for (int ni = 0; ni < 8; ++ni) {
      const int bcol = ni * 16 + fcol;
      bf16x8 b = *(const bf16x8*)&Blds[(bcol * 16 + ((ks * 4 + g) ^ (bcol & 7))) * 8];
      acc[ni] = __builtin_amdgcn_mfma_f32_16x16x32_bf16(a, b, acc[ni], 0, 0, 0);
    }
  }
#pragma unroll
  for (int ni = 0; ni < 8; ++ni) {
    const int col = ni * 16 + fcol;
    const float bv = bias[col];
#pragma unroll
    for (int r = 0; r < 4; ++r) {
      const int row = m0 + 16 * w + 4 * g + r;
      float val = acc[ni][r] + bv;
      if (z == 0) qo[(size_t)row * 128 + col] = val;
      else if (z == 1) ko[(size_t)row * 128 + col] = (bf16_t)val;
      else vo[(size_t)row * 128 + col] = (bf16_t)val;
    }
  }
}

// ---------------- ffn1: hbuf = gelu(btok @ W1 + b1) as bf16 ----------------
__global__ __launch_bounds__(256) void ffn1_mfma(const bf16_t* __restrict__ A,
    const bf16_t* __restrict__ Wt, const float* __restrict__ bias,
    bf16_t* __restrict__ hb) {
  __shared__ __align__(16) bf16_t Alds[64 * 16 * 8];
  __shared__ __align__(16) bf16_t Blds[128 * 16 * 8];
  const int tid = threadIdx.x, m0 = blockIdx.x * 64, n0 = blockIdx.y * 128;
#pragma unroll
  for (int it = 0; it < 4; ++it) {
    int u = tid + it * 256;
    int row = u >> 4, kc = u & 15;
    uint4 d = *(const uint4*)(A + (size_t)(m0 + row) * 128 + kc * 8);
    *(uint4*)&Alds[(row * 16 + (kc ^ (row & 7))) * 8] = d;
  }
#pragma unroll
  for (int it = 0; it < 8; ++it) {
    int u = tid + it * 256;
    int col = u >> 4, kcb = u & 15;
    uint4 d = *(const uint4*)(Wt + (size_t)(n0 + col) * 128 + kcb * 8);
    *(uint4*)&Blds[(col * 16 + (kcb ^ (col & 7))) * 8] = d;
  }
  __syncthreads();
  const int w = tid >> 6, lane = tid & 63, fcol = lane & 15, g = lane >> 4;
  f32x4 acc[8];
#pragma unroll
  for (int ni = 0; ni < 8; ++ni) acc[ni] = (f32x4){0.f, 0.f, 0.f, 0.f};
#pragma unroll
  for (int ks = 0; ks < 4; ++ks) {
    const int arow = 16 * w + fcol;
    bf16x8 a = *(const bf16x8*)&Alds[(arow * 16 + ((ks * 4 + g) ^ (arow & 7))) * 8];
#pragma unroll
    for (int ni = 0; ni < 8; ++ni) {
      const int bcol = ni * 16 + fcol;
      bf16x8 b = *(const bf16x8*)&Blds[(bcol * 16 + ((ks * 4 + g) ^ (bcol & 7))) * 8];
      acc[ni] = __builtin_amdgcn_mfma_f32_16x16x32_bf16(a, b, acc[ni], 0, 0, 0);
    }
  }
#pragma unroll
  for (int ni = 0; ni < 8; ++ni) {
    const int col = ni * 16 + fcol;
    const float bv = bias[n0 + col];
#pragma unroll
    for (int r = 0; r < 4; ++r) {
      const int row = m0 + 16 * w + 4 * g + r;
      hb[(size_t)row * 512 + n0 + col] = (bf16_t)egelu(acc[ni][r] + bv);
    }
  }
}

// ---------------- gemm + residual + LayerNorm (N=128 full row) -------------
__global__ __launch_bounds__(256) void gemmln_mfma(const bf16_t* __restrict__ A,
    int lda, int K, const bf16_t* __restrict__ Wt, const float* __restrict__ bias,
    const float* __restrict__ lng, const float* __restrict__ lnb,
    float* __restrict__ btok, bf16_t* __restrict__ btokbf) {
  __shared__ __align__(16) bf16_t Alds[64 * 16 * 8];
  __shared__ __align__(16) bf16_t Blds[128 * 16 * 8];
  const int tid = threadIdx.x, m0 = blockIdx.x * 64;
  const int w = tid >> 6, lane = tid & 63, fcol = lane & 15, g = lane >> 4;
  f32x4 acc[8];
#pragma unroll
  for (int ni = 0; ni < 8; ++ni) acc[ni] = (f32x4){0.f, 0.f, 0.f, 0.f};
  for (int kc0 = 0; kc0 < K; kc0 += 128) {
    if (kc0) __syncthreads();
#pragma unroll
    for (int it = 0; it < 4; ++it) {
      int u = tid + it * 256;
      int row = u >> 4, kc = u & 15;
      uint4 d = *(const uint4*)(A + (size_t)(m0 + row) * lda + kc0 + kc * 8);
      *(uint4*)&Alds[(row * 16 + (kc ^ (row & 7))) * 8] = d;
    }
#pragma unroll
    for (int it = 0; it < 8; ++it) {
      int u = tid + it * 256;
      int col = u >> 4, kcb = u & 15;
      uint4 d = *(const uint4*)(Wt + (size_t)col * K + kc0 + kcb * 8);
      *(uint4*)&Blds[(col * 16 + (kcb ^ (col & 7))) * 8] = d;
    }
    __syncthreads();
#pragma unroll
    for (int ks = 0; ks < 4; ++ks) {
      const int arow = 16 * w + fcol;
      bf16x8 a = *(const bf16x8*)&Alds[(arow * 16 + ((ks * 4 + g) ^ (arow & 7))) * 8];
#pragma unroll
      for (int ni = 0; ni < 8; ++ni) {
        const int bcol = ni * 16 + fcol;
        bf16x8 b = *(const bf16x8*)&Blds[(bcol * 16 + ((ks * 4 + g) ^ (bcol & 7))) * 8];
        acc[ni] = __builtin_amdgcn_mfma_f32_16x16x32_bf16(a, b, acc[ni], 0, 0, 0);
      }
    }
  }
  float t[8][4];
  float s0 = 0.f, s1 = 0.f, s2 = 0.f, s3 = 0.f;
  float q0 = 0.f, q1 = 0.f, q2 = 0.f, q3 = 0.f;
#pragma unroll
  for (int ni = 0; ni < 8; ++ni) {
    const int col = ni * 16 + fcol;
    const float bv = bias[col];
#pragma unroll
    for (int r = 0; r < 4; ++r) {
      const int row = m0 + 16 * w + 4 * g + r;
      float val = acc[ni][r] + bv + btok[(size_t)row * 128 + col];
      t[ni][r] = val;
      if (r == 0) { s0 += val; q0 += val * val; }
      else if (r == 1) { s1 += val; q1 += val * val; }
      else if (r == 2) { s2 += val; q2 += val * val; }
      else { s3 += val; q3 += val * val; }
    }
  }
#pragma unroll
  for (int m = 1; m <= 8; m <<= 1) {
    s0 += __shfl_xor(s0, m); q0 += __shfl_xor(q0, m);
    s1 += __shfl_xor(s1, m); q1 += __shfl_xor(q1, m);
    s2 += __shfl_xor(s2, m); q2 += __shfl_xor(q2, m);
    s3 += __shfl_xor(s3, m); q3 += __shfl_xor(q3, m);
  }
  float mean[4], rs[4];
  mean[0] = s0 * (1.f / 128.f); mean[1] = s1 * (1.f / 128.f);
  mean[2] = s2 * (1.f / 128.f); mean[3] = s3 * (1.f / 128.f);
  rs[0] = rsqrtf(q0 * (1.f / 128.f) - mean[0] * mean[0] + 1e-5f);
  rs[1] = rsqrtf(q1 * (1.f / 128.f) - mean[1] * mean[1] + 1e-5f);
  rs[2] = rsqrtf(q2 * (1.f / 128.f) - mean[2] * mean[2] + 1e-5f);
  rs[3] = rsqrtf(q3 * (1.f / 128.f) - mean[3] * mean[3] + 1e-5f);
#pragma unroll
  for (int ni = 0; ni < 8; ++ni) {
    const int col = ni * 16 + fcol;
    const float gv = lng[col], bv2 = lnb[col];
#pragma unroll
    for (int r = 0; r < 4; ++r) {
      const int row = m0 + 16 * w + 4 * g + r;
      float o = (t[ni][r] - mean[r]) * rs[r] * gv + bv2;
      btok[(size_t)row * 128 + col] = o;
      btokbf[(size_t)row * 128 + col] = (bf16_t)o;
    }
  }
}

// ---------------- fused relational attention v5 ----------------------------
// LDS 39.7KB -> 4 blocks/CU; bf16 W1; v_rcp; 4-chain gelu tree; c-unroll.
__global__ __launch_bounds__(256, 4) void rel_attn_mfma(
    const float* __restrict__ q, const bf16_t* __restrict__ kbf,
    const bf16_t* __restrict__ vbf,
    const float* __restrict__ W1g, const float* __restrict__ b1g,
    const float* __restrict__ w2p, bf16_t* __restrict__ o) {
  __shared__ __align__(16) bf16_t ksh[208 * 32];   // 13312 B, 16B-block swizz
  __shared__ __align__(16) bf16_t vtsh[32 * 224];  // 14336 B, V^T [f'][j]
  __shared__ __align__(16) bf16_t psh[8 * 224];    // 3584 B, P [i][j]
  __shared__ bf16_t W1ki[32 * 66];                 // 4224 B (k,i) pairs, pad
  __shared__ bf16_t W1qb[32 * 34];                 // 2176 B
  __shared__ __align__(16) float qsh[8 * 32];      // 1024 B
  __shared__ __align__(16) float qtsh[8 * 32];     // 1024 B
  const int tid = threadIdx.x;
  const int bh = blockIdx.y, bb = bh >> 2, h = bh & 3;
  const int i0 = blockIdx.x * 8;
  const bf16_t* kgb = kbf + (size_t)(bb * KK) * DDIM + h * DH;
  const bf16_t* vgb = vbf + (size_t)(bb * KK) * DDIM + h * DH;
  const float* qg = q + (size_t)(bb * KK) * DDIM + h * DH;
  // ---- stage K (16B units, swizzled) ----
#pragma unroll
  for (int it = 0; it < 4; ++it) {
    int u = tid + it * 256;                 // < 832
    if (u < 832) {
      int j = u >> 2, bi = u & 3;
      uint4 d = {0u, 0u, 0u, 0u};
      if (j < KK) d = *(const uint4*)(kgb + (size_t)j * DDIM + bi * 8);
      *(uint4*)&ksh[j * 32 + (bi ^ ((j >> 1) & 3)) * 8] = d;
    }
  }
  // ---- stage V^T ----
#pragma unroll
  for (int it = 0; it < 13; ++it) {
    int u = tid + it * 256;                 // < 3328 = 104 j-pairs * 32 f
    int jp = u >> 5, f = u & 31;
    int j0 = jp * 2;
    bf16_t a0 = (j0 < KK) ? vgb[(size_t)j0 * DDIM + f] : (bf16_t)0.f;
    bf16_t a1 = (j0 + 1 < KK) ? vgb[(size_t)(j0 + 1) * DDIM + f] : (bf16_t)0.f;
    union { bf16_t h2[2]; unsigned uu; } pk;
    pk.h2[0] = a0; pk.h2[1] = a1;
    *(unsigned*)&vtsh[f * 224 + j0] = pk.uu;
  }
  {                                         // vtsh pad cols 208..223
    int f = tid >> 3, cp = tid & 7;
    *(unsigned*)&vtsh[f * 224 + 208 + cp * 2] = 0u;
  }
  if (tid < 64) {                           // psh pad cols 208..223
    int r = tid >> 3, cp = tid & 7;
    *(unsigned*)&psh[r * 224 + 208 + cp * 2] = 0u;
  }
  // ---- stage W1 (bf16) ----
#pragma unroll
  for (int it = 0; it < 8; ++it) {
    int u = tid + it * 256;                 // < 2048
    int sel = u & 1, f = (u >> 1) & 31, e = u >> 6;
    W1ki[e * 66 + f * 2 + sel] = (bf16_t)W1g[(32 + sel * 32 + e) * 32 + f];
  }
#pragma unroll
  for (int it = 0; it < 4; ++it) {
    int u = tid + it * 256;                 // < 1024
    int e = u >> 5, f = u & 31;
    W1qb[e * 34 + f] = (bf16_t)W1g[e * 32 + f];
  }
  {
    int il = tid >> 5, e = tid & 31;
    qsh[il * 32 + e] = qg[(size_t)(i0 + il) * DDIM + e];
  }
  __syncthreads();
  // ---- qtv = q @ W1q + b1 ----
  {
    int il = tid >> 5, f = tid & 31;
    float a = b1g[f];
#pragma unroll
    for (int e = 0; e < 32; ++e)
      a = fmaf(qsh[il * 32 + e], (float)W1qb[e * 34 + f], a);
    qtsh[il * 32 + f] = a;
  }
  __syncthreads();
  const int w = tid >> 6, lane = tid & 63;
  const int fcol = lane & 15, g = lane >> 4;
  const float w2c = 0.17677669529663687f * 1.4426950408889634f;
  float4 w2a = *(const float4*)(w2p + 4 * g);
  float4 w2b = *(const float4*)(w2p + 16 + 4 * g);
  w2a.x *= w2c; w2a.y *= w2c; w2a.z *= w2c; w2a.w *= w2c;
  w2b.x *= w2c; w2b.y *= w2c; w2b.z *= w2c; w2b.w *= w2c;
#pragma unroll
  for (int c = 0; c < 2; ++c) {
    const int il = w * 2 + c;
    const float4 qa = *(const float4*)&qsh[il * 32 + g * 8];
    const float4 qb4 = *(const float4*)&qsh[il * 32 + g * 8 + 4];
    const float qv[8] = {qa.x, qa.y, qa.z, qa.w, qb4.x, qb4.y, qb4.z, qb4.w};
    bf16x8 bw0, bw1;
#pragma unroll
    for (int e8 = 0; e8 < 8; ++e8) {
      int e = g * 8 + e8;
      union { unsigned u; bf16_t h[2]; } k0_, k1_;
      k0_.u = *(const unsigned*)&W1ki[e * 66 + fcol * 2];
      k1_.u = *(const unsigned*)&W1ki[e * 66 + (fcol + 16) * 2];
      bw0[e8] = (bf16_t)fmaf(qv[e8], (float)k0_.h[1], (float)k0_.h[0]);
      bw1[e8] = (bf16_t)fmaf(qv[e8], (float)k1_.h[1], (float)k1_.h[0]);
    }
    const float4 qta = *(const float4*)&qtsh[il * 32 + 4 * g];
    const float4 qtb = *(const float4*)&qtsh[il * 32 + 16 + 4 * g];
    float s[13];
#pragma unroll
    for (int jt = 0; jt < 13; ++jt) {
      int j = jt * 16 + fcol;
      bf16x8 af = *(const bf16x8*)&ksh[j * 32 + (g ^ ((j >> 1) & 3)) * 8];
      f32x4 acc0 = {0.f, 0.f, 0.f, 0.f}, acc1 = {0.f, 0.f, 0.f, 0.f};
      acc0 = __builtin_amdgcn_mfma_f32_16x16x32_bf16(bw0, af, acc0, 0, 0, 0);
      acc1 = __builtin_amdgcn_mfma_f32_16x16x32_bf16(bw1, af, acc1, 0, 0, 0);
      float t0 = fgelu2(acc0[0] + qta.x) * w2a.x;
      t0 = fmaf(fgelu2(acc0[1] + qta.y), w2a.y, t0);
      float t1 = fgelu2(acc0[2] + qta.z) * w2a.z;
      t1 = fmaf(fgelu2(acc0[3] + qta.w), w2a.w, t1);
      float t2 = fgelu2(acc1[0] + qtb.x) * w2b.x;
      t2 = fmaf(fgelu2(acc1[1] + qtb.y), w2b.y, t2);
      float t3 = fgelu2(acc1[2] + qtb.z) * w2b.z;
      t3 = fmaf(fgelu2(acc1[3] + qtb.w), w2b.w, t3);
      float t = (t0 + t1) + (t2 + t3);
      t += __shfl_xor(t, 16);
      t += __shfl_xor(t, 32);
      s[jt] = t;
    }
    if (fcol >= 8) s[12] = -1e30f;
    float m = s[0];
#pragma unroll
    for (int jt = 1; jt < 13; ++jt) m = fmaxf(m, s[jt]);
    m = fmaxf(m, __shfl_xor(m, 1));
    m = fmaxf(m, __shfl_xor(m, 2));
    m = fmaxf(m, __shfl_xor(m, 4));
    m = fmaxf(m, __shfl_xor(m, 8));
    float l = 0.f;
#pragma unroll
    for (int jt = 0; jt < 13; ++jt) {
      float p = exp2f(s[jt] - m);
      s[jt] = p;
      l += p;
    }
    l += __shfl_xor(l, 1);
    l += __shfl_xor(l, 2);
    l += __shfl_xor(l, 4);
    l += __shfl_xor(l, 8);
    const float inv = fastrcp(l);
    if (g == 0) {
#pragma unroll
      for (int jt = 0; jt < 13; ++jt)
        psh[il * 224 + jt * 16 + fcol] = (bf16_t)(s[jt] * inv);
    }
  }
  __syncthreads();
  // ---- PV ----
  if (w < 2) {
    f32x4 acc = {0.f, 0.f, 0.f, 0.f};
#pragma unroll
    for (int ks = 0; ks < 7; ++ks) {
      bf16x8 ap;
      if (fcol < 8) ap = *(const bf16x8*)&psh[fcol * 224 + ks * 32 + g * 8];
      else { bf16x8 z = {}; ap = z; }
      bf16x8 bv = *(const bf16x8*)&vtsh[(w * 16 + fcol) * 224 + ks * 32 + g * 8];
      acc = __builtin_amdgcn_mfma_f32_16x16x32_bf16(ap, bv, acc, 0, 0, 0);
    }
    if (g < 2) {
#pragma unroll
      for (int r = 0; r < 4; ++r) {
        int i = i0 + g * 4 + r;
        o[(size_t)(bb * KK + i) * DDIM + h * DH + w * 16 + fcol] = (bf16_t)acc[r];
      }
    }
  }
}

// ---------------- memory-slot attention rows: ma[b,s,c] --------------------
__global__ __launch_bounds__(256) void slot_ma(const float* __restrict__ B,
    const float* __restrict__ slots, float* __restrict__ ma) {
  const int bs = blockIdx.x;
  const int s = bs & 63;
  const int b = bs >> 6;
  const int tid = threadIdx.x;
  __shared__ __align__(16) float sl[128];
  __shared__ float red1[4], red2[4];
  if (tid < 128) sl[tid] = slots[(size_t)s * DDIM + tid];
  __syncthreads();
  float sc = -1e30f;
  if (tid < KK) {
    const float* br = B + (size_t)(b * KK + tid) * DDIM;
    float a = 0.f;
#pragma unroll
    for (int d4 = 0; d4 < 32; d4++) {
      float4 bb = *(const float4*)(br + d4 * 4);
      float4 ss = *(const float4*)(sl + d4 * 4);
      a += bb.x * ss.x + bb.y * ss.y + bb.z * ss.z + bb.w * ss.w;
    }
    sc = a * 0.08838834764831845f;
  }
  float mx = sc;
#pragma unroll
  for (int m = 1; m <= 32; m <<= 1) mx = fmaxf(mx, __shfl_xor(mx, m));
  if ((tid & 63) == 0) red1[tid >> 6] = mx;
  __syncthreads();
  mx = fmaxf(fmaxf(red1[0], red1[1]), fmaxf(red1[2], red1[3]));
  float p = (tid < KK) ? __expf(sc - mx) : 0.f;
  float sm = p;
#pragma unroll
  for (int m = 1; m <= 32; m <<= 1) sm += __shfl_xor(sm, m);
  if ((tid & 63) == 0) red2[tid >> 6] = sm;
  __syncthreads();
  sm = red2[0] + red2[1] + red2[2] + red2[3];
  if (tid < KK) ma[(size_t)bs * KK + tid] = p / sm;
}

// ---------------- final readout: h + LN(mem) -> head ------------------------
__global__ __launch_bounds__(256) void readout_kernel(const float* __restrict__ B,
    const float* __restrict__ ma, const float* __restrict__ task_q,
    const float* __restrict__ memg, const float* __restrict__ membt,
    const float* __restrict__ headW, const float* __restrict__ headb,
    float* __restrict__ out) {
  const int b = blockIdx.x, tid = threadIdx.x;
  __shared__ __align__(16) float tq[128];
  __shared__ float ras[KK];
  __shared__ float wc[KK];
  __shared__ float red1[4], red2[4];
  __shared__ float hv2[256], mv2[256];
  __shared__ float hv[128], mv[128], rv[128];
  __shared__ float stats[2];
  if (tid < 128) tq[tid] = task_q[tid];
  __syncthreads();
  float sc = -1e30f;
  if (tid < KK) {
    const float* br = B + (size_t)(b * KK + tid) * DDIM;
    float a = 0.f;
#pragma unroll
    for (int d4 = 0; d4 < 32; d4++) {
      float4 bb = *(const float4*)(br + d4 * 4);
      float4 ss = *(const float4*)(tq + d4 * 4);
      a += bb.x * ss.x + bb.y * ss.y + bb.z * ss.z + bb.w * ss.w;
    }
    sc = a * 0.08838834764831845f;
  }
  float mx = sc;
#pragma unroll
  for (int m = 1; m <= 32; m <<= 1) mx = fmaxf(mx, __shfl_xor(mx, m));
  if ((tid & 63) == 0) red1[tid >> 6] = mx;
  __syncthreads();
  mx = fmaxf(fmaxf(red1[0], red1[1]), fmaxf(red1[2], red1[3]));
  float p = (tid < KK) ? __expf(sc - mx) : 0.f;
  float sm = p;
#pragma unroll
  for (int m = 1; m <= 32; m <<= 1) sm += __shfl_xor(sm, m);
  if ((tid & 63) == 0) red2[tid >> 6] = sm;
  __syncthreads();
  sm = red2[0] + red2[1] + red2[2] + red2[3];
  if (tid < KK) {
    ras[tid] = p / sm;
    float a = 0.f;
    for (int s_ = 0; s_ < SSLOT; s_++) a += ma[((size_t)b * SSLOT + s_) * KK + tid];
    wc[tid] = a * (1.f / 64.f);
  }
  __syncthreads();
  {
    const int d = tid & 127, half = tid >> 7;
    float hd = 0.f, md = 0.f;
    const float* Bb = B + ((size_t)b * KK + half * 100) * DDIM + d;
    const float* rp = ras + half * 100;
    const float* wp = wc + half * 100;
#pragma unroll 2
    for (int c = 0; c < 100; ++c) {
      float bv = Bb[(size_t)c * DDIM];
      hd = fmaf(rp[c], bv, hd);
      md = fmaf(wp[c], bv, md);
    }
    hv2[tid] = hd; mv2[tid] = md;
  }
  __syncthreads();
  if (tid < 128) {
    hv[tid] = hv2[tid] + hv2[tid + 128];
    mv[tid] = mv2[tid] + mv2[tid + 128];
  }
  __syncthreads();
  if (tid < 64) {
    float x0 = mv[tid], x1 = mv[tid + 64];
    float s = x0 + x1, qq = x0 * x0 + x1 * x1;
#pragma unroll
    for (int m = 1; m <= 32; m <<= 1) { s += __shfl_xor(s, m); qq += __shfl_xor(qq, m); }
    if (tid == 0) { stats[0] = s; stats[1] = qq; }
  }
  __syncthreads();
  float mean = stats[0] * (1.f / 128.f);
  float var = stats[1] * (1.f / 128.f) - mean * mean;
  float rs = rsqrtf(var + 1e-5f);
  if (tid < 128) rv[tid] = hv[tid] + (mv[tid] - mean) * rs * memg[tid] + membt[tid];
  __syncthreads();
  if (tid < OUTN) {
    float a = headb[tid];
    for (int dd = 0; dd < 128; dd++) a = fmaf(rv[dd], headW[dd * OUTN + tid], a);
    out[b * OUTN + tid] = a;
  }
}

// ---------------------------------------------------------------------------
extern "C" void kernel_launch(void* const* d_in, const int* in_sizes, int n_in,
                              void* d_out, int out_size, void* d_ws, size_t ws_size,
                              hipStream_t stream) {
  (void)in_sizes; (void)n_in; (void)out_size; (void)ws_size;
  const float* x        = (const float*)d_in[0];
  const float* role_emb = (const float*)d_in[1];
  const float* filler_w = (const float*)d_in[2];
  const float* qW = (const float*)d_in[3];
  const float* qb = (const float*)d_in[4];
  const float* kW = (const float*)d_in[5];
  const float* kb = (const float*)d_in[6];
  const float* vW = (const float*)d_in[7];
  const float* vb = (const float*)d_in[8];
  const float* oW = (const float*)d_in[9];
  const float* ob = (const float*)d_in[10];
  const float* relW1 = (const float*)d_in[11];
  const float* relb1 = (const float*)d_in[12];
  const float* relW2 = (const float*)d_in[13];
  const float* relb2 = (const float*)d_in[14];
  const float* ln1g = (const float*)d_in[15];
  const float* ln1b = (const float*)d_in[16];
  const float* ln2g = (const float*)d_in[17];
  const float* ln2b = (const float*)d_in[18];
  const float* fW1 = (const float*)d_in[19];
  const float* fb1 = (const float*)d_in[20];
  const float* fW2 = (const float*)d_in[21];
  const float* fb2 = (const float*)d_in[22];
  const float* slots = (const float*)d_in[23];
  const float* memg = (const float*)d_in[24];
  const float* memb = (const float*)d_in[25];
  const float* taskq = (const float*)d_in[26];
  const float* headW = (const float*)d_in[27];
  const float* headb = (const float*)d_in[28];
  float* out = (float*)d_out;
  (void)relb2;  // dropped: softmax shift-invariance

  // workspace layout (float-slot offsets; all 16B aligned)
  float* fws  = (float*)d_ws;
  int*    idxb   = (int*)d_ws;                //   1600 ints
  float*  vals   = fws + 1600;                //   1600 f
  float*  btok   = fws + 3200;                // 204800 f
  float*  qbuf   = fws + 208000;              // 204800 f
  float*  mab    = fws + 412800;              // 102400 f
  bf16_t* btokbf = (bf16_t*)(fws + 515200);   // 204800 bf16
  bf16_t* kbf    = (bf16_t*)(fws + 617600);   // 204800 bf16
  bf16_t* vbf    = (bf16_t*)(fws + 720000);   // 204800 bf16
  bf16_t* obufbf = (bf16_t*)(fws + 822400);   // 204800 bf16
  bf16_t* hbuf   = (bf16_t*)(fws + 924800);   // 819200 bf16
  bf16_t* wtb    = (bf16_t*)(fws + 1334400);  // 589824 bf16 (end 1629312 ~6.5MB)
  bf16_t* qWt = wtb, *kWt = wtb + 49152, *vWt = wtb + 98304, *oWt = wtb + 147456;
  bf16_t* fW1t = wtb + 196608, *fW2t = wtb + 393216;

  wconv_kernel<<<144, 256, 0, stream>>>(qW, kW, vW, oW, fW1, fW2, wtb);
  topk_kernel<<<8, 256, 0, stream>>>(x, vals, idxb);
  bind_kernel<<<800, 256, 0, stream>>>(vals, idxb, role_emb, filler_w, btok, btokbf);
  for (int l = 0; l < LLAY; l++) {
    qkv_mfma<<<dim3(25, 3), 256, 0, stream>>>(btokbf,
        qWt + l * 16384, qb + l * 128, kWt + l * 16384, kb + l * 128,
        vWt + l * 16384, vb + l * 128, qbuf, kbf, vbf);
    rel_attn_mfma<<<dim3(25, 32), 256, 0, stream>>>(qbuf, kbf, vbf,
        relW1 + l * 3072, relb1 + l * 32, relW2 + l * 32, obufbf);
    gemmln_mfma<<<25, 256, 0, stream>>>(obufbf, 128, 128, oWt + l * 16384,
        ob + l * 128, ln1g + l * 128, ln1b + l * 128, btok, btokbf);
    ffn1_mfma<<<dim3(25, 4), 256, 0, stream>>>(btokbf, fW1t + l * 65536,
        fb1 + l * 512, hbuf);
    gemmln_mfma<<<25, 256, 0, stream>>>(hbuf, 512, 512, fW2t + l * 65536,
        fb2 + l * 128, ln2g + l * 128, ln2b + l * 128, btok, btokbf);
  }
  slot_ma<<<512, 256, 0, stream>>>(btok, slots, mab);
  readout_kernel<<<8, 256, 0, stream>>>(btok, mab, taskq, memg, memb, headW, headb, out);
}

// Round 7
// 271.336 us; speedup vs baseline: 2.6797x; 1.0162x over previous
//
#include <hip/hip_runtime.h>
#include <math.h>

#define BQ 8
#define CC 2048
#define DDIM 128
#define LLAY 3
#define HH 4
#define KK 200
#define SSLOT 64
#define OUTN 24
#define DH 32

typedef __bf16 bf16_t;
typedef __bf16 bf16x8 __attribute__((ext_vector_type(8)));
typedef float f32x4 __attribute__((ext_vector_type(4)));

__device__ __forceinline__ float fastrcp(float x) {
#if __has_builtin(__builtin_amdgcn_rcpf)
  return __builtin_amdgcn_rcpf(x);
#else
  return 1.0f / x;
#endif
}
__device__ __forceinline__ float fgelu2(float x) {
  // tanh-approx gelu: x*sigmoid(2*0.79788*(x+0.044715x^3)), exp2+v_rcp
  float xc = fminf(x, 8.f);
  float inner = fmaf(0.044715f * xc * xc, xc, xc);
  float e = exp2f(inner * 2.302118610509359f);
  return x * e * fastrcp(1.f + e);
}
__device__ __forceinline__ float egelu(float x) {
  return 0.5f * x * (1.f + erff(x * 0.7071067811865476f));
}

// ---------------- top-k over 2048 per row (binary search on float bits) ----
__global__ __launch_bounds__(256) void topk_kernel(const float* __restrict__ x,
                                                   float* __restrict__ vals,
                                                   int* __restrict__ idx) {
  const int b = blockIdx.x, tid = threadIdx.x;
  float xv[8]; unsigned xb[8];
#pragma unroll
  for (int t = 0; t < 8; t++) {
    float v = x[b * CC + t * 256 + tid];
    xv[t] = v;
    xb[t] = __float_as_uint(v);
  }
  __shared__ int red[4];
  __shared__ int cnt;
  unsigned lo = 0u, hi = 0x7f800000u;
  while (lo < hi) {
    unsigned mid = (lo + hi) >> 1;
    int c = 0;
#pragma unroll
    for (int t = 0; t < 8; t++) c += (xb[t] > mid) ? 1 : 0;
#pragma unroll
    for (int m = 1; m <= 32; m <<= 1) c += __shfl_xor(c, m);
    if ((tid & 63) == 0) red[tid >> 6] = c;
    __syncthreads();
    int ct = red[0] + red[1] + red[2] + red[3];
    __syncthreads();
    if (ct >= KK) lo = mid + 1; else hi = mid;
  }
  const unsigned thr = lo;
  if (tid == 0) cnt = 0;
  __syncthreads();
#pragma unroll
  for (int t = 0; t < 8; t++) {
    if (xb[t] > thr) {
      int p = atomicAdd(&cnt, 1);
      vals[b * KK + p] = log1pf(xv[t]);
      idx[b * KK + p] = t * 256 + tid;
    }
  }
  __syncthreads();
#pragma unroll
  for (int t = 0; t < 8; t++) {
    if (xb[t] == thr) {
      int p = atomicAdd(&cnt, 1);
      if (p < KK) {
        vals[b * KK + p] = log1pf(xv[t]);
        idx[b * KK + p] = t * 256 + tid;
      }
    }
  }
}

// ---------------- weight convert+transpose: f32 row-major -> bf16 col-major -
__global__ __launch_bounds__(256) void wconv_kernel(
    const float* __restrict__ qW, const float* __restrict__ kW,
    const float* __restrict__ vW, const float* __restrict__ oW,
    const float* __restrict__ fW1, const float* __restrict__ fW2,
    bf16_t* __restrict__ wtb) {
  __shared__ float Ts[64][65];
  const int t = blockIdx.x, tid = threadIdx.x;
  const float* src; bf16_t* dst; int N, K, k0, n0;
  if (t < 48) {
    int which = t / 12, rem = t % 12;
    int l = rem >> 2, tt = rem & 3;
    N = 128; K = 128; k0 = (tt >> 1) * 64; n0 = (tt & 1) * 64;
    src = (which == 0 ? qW : which == 1 ? kW : which == 2 ? vW : oW) + l * 16384;
    dst = wtb + which * 49152 + l * 16384;
  } else if (t < 96) {
    int t2 = t - 48, l = t2 >> 4, tt = t2 & 15;
    N = 512; K = 128; k0 = (tt >> 3) * 64; n0 = (tt & 7) * 64;
    src = fW1 + l * 65536;
    dst = wtb + 196608 + l * 65536;
  } else {
    int t3 = t - 96, l = t3 >> 4, tt = t3 & 15;
    N = 128; K = 512; k0 = (tt >> 1) * 64; n0 = (tt & 1) * 64;
    src = fW2 + l * 65536;
    dst = wtb + 393216 + l * 65536;
  }
#pragma unroll
  for (int i = 0; i < 16; ++i) {
    int u = tid + i * 256;
    int r = u >> 6, c = u & 63;
    Ts[r][c] = src[(size_t)(k0 + r) * N + n0 + c];
  }
  __syncthreads();
#pragma unroll
  for (int i = 0; i < 16; ++i) {
    int u = tid + i * 256;
    int rn = u >> 6, ck = u & 63;
    dst[(size_t)(n0 + rn) * K + k0 + ck] = (bf16_t)Ts[ck][rn];
  }
}

// ---------------- b = role_emb[idx] * gelu(val * filler_w) -----------------
__global__ __launch_bounds__(256) void bind_kernel(const float* __restrict__ vals,
    const int* __restrict__ idx, const float* __restrict__ role_emb,
    const float* __restrict__ fw, float* __restrict__ btok,
    bf16_t* __restrict__ btokbf) {
  int u = blockIdx.x * 256 + threadIdx.x;  // < 204800
  int dd = u & 127;
  int r = u >> 7;
  int b = r / KK, t = r - b * KK;
  float v = vals[b * KK + t];
  float fill = egelu(v * fw[dd]);
  float val = role_emb[(size_t)idx[b * KK + t] * DDIM + dd] * fill;
  btok[u] = val;
  btokbf[u] = (bf16_t)val;
}

// ====== MFMA GEMM blocks: BM=64, BN=128, bf16 col-major weights ============

// ---------------- qkv: z selects q/k/v; q -> f32; k,v -> bf16 --------------
__global__ __launch_bounds__(256) void qkv_mfma(const bf16_t* __restrict__ A,
    const bf16_t* __restrict__ qWt, const float* __restrict__ qb,
    const bf16_t* __restrict__ kWt, const float* __restrict__ kb,
    const bf16_t* __restrict__ vWt, const float* __restrict__ vb,
    float* __restrict__ qo, bf16_t* __restrict__ ko, bf16_t* __restrict__ vo) {
  __shared__ __align__(16) bf16_t Alds[64 * 16 * 8];
  __shared__ __align__(16) bf16_t Blds[128 * 16 * 8];
  const int tid = threadIdx.x, m0 = blockIdx.x * 64, z = blockIdx.y;
  const bf16_t* Wt; const float* bias;
  if (z == 0) { Wt = qWt; bias = qb; }
  else if (z == 1) { Wt = kWt; bias = kb; }
  else { Wt = vWt; bias = vb; }
#pragma unroll
  for (int it = 0; it < 4; ++it) {
    int u = tid + it * 256;
    int row = u >> 4, kc = u & 15;
    uint4 d = *(const uint4*)(A + (size_t)(m0 + row) * 128 + kc * 8);
    *(uint4*)&Alds[(row * 16 + (kc ^ (row & 7))) * 8] = d;
  }
#pragma unroll
  for (int it = 0; it < 8; ++it) {
    int u = tid + it * 256;
    int col = u >> 4, kcb = u & 15;
    uint4 d = *(const uint4*)(Wt + (size_t)col * 128 + kcb * 8);
    *(uint4*)&Blds[(col * 16 + (kcb ^ (col & 7))) * 8] = d;
  }
  __syncthreads();
  const int w = tid >> 6, lane = tid & 63, fcol = lane & 15, g = lane >> 4;
  f32x4 acc[8];
#pragma unroll
  for (int ni = 0; ni < 8; ++ni) acc[ni] = (f32x4){0.f, 0.f, 0.f, 0.f};
#pragma unroll
  for (int ks = 0; ks < 4; ++ks) {
    const int arow = 16 * w + fcol;
    bf16x8 a = *(const bf16x8*)&Alds[(arow * 16 + ((ks * 4 + g) ^ (arow & 7))) * 8];
#pragma unroll
    for (int ni = 0; ni < 8; ++ni) {
      const int bcol = ni * 16 + fcol;
      bf16x8 b = *(const bf16x8*)&Blds[(bcol * 16 + ((ks * 4 + g) ^ (bcol & 7))) * 8];
      acc[ni] = __builtin_amdgcn_mfma_f32_16x16x32_bf16(a, b, acc[ni], 0, 0, 0);
    }
  }
#pragma unroll
  for (int ni = 0; ni < 8; ++ni) {
    const int col = ni * 16 + fcol;
    const float bv = bias[col];
#pragma unroll
    for (int r = 0; r < 4; ++r) {
      const int row = m0 + 16 * w + 4 * g + r;
      float val = acc[ni][r] + bv;
      if (z == 0) qo[(size_t)row * 128 + col] = val;
      else if (z == 1) ko[(size_t)row * 128 + col] = (bf16_t)val;
      else vo[(size_t)row * 128 + col] = (bf16_t)val;
    }
  }
}

// ---------------- gemm + residual + LayerNorm (oproj path) -----------------
__global__ __launch_bounds__(256) void gemmln_mfma(const bf16_t* __restrict__ A,
    int lda, int K, const bf16_t* __restrict__ Wt, const float* __restrict__ bias,
    const float* __restrict__ lng, const float* __restrict__ lnb,
    float* __restrict__ btok, bf16_t* __restrict__ btokbf) {
  __shared__ __align__(16) bf16_t Alds[64 * 16 * 8];
  __shared__ __align__(16) bf16_t Blds[128 * 16 * 8];
  const int tid = threadIdx.x, m0 = blockIdx.x * 64;
  const int w = tid >> 6, lane = tid & 63, fcol = lane & 15, g = lane >> 4;
  f32x4 acc[8];
#pragma unroll
  for (int ni = 0; ni < 8; ++ni) acc[ni] = (f32x4){0.f, 0.f, 0.f, 0.f};
  for (int kc0 = 0; kc0 < K; kc0 += 128) {
    if (kc0) __syncthreads();
#pragma unroll
    for (int it = 0; it < 4; ++it) {
      int u = tid + it * 256;
      int row = u >> 4, kc = u & 15;
      uint4 d = *(const uint4*)(A + (size_t)(m0 + row) * lda + kc0 + kc * 8);
      *(uint4*)&Alds[(row * 16 + (kc ^ (row & 7))) * 8] = d;
    }
#pragma unroll
    for (int it = 0; it < 8; ++it) {
      int u = tid + it * 256;
      int col = u >> 4, kcb = u & 15;
      uint4 d = *(const uint4*)(Wt + (size_t)col * K + kc0 + kcb * 8);
      *(uint4*)&Blds[(col * 16 + (kcb ^ (col & 7))) * 8] = d;
    }
    __syncthreads();
#pragma unroll
    for (int ks = 0; ks < 4; ++ks) {
      const int arow = 16 * w + fcol;
      bf16x8 a = *(const bf16x8*)&Alds[(arow * 16 + ((ks * 4 + g) ^ (arow & 7))) * 8];
#pragma unroll
      for (int ni = 0; ni < 8; ++ni) {
        const int bcol = ni * 16 + fcol;
        bf16x8 b = *(const bf16x8*)&Blds[(bcol * 16 + ((ks * 4 + g) ^ (bcol & 7))) * 8];
        acc[ni] = __builtin_amdgcn_mfma_f32_16x16x32_bf16(a, b, acc[ni], 0, 0, 0);
      }
    }
  }
  float t[8][4];
  float s0 = 0.f, s1 = 0.f, s2 = 0.f, s3 = 0.f;
  float q0 = 0.f, q1 = 0.f, q2 = 0.f, q3 = 0.f;
#pragma unroll
  for (int ni = 0; ni < 8; ++ni) {
    const int col = ni * 16 + fcol;
    const float bv = bias[col];
#pragma unroll
    for (int r = 0; r < 4; ++r) {
      const int row = m0 + 16 * w + 4 * g + r;
      float val = acc[ni][r] + bv + btok[(size_t)row * 128 + col];
      t[ni][r] = val;
      if (r == 0) { s0 += val; q0 += val * val; }
      else if (r == 1) { s1 += val; q1 += val * val; }
      else if (r == 2) { s2 += val; q2 += val * val; }
      else { s3 += val; q3 += val * val; }
    }
  }
#pragma unroll
  for (int m = 1; m <= 8; m <<= 1) {
    s0 += __shfl_xor(s0, m); q0 += __shfl_xor(q0, m);
    s1 += __shfl_xor(s1, m); q1 += __shfl_xor(q1, m);
    s2 += __shfl_xor(s2, m); q2 += __shfl_xor(q2, m);
    s3 += __shfl_xor(s3, m); q3 += __shfl_xor(q3, m);
  }
  float mean[4], rs[4];
  mean[0] = s0 * (1.f / 128.f); mean[1] = s1 * (1.f / 128.f);
  mean[2] = s2 * (1.f / 128.f); mean[3] = s3 * (1.f / 128.f);
  rs[0] = rsqrtf(q0 * (1.f / 128.f) - mean[0] * mean[0] + 1e-5f);
  rs[1] = rsqrtf(q1 * (1.f / 128.f) - mean[1] * mean[1] + 1e-5f);
  rs[2] = rsqrtf(q2 * (1.f / 128.f) - mean[2] * mean[2] + 1e-5f);
  rs[3] = rsqrtf(q3 * (1.f / 128.f) - mean[3] * mean[3] + 1e-5f);
#pragma unroll
  for (int ni = 0; ni < 8; ++ni) {
    const int col = ni * 16 + fcol;
    const float gv = lng[col], bv2 = lnb[col];
#pragma unroll
    for (int r = 0; r < 4; ++r) {
      const int row = m0 + 16 * w + 4 * g + r;
      float o = (t[ni][r] - mean[r]) * rs[r] * gv + bv2;
      btok[(size_t)row * 128 + col] = o;
      btokbf[(size_t)row * 128 + col] = (bf16_t)o;
    }
  }
}

// ---------------- fused FFN: btok = LN2(btok + gelu(btok@W1+b1)@W2+b2) -----
// hbuf lives entirely in swizzled LDS; W1/W2 streamed through one 32KB buffer.
__global__ __launch_bounds__(256) void ffn_fused(const bf16_t* __restrict__ Abf,
    const bf16_t* __restrict__ W1t, const float* __restrict__ b1,
    const bf16_t* __restrict__ W2t, const float* __restrict__ b2,
    const float* __restrict__ lng, const float* __restrict__ lnb,
    float* __restrict__ btok, bf16_t* __restrict__ btokbf) {
  __shared__ __align__(16) bf16_t Alds[64 * 16 * 8];   // 16KB
  __shared__ __align__(16) bf16_t Blds[128 * 16 * 8];  // 32KB (streamed)
  __shared__ __align__(16) bf16_t Hlds[64 * 512];      // 64KB hbuf, 16B-swz
  const int tid = threadIdx.x, m0 = blockIdx.x * 64;
  const int w = tid >> 6, lane = tid & 63, fcol = lane & 15, g = lane >> 4;
#pragma unroll
  for (int it = 0; it < 4; ++it) {
    int u = tid + it * 256;
    int row = u >> 4, kc = u & 15;
    uint4 d = *(const uint4*)(Abf + (size_t)(m0 + row) * 128 + kc * 8);
    *(uint4*)&Alds[(row * 16 + (kc ^ (row & 7))) * 8] = d;
  }
  // ---- phase 1: hbuf = gelu(A@W1+b1), 4 n-chunks of 128 ----
  for (int nc = 0; nc < 4; ++nc) {
#pragma unroll
    for (int it = 0; it < 8; ++it) {
      int u = tid + it * 256;
      int col = u >> 4, kcb = u & 15;
      uint4 d = *(const uint4*)(W1t + (size_t)(nc * 128 + col) * 128 + kcb * 8);
      *(uint4*)&Blds[(col * 16 + (kcb ^ (col & 7))) * 8] = d;
    }
    __syncthreads();
    f32x4 acc[8];
#pragma unroll
    for (int ni = 0; ni < 8; ++ni) acc[ni] = (f32x4){0.f, 0.f, 0.f, 0.f};
#pragma unroll
    for (int ks = 0; ks < 4; ++ks) {
      const int arow = 16 * w + fcol;
      bf16x8 a = *(const bf16x8*)&Alds[(arow * 16 + ((ks * 4 + g) ^ (arow & 7))) * 8];
#pragma unroll
      for (int ni = 0; ni < 8; ++ni) {
        const int bcol = ni * 16 + fcol;
        bf16x8 b = *(const bf16x8*)&Blds[(bcol * 16 + ((ks * 4 + g) ^ (bcol & 7))) * 8];
        acc[ni] = __builtin_amdgcn_mfma_f32_16x16x32_bf16(a, b, acc[ni], 0, 0, 0);
      }
    }
#pragma unroll
    for (int ni = 0; ni < 8; ++ni) {
      const int c = nc * 128 + ni * 16 + fcol;
      const float bv = b1[c];
      const int kb = c >> 3, within = c & 7;
#pragma unroll
      for (int r = 0; r < 4; ++r) {
        const int row = 16 * w + 4 * g + r;
        const int kbs = kb ^ (row & 7);
        Hlds[row * 512 + kbs * 8 + within] = (bf16_t)egelu(acc[ni][r] + bv);
      }
    }
    __syncthreads();
  }
  // ---- phase 2: out = hbuf@W2 + b2 + residual -> LN2 ----
  f32x4 acc2[8];
#pragma unroll
  for (int ni = 0; ni < 8; ++ni) acc2[ni] = (f32x4){0.f, 0.f, 0.f, 0.f};
  for (int kc = 0; kc < 4; ++kc) {
    if (kc) __syncthreads();
#pragma unroll
    for (int it = 0; it < 8; ++it) {
      int u = tid + it * 256;
      int col = u >> 4, kcb = u & 15;
      uint4 d = *(const uint4*)(W2t + (size_t)col * 512 + kc * 128 + kcb * 8);
      *(uint4*)&Blds[(col * 16 + (kcb ^ (col & 7))) * 8] = d;
    }
    __syncthreads();
#pragma unroll
    for (int ks = 0; ks < 4; ++ks) {
      const int arow = 16 * w + fcol;
      const int kb = kc * 16 + ks * 4 + g;
      const int kbs = kb ^ (arow & 7);
      bf16x8 a = *(const bf16x8*)&Hlds[arow * 512 + kbs * 8];
#pragma unroll
      for (int ni = 0; ni < 8; ++ni) {
        const int bcol = ni * 16 + fcol;
        bf16x8 b = *(const bf16x8*)&Blds[(bcol * 16 + ((ks * 4 + g) ^ (bcol & 7))) * 8];
        acc2[ni] = __builtin_amdgcn_mfma_f32_16x16x32_bf16(a, b, acc2[ni], 0, 0, 0);
      }
    }
  }
  float t[8][4];
  float s0 = 0.f, s1 = 0.f, s2 = 0.f, s3 = 0.f;
  float q0 = 0.f, q1 = 0.f, q2 = 0.f, q3 = 0.f;
#pragma unroll
  for (int ni = 0; ni < 8; ++ni) {
    const int col = ni * 16 + fcol;
    const float bv = b2[col];
#pragma unroll
    for (int r = 0; r < 4; ++r) {
      const int row = m0 + 16 * w + 4 * g + r;
      float val = acc2[ni][r] + bv + btok[(size_t)row * 128 + col];
      t[ni][r] = val;
      if (r == 0) { s0 += val; q0 += val * val; }
      else if (r == 1) { s1 += val; q1 += val * val; }
      else if (r == 2) { s2 += val; q2 += val * val; }
      else { s3 += val; q3 += val * val; }
    }
  }
#pragma unroll
  for (int m = 1; m <= 8; m <<= 1) {
    s0 += __shfl_xor(s0, m); q0 += __shfl_xor(q0, m);
    s1 += __shfl_xor(s1, m); q1 += __shfl_xor(q1, m);
    s2 += __shfl_xor(s2, m); q2 += __shfl_xor(q2, m);
    s3 += __shfl_xor(s3, m); q3 += __shfl_xor(q3, m);
  }
  float mean[4], rs[4];
  mean[0] = s0 * (1.f / 128.f); mean[1] = s1 * (1.f / 128.f);
  mean[2] = s2 * (1.f / 128.f); mean[3] = s3 * (1.f / 128.f);
  rs[0] = rsqrtf(q0 * (1.f / 128.f) - mean[0] * mean[0] + 1e-5f);
  rs[1] = rsqrtf(q1 * (1.f / 128.f) - mean[1] * mean[1] + 1e-5f);
  rs[2] = rsqrtf(q2 * (1.f / 128.f) - mean[2] * mean[2] + 1e-5f);
  rs[3] = rsqrtf(q3 * (1.f / 128.f) - mean[3] * mean[3] + 1e-5f);
#pragma unroll
  for (int ni = 0; ni < 8; ++ni) {
    const int col = ni * 16 + fcol;
    const float gv = lng[col], bv2 = lnb[col];
#pragma unroll
    for (int r = 0; r < 4; ++r) {
      const int row = m0 + 16 * w + 4 * g + r;
      float o = (t[ni][r] - mean[r]) * rs[r] * gv + bv2;
      btok[(size_t)row * 128 + col] = o;
      btokbf[(size_t)row * 128 + col] = (bf16_t)o;
    }
  }
}

// ---------------- fused relational attention v6: no spill, C-init=qtv ------
__global__ __launch_bounds__(256, 3) void rel_attn_mfma(
    const float* __restrict__ q, const bf16_t* __restrict__ kbf,
    const bf16_t* __restrict__ vbf,
    const float* __restrict__ W1g, const float* __restrict__ b1g,
    const float* __restrict__ w2p, bf16_t* __restrict__ o) {
  __shared__ __align__(16) bf16_t ksh[208 * 32];   // 13312 B, 16B-block swizz
  __shared__ __align__(16) bf16_t vtsh[32 * 224];  // 14336 B, V^T [f'][j]
  __shared__ __align__(16) bf16_t psh[8 * 224];    // 3584 B, P [i][j]
  __shared__ bf16_t W1ki[32 * 66];                 // 4224 B (k,i) pairs, pad
  __shared__ bf16_t W1qb[32 * 34];                 // 2176 B
  __shared__ __align__(16) float qsh[8 * 32];      // 1024 B
  __shared__ __align__(16) float qtsh[8 * 32];     // 1024 B
  const int tid = threadIdx.x;
  const int bh = blockIdx.y, bb = bh >> 2, h = bh & 3;
  const int i0 = blockIdx.x * 8;
  const bf16_t* kgb = kbf + (size_t)(bb * KK) * DDIM + h * DH;
  const bf16_t* vgb = vbf + (size_t)(bb * KK) * DDIM + h * DH;
  const float* qg = q + (size_t)(bb * KK) * DDIM + h * DH;
#pragma unroll
  for (int it = 0; it < 4; ++it) {
    int u = tid + it * 256;                 // < 832
    if (u < 832) {
      int j = u >> 2, bi = u & 3;
      uint4 d = {0u, 0u, 0u, 0u};
      if (j < KK) d = *(const uint4*)(kgb + (size_t)j * DDIM + bi * 8);
      *(uint4*)&ksh[j * 32 + (bi ^ ((j >> 1) & 3)) * 8] = d;
    }
  }
#pragma unroll
  for (int it = 0; it < 13; ++it) {
    int u = tid + it * 256;                 // < 3328 = 104 j-pairs * 32 f
    int jp = u >> 5, f = u & 31;
    int j0 = jp * 2;
    bf16_t a0 = (j0 < KK) ? vgb[(size_t)j0 * DDIM + f] : (bf16_t)0.f;
    bf16_t a1 = (j0 + 1 < KK) ? vgb[(size_t)(j0 + 1) * DDIM + f] : (bf16_t)0.f;
    union { bf16_t h2[2]; unsigned uu; } pk;
    pk.h2[0] = a0; pk.h2[1] = a1;
    *(unsigned*)&vtsh[f * 224 + j0] = pk.uu;
  }
  {
    int f = tid >> 3, cp = tid & 7;
    *(unsigned*)&vtsh[f * 224 + 208 + cp * 2] = 0u;
  }
  if (tid < 64) {
    int r = tid >> 3, cp = tid & 7;
    *(unsigned*)&psh[r * 224 + 208 + cp * 2] = 0u;
  }
#pragma unroll
  for (int it = 0; it < 8; ++it) {
    int u = tid + it * 256;                 // < 2048
    int sel = u & 1, f = (u >> 1) & 31, e = u >> 6;
    W1ki[e * 66 + f * 2 + sel] = (bf16_t)W1g[(32 + sel * 32 + e) * 32 + f];
  }
#pragma unroll
  for (int it = 0; it < 4; ++it) {
    int u = tid + it * 256;                 // < 1024
    int e = u >> 5, f = u & 31;
    W1qb[e * 34 + f] = (bf16_t)W1g[e * 32 + f];
  }
  {
    int il = tid >> 5, e = tid & 31;
    qsh[il * 32 + e] = qg[(size_t)(i0 + il) * DDIM + e];
  }
  __syncthreads();
  {
    int il = tid >> 5, f = tid & 31;
    float a = b1g[f];
#pragma unroll
    for (int e = 0; e < 32; ++e)
      a = fmaf(qsh[il * 32 + e], (float)W1qb[e * 34 + f], a);
    qtsh[il * 32 + f] = a;
  }
  __syncthreads();
  const int w = tid >> 6, lane = tid & 63;
  const int fcol = lane & 15, g = lane >> 4;
  const float w2c = 0.17677669529663687f * 1.4426950408889634f;
  float4 w2a = *(const float4*)(w2p + 4 * g);
  float4 w2b = *(const float4*)(w2p + 16 + 4 * g);
  w2a.x *= w2c; w2a.y *= w2c; w2a.z *= w2c; w2a.w *= w2c;
  w2b.x *= w2c; w2b.y *= w2c; w2b.z *= w2c; w2b.w *= w2c;
#pragma unroll
  for (int c = 0; c < 2; ++c) {
    const int il = w * 2 + c;
    const float4 qa = *(const float4*)&qsh[il * 32 + g * 8];
    const float4 qb4 = *(const float4*)&qsh[il * 32 + g * 8 + 4];
    const float qv[8] = {qa.x, qa.y, qa.z, qa.w, qb4.x, qb4.y, qb4.z, qb4.w};
    bf16x8 bw0, bw1;
#pragma unroll
    for (int e8 = 0; e8 < 8; ++e8) {
      int e = g * 8 + e8;
      union { unsigned u; bf16_t h[2]; } k0_, k1_;
      k0_.u = *(const unsigned*)&W1ki[e * 66 + fcol * 2];
      k1_.u = *(const unsigned*)&W1ki[e * 66 + (fcol + 16) * 2];
      bw0[e8] = (bf16_t)fmaf(qv[e8], (float)k0_.h[1], (float)k0_.h[0]);
      bw1[e8] = (bf16_t)fmaf(qv[e8], (float)k1_.h[1], (float)k1_.h[0]);
    }
    const float4 qta = *(const float4*)&qtsh[il * 32 + 4 * g];
    const float4 qtb = *(const float4*)&qtsh[il * 32 + 16 + 4 * g];
    const f32x4 cin0 = {qta.x, qta.y, qta.z, qta.w};
    const f32x4 cin1 = {qtb.x, qtb.y, qtb.z, qtb.w};
    float s[13];
#pragma unroll
    for (int jt = 0; jt < 13; ++jt) {
      int j = jt * 16 + fcol;
      bf16x8 af = *(const bf16x8*)&ksh[j * 32 + (g ^ ((j >> 1) & 3)) * 8];
      f32x4 acc0 = __builtin_amdgcn_mfma_f32_16x16x32_bf16(bw0, af, cin0, 0, 0, 0);
      f32x4 acc1 = __builtin_amdgcn_mfma_f32_16x16x32_bf16(bw1, af, cin1, 0, 0, 0);
      float t0 = fgelu2(acc0[0]) * w2a.x;
      t0 = fmaf(fgelu2(acc0[1]), w2a.y, t0);
      float t1 = fgelu2(acc0[2]) * w2a.z;
      t1 = fmaf(fgelu2(acc0[3]), w2a.w, t1);
      float t2 = fgelu2(acc1[0]) * w2b.x;
      t2 = fmaf(fgelu2(acc1[1]), w2b.y, t2);
      float t3 = fgelu2(acc1[2]) * w2b.z;
      t3 = fmaf(fgelu2(acc1[3]), w2b.w, t3);
      float t = (t0 + t1) + (t2 + t3);
      t += __shfl_xor(t, 16);
      t += __shfl_xor(t, 32);
      s[jt] = t;
    }
    if (fcol >= 8) s[12] = -1e30f;
    float m = s[0];
#pragma unroll
    for (int jt = 1; jt < 13; ++jt) m = fmaxf(m, s[jt]);
    m = fmaxf(m, __shfl_xor(m, 1));
    m = fmaxf(m, __shfl_xor(m, 2));
    m = fmaxf(m, __shfl_xor(m, 4));
    m = fmaxf(m, __shfl_xor(m, 8));
    float l = 0.f;
#pragma unroll
    for (int jt = 0; jt < 13; ++jt) {
      float p = exp2f(s[jt] - m);
      s[jt] = p;
      l += p;
    }
    l += __shfl_xor(l, 1);
    l += __shfl_xor(l, 2);
    l += __shfl_xor(l, 4);
    l += __shfl_xor(l, 8);
    const float inv = fastrcp(l);
    if (g == 0) {
#pragma unroll
      for (int jt = 0; jt < 13; ++jt)
        psh[il * 224 + jt * 16 + fcol] = (bf16_t)(s[jt] * inv);
    }
  }
  __syncthreads();
  if (w < 2) {
    f32x4 acc = {0.f, 0.f, 0.f, 0.f};
#pragma unroll
    for (int ks = 0; ks < 7; ++ks) {
      bf16x8 ap;
      if (fcol < 8) ap = *(const bf16x8*)&psh[fcol * 224 + ks * 32 + g * 8];
      else { bf16x8 z = {}; ap = z; }
      bf16x8 bv = *(const bf16x8*)&vtsh[(w * 16 + fcol) * 224 + ks * 32 + g * 8];
      acc = __builtin_amdgcn_mfma_f32_16x16x32_bf16(ap, bv, acc, 0, 0, 0);
    }
    if (g < 2) {
#pragma unroll
      for (int r = 0; r < 4; ++r) {
        int i = i0 + g * 4 + r;
        o[(size_t)(bb * KK + i) * DDIM + h * DH + w * 16 + fcol] = (bf16_t)acc[r];
      }
    }
  }
}

// ---------------- fused readout: slot-attention + task readout + head ------
// wc[c] = (1/64) sum_s softmax_c(slots_s . b_c / sqrt(128)); scores via MFMA.
__global__ __launch_bounds__(256) void readout_fused(const float* __restrict__ B,
    const bf16_t* __restrict__ Bbf, const float* __restrict__ slots,
    const float* __restrict__ task_q, const float* __restrict__ memg,
    const float* __restrict__ membt, const float* __restrict__ headW,
    const float* __restrict__ headb, float* __restrict__ out) {
  __shared__ __align__(16) bf16_t Ssh[64 * 16 * 8];   // slots bf16 swz 16KB
  __shared__ __align__(16) bf16_t Bsh[208 * 128];     // b rows bf16 swz 53KB
  __shared__ float wcsh[4][208];
  __shared__ __align__(16) float tq[128];
  __shared__ float ras[KK];
  __shared__ float wc[208];
  __shared__ float red1[4], red2[4];
  __shared__ float hv2[256], mv2[256];
  __shared__ float hv[128], mv[128], rv[128];
  __shared__ float stats[2];
  const int b = blockIdx.x, tid = threadIdx.x;
  const int w = tid >> 6, lane = tid & 63, fcol = lane & 15, g = lane >> 4;
  // stage slots -> bf16 swizzled A-layout
#pragma unroll
  for (int it = 0; it < 4; ++it) {
    int u = tid + it * 256;                 // < 1024 = 64 rows * 16 kb
    int row = u >> 4, kb = u & 15;
    const float* sp = slots + (size_t)row * 128 + kb * 8;
    bf16_t tmp[8];
#pragma unroll
    for (int e = 0; e < 8; ++e) tmp[e] = (bf16_t)sp[e];
    *(uint4*)&Ssh[(row * 16 + (kb ^ (row & 7))) * 8] = *(uint4*)tmp;
  }
  // stage b rows (bf16 source) swizzled B-layout
#pragma unroll
  for (int it = 0; it < 13; ++it) {
    int u = tid + it * 256;                 // < 3328 = 208 c * 16 kb
    int c = u >> 4, kb = u & 15;
    uint4 d = {0u, 0u, 0u, 0u};
    if (c < KK) d = *(const uint4*)(Bbf + (size_t)(b * KK + c) * 128 + kb * 8);
    *(uint4*)&Bsh[(c * 16 + (kb ^ (c & 7))) * 8] = d;
  }
  if (tid < 128) tq[tid] = task_q[tid];
  __syncthreads();
  // ---- slot scores via MFMA: s-tile = wave, c-tiles 13 ----
  {
    bf16x8 afr[4];
#pragma unroll
    for (int ks = 0; ks < 4; ++ks) {
      const int arow = 16 * w + fcol;
      afr[ks] = *(const bf16x8*)&Ssh[(arow * 16 + ((ks * 4 + g) ^ (arow & 7))) * 8];
    }
    f32x4 acc[13];
#pragma unroll
    for (int ct = 0; ct < 13; ++ct) {
      acc[ct] = (f32x4){0.f, 0.f, 0.f, 0.f};
#pragma unroll
      for (int ks = 0; ks < 4; ++ks) {
        const int bcol = ct * 16 + fcol;
        bf16x8 bb = *(const bf16x8*)&Bsh[(bcol * 16 + ((ks * 4 + g) ^ (bcol & 7))) * 8];
        acc[ct] = __builtin_amdgcn_mfma_f32_16x16x32_bf16(afr[ks], bb, acc[ct], 0, 0, 0);
      }
    }
    if (fcol >= 8) { acc[12][0] = -1e30f; acc[12][1] = -1e30f; acc[12][2] = -1e30f; acc[12][3] = -1e30f; }
    const float s2 = 0.08838834764831845f * 1.4426950408889634f;  // log2e/sqrt(128)
    float wcp[13];
#pragma unroll
    for (int ct = 0; ct < 13; ++ct) wcp[ct] = 0.f;
#pragma unroll
    for (int r = 0; r < 4; ++r) {
      float m = acc[0][r];
#pragma unroll
      for (int ct = 1; ct < 13; ++ct) m = fmaxf(m, acc[ct][r]);
      m = fmaxf(m, __shfl_xor(m, 1));
      m = fmaxf(m, __shfl_xor(m, 2));
      m = fmaxf(m, __shfl_xor(m, 4));
      m = fmaxf(m, __shfl_xor(m, 8));
      float l = 0.f;
      float p[13];
#pragma unroll
      for (int ct = 0; ct < 13; ++ct) {
        p[ct] = exp2f((acc[ct][r] - m) * s2);
        l += p[ct];
      }
      l += __shfl_xor(l, 1);
      l += __shfl_xor(l, 2);
      l += __shfl_xor(l, 4);
      l += __shfl_xor(l, 8);
      const float inv = fastrcp(l);
#pragma unroll
      for (int ct = 0; ct < 13; ++ct) wcp[ct] = fmaf(p[ct], inv, wcp[ct]);
    }
#pragma unroll
    for (int ct = 0; ct < 13; ++ct) {
      wcp[ct] += __shfl_xor(wcp[ct], 16);
      wcp[ct] += __shfl_xor(wcp[ct], 32);
      if (g == 0) wcsh[w][ct * 16 + fcol] = wcp[ct];
    }
  }
  // ---- ra = softmax(b . task_q / sqrt(128)) ----
  float sc = -1e30f;
  if (tid < KK) {
    const float* br = B + (size_t)(b * KK + tid) * DDIM;
    float a = 0.f;
#pragma unroll
    for (int d4 = 0; d4 < 32; d4++) {
      float4 bb = *(const float4*)(br + d4 * 4);
      float4 ss = *(const float4*)(tq + d4 * 4);
      a += bb.x * ss.x + bb.y * ss.y + bb.z * ss.z + bb.w * ss.w;
    }
    sc = a * 0.08838834764831845f;
  }
  float mx = sc;
#pragma unroll
  for (int m = 1; m <= 32; m <<= 1) mx = fmaxf(mx, __shfl_xor(mx, m));
  if ((tid & 63) == 0) red1[tid >> 6] = mx;
  __syncthreads();
  mx = fmaxf(fmaxf(red1[0], red1[1]), fmaxf(red1[2], red1[3]));
  float p = (tid < KK) ? __expf(sc - mx) : 0.f;
  float sm = p;
#pragma unroll
  for (int m = 1; m <= 32; m <<= 1) sm += __shfl_xor(sm, m);
  if ((tid & 63) == 0) red2[tid >> 6] = sm;
  __syncthreads();
  sm = red2[0] + red2[1] + red2[2] + red2[3];
  if (tid < KK) ras[tid] = p / sm;
  if (tid < 208)
    wc[tid] = (wcsh[0][tid] + wcsh[1][tid] + wcsh[2][tid] + wcsh[3][tid]) * (1.f / 64.f);
  __syncthreads();
  // ---- hv = ras @ B ; mv = wc @ B ----
  {
    const int d = tid & 127, half = tid >> 7;
    float hd = 0.f, md = 0.f;
    const float* Bb = B + ((size_t)b * KK + half * 100) * DDIM + d;
    const float* rp = ras + half * 100;
    const float* wp = wc + half * 100;
#pragma unroll 2
    for (int c = 0; c < 100; ++c) {
      float bv = Bb[(size_t)c * DDIM];
      hd = fmaf(rp[c], bv, hd);
      md = fmaf(wp[c], bv, md);
    }
    hv2[tid] = hd; mv2[tid] = md;
  }
  __syncthreads();
  if (tid < 128) {
    hv[tid] = hv2[tid] + hv2[tid + 128];
    mv[tid] = mv2[tid] + mv2[tid + 128];
  }
  __syncthreads();
  if (tid < 64) {
    float x0 = mv[tid], x1 = mv[tid + 64];
    float s = x0 + x1, qq = x0 * x0 + x1 * x1;
#pragma unroll
    for (int m = 1; m <= 32; m <<= 1) { s += __shfl_xor(s, m); qq += __shfl_xor(qq, m); }
    if (tid == 0) { stats[0] = s; stats[1] = qq; }
  }
  __syncthreads();
  float mean = stats[0] * (1.f / 128.f);
  float var = stats[1] * (1.f / 128.f) - mean * mean;
  float rs = rsqrtf(var + 1e-5f);
  if (tid < 128) rv[tid] = hv[tid] + (mv[tid] - mean) * rs * memg[tid] + membt[tid];
  __syncthreads();
  if (tid < OUTN) {
    float a = headb[tid];
    for (int dd = 0; dd < 128; dd++) a = fmaf(rv[dd], headW[dd * OUTN + tid], a);
    out[b * OUTN + tid] = a;
  }
}

// ---------------------------------------------------------------------------
extern "C" void kernel_launch(void* const* d_in, const int* in_sizes, int n_in,
                              void* d_out, int out_size, void* d_ws, size_t ws_size,
                              hipStream_t stream) {
  (void)in_sizes; (void)n_in; (void)out_size; (void)ws_size;
  const float* x        = (const float*)d_in[0];
  const float* role_emb = (const float*)d_in[1];
  const float* filler_w = (const float*)d_in[2];
  const float* qW = (const float*)d_in[3];
  const float* qb = (const float*)d_in[4];
  const float* kW = (const float*)d_in[5];
  const float* kb = (const float*)d_in[6];
  const float* vW = (const float*)d_in[7];
  const float* vb = (const float*)d_in[8];
  const float* oW = (const float*)d_in[9];
  const float* ob = (const float*)d_in[10];
  const float* relW1 = (const float*)d_in[11];
  const float* relb1 = (const float*)d_in[12];
  const float* relW2 = (const float*)d_in[13];
  const float* relb2 = (const float*)d_in[14];
  const float* ln1g = (const float*)d_in[15];
  const float* ln1b = (const float*)d_in[16];
  const float* ln2g = (const float*)d_in[17];
  const float* ln2b = (const float*)d_in[18];
  const float* fW1 = (const float*)d_in[19];
  const float* fb1 = (const float*)d_in[20];
  const float* fW2 = (const float*)d_in[21];
  const float* fb2 = (const float*)d_in[22];
  const float* slots = (const float*)d_in[23];
  const float* memg = (const float*)d_in[24];
  const float* memb = (const float*)d_in[25];
  const float* taskq = (const float*)d_in[26];
  const float* headW = (const float*)d_in[27];
  const float* headb = (const float*)d_in[28];
  float* out = (float*)d_out;
  (void)relb2;  // dropped: softmax shift-invariance

  // workspace layout (float-slot offsets; all 16B aligned)
  float* fws  = (float*)d_ws;
  int*    idxb   = (int*)d_ws;                //   1600 ints
  float*  vals   = fws + 1600;                //   1600 f
  float*  btok   = fws + 3200;                // 204800 f
  float*  qbuf   = fws + 208000;              // 204800 f
  bf16_t* btokbf = (bf16_t*)(fws + 412800);   // 204800 bf16
  bf16_t* kbf    = (bf16_t*)(fws + 515200);   // 204800 bf16
  bf16_t* vbf    = (bf16_t*)(fws + 617600);   // 204800 bf16
  bf16_t* obufbf = (bf16_t*)(fws + 720000);   // 204800 bf16
  bf16_t* wtb    = (bf16_t*)(fws + 822400);   // 589824 bf16 (end ~4.5MB)
  bf16_t* qWt = wtb, *kWt = wtb + 49152, *vWt = wtb + 98304, *oWt = wtb + 147456;
  bf16_t* fW1t = wtb + 196608, *fW2t = wtb + 393216;

  wconv_kernel<<<144, 256, 0, stream>>>(qW, kW, vW, oW, fW1, fW2, wtb);
  topk_kernel<<<8, 256, 0, stream>>>(x, vals, idxb);
  bind_kernel<<<800, 256, 0, stream>>>(vals, idxb, role_emb, filler_w, btok, btokbf);
  for (int l = 0; l < LLAY; l++) {
    qkv_mfma<<<dim3(25, 3), 256, 0, stream>>>(btokbf,
        qWt + l * 16384, qb + l * 128, kWt + l * 16384, kb + l * 128,
        vWt + l * 16384, vb + l * 128, qbuf, kbf, vbf);
    rel_attn_mfma<<<dim3(25, 32), 256, 0, stream>>>(qbuf, kbf, vbf,
        relW1 + l * 3072, relb1 + l * 32, relW2 + l * 32, obufbf);
    gemmln_mfma<<<25, 256, 0, stream>>>(obufbf, 128, 128, oWt + l * 16384,
        ob + l * 128, ln1g + l * 128, ln1b + l * 128, btok, btokbf);
    ffn_fused<<<25, 256, 0, stream>>>(btokbf, fW1t + l * 65536, fb1 + l * 512,
        fW2t + l * 65536, fb2 + l * 128, ln2g + l * 128, ln2b + l * 128,
        btok, btokbf);
  }
  readout_fused<<<8, 256, 0, stream>>>(btok, btokbf, slots, taskq,
      memg, memb, headW, headb, out);
}